// Round 8
// baseline (1154.032 us; speedup 1.0000x reference)
//
#include <hip/hip_runtime.h>
#include <math.h>

#define SDIM 64
#define KDIM 16
#define ODIM 32
#define HDIM 30
#define TDIM 200
#define NDIM 512
#define NP 69761
#define EPSV 1e-6f
#define LOG2PIF 1.8378770664093453f

__device__ __forceinline__ float softplusf(float x) {
    return (x > 0.f) ? x + log1pf(expf(-x)) : log1pf(expf(x));
}
__device__ __forceinline__ float wave_max64(float v) {
#pragma unroll
    for (int off = 32; off; off >>= 1) v = fmaxf(v, __shfl_xor(v, off, 64));
    return v;
}
__device__ __forceinline__ float wave_sum64(float v) {
#pragma unroll
    for (int off = 32; off; off >>= 1) v += __shfl_xor(v, off, 64);
    return v;
}
// barrier that waits only on LDS ops — leaves global loads/stores in flight
__device__ __forceinline__ void bar_lds() {
    asm volatile("s_waitcnt lgkmcnt(0)\n\ts_barrier" ::: "memory");
}

// ---------------- kernel 1: per-n parameter transforms ----------------
__global__ __launch_bounds__(256) void transform_kernel(
    const float* __restrict__ theta, float* __restrict__ invstd,
    float* __restrict__ c0, float* __restrict__ ent,
    float* __restrict__ logC, float* __restrict__ Dws,
    float* __restrict__ pdfws)
{
    __shared__ float ls[SDIM * 33];
    const int n = blockIdx.x, tid = threadIdx.x;
    const float* thn = theta + (size_t)n * NP;

    for (int idx = tid; idx < SDIM * ODIM; idx += 256) {
        float x = thn[2048 + idx];
        float sp = softplusf(x) + EPSV;            // A_std
        invstd[(size_t)n * SDIM * ODIM + idx] = 1.f / sp;
        int s = idx >> 5, oo = idx & 31;
        ls[s * 33 + oo] = logf(sp);
    }
    __syncthreads();

    const int wave = tid >> 6, lane = tid & 63;
    if (wave == 0) {                                // c0, ent per state s
        float sum = 0.f;
#pragma unroll
        for (int oo = 0; oo < ODIM; ++oo) sum += ls[lane * 33 + oo];
        c0[n * SDIM + lane]  = -sum - 16.f * LOG2PIF;
        ent[n * SDIM + lane] =  sum + 32.f * (0.5f + 0.5f * LOG2PIF);
    } else if (wave == 1) {                         // log(C + eps)
        float x = thn[69632 + lane];
        float m = wave_max64(x);
        float e = expf(x - m);
        float ssum = wave_sum64(e);
        logC[n * SDIM + lane] = logf(e / ssum + EPSV);
    } else if (wave == 2) {                         // D = softmax(tD)
        float x = thn[69696 + lane];
        float m = wave_max64(x);
        float e = expf(x - m);
        float ssum = wave_sum64(e);
        Dws[n * SDIM + lane] = e / ssum;
    } else {                                        // truncated poisson pdf
        float tt = thn[69760];
        float tau = 60.f / (1.f + expf(-tt)) + 1.f;
        float p = 0.f;
        if (lane < HDIM)
            p = expf((float)lane * logf(tau) - tau - lgammaf((float)lane + 1.f));
        float ssum = wave_sum64(p);
        if (lane < HDIM) pdfws[n * HDIM + lane] = p / ssum;
    }
}

// ------------- kernel 2: per-row B softmax stats (lse) + reward r -------------
__global__ __launch_bounds__(256) void row_stats_kernel(
    const float* __restrict__ theta, const float* __restrict__ logC,
    const float* __restrict__ ent, float* __restrict__ lse,
    float* __restrict__ rws)
{
    const int gw = blockIdx.x * 4 + (threadIdx.x >> 6);  // global row (n,k,i)
    const int lane = threadIdx.x & 63;
    const int n = gw >> 10, rl = gw & 1023;
    float x = theta[(size_t)n * NP + 4096 + (size_t)rl * 64 + lane];
    float m = wave_max64(x);
    float e = expf(x - m);
    float ssum = wave_sum64(e);
    float Bj = e / ssum;
    float contrib = Bj * (logf(Bj + EPSV) - logC[n * SDIM + lane] + ent[n * SDIM + lane]);
    contrib = wave_sum64(contrib);
    if (lane == 0) {
        lse[gw] = m + logf(ssum);
        rws[gw] = -contrib;
    }
}

// ------- kernel 3: belief scan, 3 waves per n (2 producers + 1 consumer) -------
__global__ __launch_bounds__(192) void belief3_kernel(
    const float* __restrict__ o, const int* __restrict__ a,
    const float* __restrict__ theta, const float* __restrict__ lse,
    const float* __restrict__ invstd, const float* __restrict__ c0g,
    const float* __restrict__ Dws,
    float* __restrict__ out_b, float* __restrict__ out_lp)
{
    __shared__ float o_s[TDIM * ODIM];       // 25.6 KB
    __shared__ int   a_s[TDIM];
    __shared__ float lse_s[KDIM * SDIM];     // 4 KB
    __shared__ __align__(16) float b_bc[2][SDIM];
    __shared__ float part_s[2][SDIM];

    const int n = blockIdx.x, tid = threadIdx.x;
    const int w = tid / 64, lane = tid & 63;
    const float* thn = theta + (size_t)n * NP;
    const float* Xn  = thn + 4096;

    for (int idx = tid; idx < TDIM * ODIM; idx += 192)
        o_s[idx] = o[((size_t)(idx >> 5) * NDIM + n) * ODIM + (idx & 31)];
    for (int idx = tid; idx < TDIM; idx += 192)
        a_s[idx] = a[idx * NDIM + n];
    for (int idx = tid; idx < KDIM * SDIM; idx += 192)
        lse_s[idx] = lse[(size_t)n * KDIM * SDIM + idx];

    // consumer-wave registers
    float mean_r[ODIM], istd_r[ODIM], c0_r = 0.f, bval = 0.f;
    if (w == 0) {
#pragma unroll
        for (int q = 0; q < 8; ++q) {
            float4 mv = *(const float4*)&thn[lane * ODIM + q * 4];
            float4 iv = *(const float4*)&invstd[((size_t)n * SDIM + lane) * ODIM + q * 4];
            mean_r[q * 4 + 0] = mv.x; mean_r[q * 4 + 1] = mv.y;
            mean_r[q * 4 + 2] = mv.z; mean_r[q * 4 + 3] = mv.w;
            istd_r[q * 4 + 0] = iv.x; istd_r[q * 4 + 1] = iv.y;
            istd_r[q * 4 + 2] = iv.z; istd_r[q * 4 + 3] = iv.w;
        }
        c0_r = c0g[n * SDIM + lane];
        bval = Dws[n * SDIM + lane];
        b_bc[0][lane] = bval;
    }
    __syncthreads();

    // producer state: wave w (1,2) owns i-range ioff..ioff+31 (columns j = lane)
    const int ioff = (w - 1) * 32;
    float raw[32], er[32];
    if (w >= 1) {
        const int a0 = a_s[0];
        const float* X0 = Xn + (size_t)a0 * SDIM * SDIM;
        const float* l0 = &lse_s[a0 * SDIM + ioff];
#pragma unroll
        for (int ii = 0; ii < 32; ++ii)
            er[ii] = __expf(X0[(size_t)(ioff + ii) * SDIM + lane] - l0[ii]);
        const int a1 = a_s[1];
        const float* X1 = Xn + (size_t)a1 * SDIM * SDIM;
#pragma unroll
        for (int ii = 0; ii < 32; ++ii)
            raw[ii] = X1[(size_t)(ioff + ii) * SDIM + lane];
    }

#pragma unroll 1
    for (int t = 0; t < TDIM; ++t) {
        const int cur = t & 1, nxt = cur ^ 1;
        float z2 = 0.f;

        // ===== phase 1 =====
        if (w >= 1) {
            float4 bb[8];
#pragma unroll
            for (int q = 0; q < 8; ++q)
                bb[q] = *(const float4*)&b_bc[cur][ioff + q * 4];
            float a0c = 0.f, a1c = 0.f, a2c = 0.f, a3c = 0.f;
#pragma unroll
            for (int q = 0; q < 8; ++q) {
                a0c += er[q * 4 + 0] * bb[q].x;
                a1c += er[q * 4 + 1] * bb[q].y;
                a2c += er[q * 4 + 2] * bb[q].z;
                a3c += er[q * 4 + 3] * bb[q].w;
            }
            part_s[w - 1][lane] = (a0c + a1c) + (a2c + a3c);
            // convert first half of er for t+1 (raw loaded at t-1)
            if (t + 1 < TDIM) {
                const int a1 = a_s[t + 1];
                const float* l1 = &lse_s[a1 * SDIM + ioff];
#pragma unroll
                for (int ii = 0; ii < 16; ++ii)
                    er[ii] = __expf(raw[ii] - l1[ii]);
            }
        } else {
            float4 om[8];
#pragma unroll
            for (int q = 0; q < 8; ++q)
                om[q] = *(const float4*)&o_s[t * ODIM + q * 4];
            float za = 0.f, zb = 0.f, zc = 0.f, zd = 0.f;
#pragma unroll
            for (int q = 0; q < 8; ++q) {
                float z0 = (om[q].x - mean_r[q * 4 + 0]) * istd_r[q * 4 + 0];
                float z1 = (om[q].y - mean_r[q * 4 + 1]) * istd_r[q * 4 + 1];
                float z2_ = (om[q].z - mean_r[q * 4 + 2]) * istd_r[q * 4 + 2];
                float z3 = (om[q].w - mean_r[q * 4 + 3]) * istd_r[q * 4 + 3];
                za += z0 * z0; zb += z1 * z1; zc += z2_ * z2_; zd += z3 * z3;
            }
            z2 = (za + zb) + (zc + zd);
            out_b[((size_t)t * NDIM + n) * SDIM + lane] = bval;
        }
        bar_lds();   // A: parts ready

        // ===== phase 2 =====
        if (w == 0) {
            float sv = part_s[0][lane] + part_s[1][lane];
            float joint = __logf(sv + EPSV) + c0_r - 0.5f * z2;
            float m = wave_max64(joint);
            float e = __expf(joint - m);
            float S = wave_sum64(e);
            bval = e / S;
            b_bc[nxt][lane] = bval;
            if (lane == 0) out_lp[(size_t)t * NDIM + n] = m + __logf(S);
        } else {
            if (t + 1 < TDIM) {
                const int a1 = a_s[t + 1];
                const float* l1 = &lse_s[a1 * SDIM + ioff];
#pragma unroll
                for (int ii = 16; ii < 32; ++ii)
                    er[ii] = __expf(raw[ii] - l1[ii]);
            }
            const int t2 = (t + 2 < TDIM) ? t + 2 : TDIM - 1;
            const int a2 = a_s[t2];
            const float* X2 = Xn + (size_t)a2 * SDIM * SDIM;
#pragma unroll
            for (int ii = 0; ii < 32; ++ii)
                raw[ii] = X2[(size_t)(ioff + ii) * SDIM + lane];
        }
        bar_lds();   // B: b_bc[nxt] ready
    }
}

// ------- kernel 4: fused VI (q -> LDS) + policy (q in registers, no barriers) -------
#define QLS 68
__global__ __launch_bounds__(512) void vipolicy_kernel(
    const float* __restrict__ theta, const float* __restrict__ lse,
    const float* __restrict__ rws, const float* __restrict__ pdfg,
    const float* __restrict__ out_b_g, float* __restrict__ out_pi)
{
    __shared__ __align__(16) float q_lds[HDIM * KDIM * QLS];  // 130,560 B
    __shared__ __align__(16) float v_lds[68];
    __shared__ float pdf_s[32];

    const int n = blockIdx.x, tid = threadIdx.x;
    const float* Xn = theta + (size_t)n * NP + 4096;

    // ---- VI: thread owns B rows tid and tid+512 of the (k*64+i) grid ----
    const float l0  = lse[(size_t)n * 1024 + tid];
    const float l1  = lse[(size_t)n * 1024 + 512 + tid];
    const float rr0 = rws[(size_t)n * 1024 + tid];
    const float rr1 = rws[(size_t)n * 1024 + 512 + tid];

    float4 er0[16], er1[16];
    {
        const float* X0 = Xn + (size_t)tid * 64;
        const float* X1 = Xn + (size_t)(512 + tid) * 64;
#pragma unroll
        for (int j = 0; j < 16; ++j) {
            float4 x = *(const float4*)(X0 + j * 4);
            er0[j] = make_float4(__expf(x.x - l0), __expf(x.y - l0),
                                 __expf(x.z - l0), __expf(x.w - l0));
            float4 y = *(const float4*)(X1 + j * 4);
            er1[j] = make_float4(__expf(y.x - l1), __expf(y.y - l1),
                                 __expf(y.z - l1), __expf(y.w - l1));
        }
    }

    const int kq0 = tid >> 6, iq = tid & 63;
    q_lds[(0 * KDIM + kq0) * QLS + iq] = rr0;
    q_lds[(0 * KDIM + kq0 + 8) * QLS + iq] = rr1;
    if (tid < 32) pdf_s[tid] = (tid < HDIM) ? pdfg[n * HDIM + tid] : 0.f;
    __syncthreads();

#pragma unroll 1
    for (int h = 1; h < HDIM; ++h) {
        if (tid < 64) {
            const int base = (h - 1) * KDIM;
            float m = -1e30f;
#pragma unroll
            for (int k = 0; k < KDIM; ++k) m = fmaxf(m, q_lds[(base + k) * QLS + tid]);
            float s = 0.f;
#pragma unroll
            for (int k = 0; k < KDIM; ++k) s += __expf(q_lds[(base + k) * QLS + tid] - m);
            v_lds[tid] = m + __logf(s);
        }
        bar_lds();
        float a0x = 0.f, a0y = 0.f, a0z = 0.f, a0w = 0.f;
        float a1x = 0.f, a1y = 0.f, a1z = 0.f, a1w = 0.f;
#pragma unroll
        for (int jq = 0; jq < 16; ++jq) {
            const float4 v4 = *(const float4*)&v_lds[jq * 4];
            a0x += er0[jq].x * v4.x; a0y += er0[jq].y * v4.y;
            a0z += er0[jq].z * v4.z; a0w += er0[jq].w * v4.w;
            a1x += er1[jq].x * v4.x; a1y += er1[jq].y * v4.y;
            a1z += er1[jq].z * v4.z; a1w += er1[jq].w * v4.w;
        }
        q_lds[(h * KDIM + kq0) * QLS + iq]     = rr0 + ((a0x + a0y) + (a0z + a0w));
        q_lds[(h * KDIM + kq0 + 8) * QLS + iq] = rr1 + ((a1x + a1y) + (a1z + a1w));
        bar_lds();
    }

    // ---- transition: wave w owns h = w*4 + (lane>>4); lane&15 = k ----
    const int w = tid >> 6, lane = tid & 63;
    const int hl = lane >> 4, kk = lane & 15;
    const int hown = w * 4 + hl;                      // 0..31
    const float pdfh = pdf_s[hown];                   // 0 for pad rows
    float4 qrow[16];
    if (hown < HDIM) {
#pragma unroll
        for (int jq = 0; jq < 16; ++jq)
            qrow[jq] = *(const float4*)&q_lds[(hown * KDIM + kk) * QLS + jq * 4];
    } else {
#pragma unroll
        for (int jq = 0; jq < 16; ++jq)
            qrow[jq] = make_float4(0.f, 0.f, 0.f, 0.f);
    }

    // ---- policy loop: no barriers, b ping-pong, pi via global atomics ----
    const float* bg = out_b_g + (size_t)n * SDIM;
    float* pin = out_pi + (size_t)n * KDIM;

#define PCOMP(T_, B_) do {                                                     \
    float ax_ = 0.f, ay_ = 0.f, az_ = 0.f, aw_ = 0.f;                          \
    _Pragma("unroll")                                                          \
    for (int jq = 0; jq < 16; ++jq) {                                          \
        ax_ += qrow[jq].x * B_[jq].x; ay_ += qrow[jq].y * B_[jq].y;            \
        az_ += qrow[jq].z * B_[jq].z; aw_ += qrow[jq].w * B_[jq].w;            \
    }                                                                          \
    float acc_ = (ax_ + ay_) + (az_ + aw_);                                    \
    float m_ = acc_;                                                           \
    m_ = fmaxf(m_, __shfl_xor(m_, 1, 64));                                     \
    m_ = fmaxf(m_, __shfl_xor(m_, 2, 64));                                     \
    m_ = fmaxf(m_, __shfl_xor(m_, 4, 64));                                     \
    m_ = fmaxf(m_, __shfl_xor(m_, 8, 64));                                     \
    float e_ = __expf(acc_ - m_);                                              \
    float S_ = e_;                                                             \
    S_ += __shfl_xor(S_, 1, 64);                                               \
    S_ += __shfl_xor(S_, 2, 64);                                               \
    S_ += __shfl_xor(S_, 4, 64);                                               \
    S_ += __shfl_xor(S_, 8, 64);                                               \
    float c_ = pdfh * e_ / S_;                                                 \
    c_ += __shfl_xor(c_, 16, 64);                                              \
    c_ += __shfl_xor(c_, 32, 64);                                              \
    if (lane < 16)                                                             \
        atomicAdd(&pin[(size_t)(T_) * NDIM * KDIM + lane], c_);                \
} while (0)

    float4 bA[16], bB[16];
#pragma unroll
    for (int jq = 0; jq < 16; ++jq)
        bA[jq] = *(const float4*)&bg[jq * 4];

#pragma unroll 1
    for (int t = 0; t < TDIM; t += 2) {
#pragma unroll
        for (int jq = 0; jq < 16; ++jq)
            bB[jq] = *(const float4*)&bg[(size_t)(t + 1) * NDIM * SDIM + jq * 4];
        PCOMP(t, bA);
        if (t + 2 < TDIM) {
#pragma unroll
            for (int jq = 0; jq < 16; ++jq)
                bA[jq] = *(const float4*)&bg[(size_t)(t + 2) * NDIM * SDIM + jq * 4];
        }
        PCOMP(t + 1, bB);
    }
#undef PCOMP
}

extern "C" void kernel_launch(void* const* d_in, const int* in_sizes, int n_in,
                              void* d_out, int out_size, void* d_ws, size_t ws_size,
                              hipStream_t stream) {
    (void)in_sizes; (void)n_in; (void)out_size; (void)ws_size;
    const float* o     = (const float*)d_in[0];
    const int*   a     = (const int*)d_in[1];
    const float* theta = (const float*)d_in[2];
    float* out = (float*)d_out;
    float* ws  = (float*)d_ws;

    float* lse    = ws;                                   // N*K*S
    float* rws    = lse    + (size_t)NDIM * KDIM * SDIM;  // N*K*S
    float* invstd = rws    + (size_t)NDIM * KDIM * SDIM;  // N*S*O
    float* c0     = invstd + (size_t)NDIM * SDIM * ODIM;  // N*S
    float* ent    = c0     + (size_t)NDIM * SDIM;         // N*S
    float* logC   = ent    + (size_t)NDIM * SDIM;         // N*S
    float* Dws    = logC   + (size_t)NDIM * SDIM;         // N*S
    float* pdfws  = Dws    + (size_t)NDIM * SDIM;         // N*H

    float* out_pi = out;
    float* out_b  = out + (size_t)TDIM * NDIM * KDIM;
    float* out_lp = out + (size_t)TDIM * NDIM * KDIM + (size_t)TDIM * NDIM * SDIM;

    // pi accumulated via atomics — zero it every call (deterministic work)
    hipMemsetAsync(out_pi, 0, (size_t)TDIM * NDIM * KDIM * sizeof(float), stream);

    transform_kernel<<<NDIM, 256, 0, stream>>>(theta, invstd, c0, ent, logC, Dws, pdfws);
    row_stats_kernel<<<(NDIM * KDIM * SDIM) / 4, 256, 0, stream>>>(theta, logC, ent, lse, rws);
    belief3_kernel<<<NDIM, 192, 0, stream>>>(o, a, theta, lse, invstd, c0, Dws, out_b, out_lp);
    vipolicy_kernel<<<NDIM, 512, 0, stream>>>(theta, lse, rws, pdfws, out_b, out_pi);
}

// Round 10
// 1065.844 us; speedup vs baseline: 1.0827x; 1.0827x over previous
//
#include <hip/hip_runtime.h>
#include <hip/hip_bf16.h>
#include <math.h>

#define SDIM 64
#define KDIM 16
#define ODIM 32
#define HDIM 30
#define TDIM 200
#define NDIM 512
#define NP 69761
#define EPSV 1e-6f
#define LOG2PIF 1.8378770664093453f

__device__ __forceinline__ float softplusf(float x) {
    return (x > 0.f) ? x + log1pf(expf(-x)) : log1pf(expf(x));
}
__device__ __forceinline__ float wave_max64(float v) {
#pragma unroll
    for (int off = 32; off; off >>= 1) v = fmaxf(v, __shfl_xor(v, off, 64));
    return v;
}
__device__ __forceinline__ float wave_sum64(float v) {
#pragma unroll
    for (int off = 32; off; off >>= 1) v += __shfl_xor(v, off, 64);
    return v;
}
// barrier that waits only on LDS ops — leaves global loads/stores in flight
__device__ __forceinline__ void bar_lds() {
    asm volatile("s_waitcnt lgkmcnt(0)\n\ts_barrier" ::: "memory");
}

// ---------------- kernel 1: per-n parameter transforms ----------------
__global__ __launch_bounds__(256) void transform_kernel(
    const float* __restrict__ theta, float* __restrict__ invstd,
    float* __restrict__ c0, float* __restrict__ ent,
    float* __restrict__ logC, float* __restrict__ Dws,
    float* __restrict__ pdfws)
{
    __shared__ float ls[SDIM * 33];
    const int n = blockIdx.x, tid = threadIdx.x;
    const float* thn = theta + (size_t)n * NP;

    for (int idx = tid; idx < SDIM * ODIM; idx += 256) {
        float x = thn[2048 + idx];
        float sp = softplusf(x) + EPSV;            // A_std
        invstd[(size_t)n * SDIM * ODIM + idx] = 1.f / sp;
        int s = idx >> 5, oo = idx & 31;
        ls[s * 33 + oo] = logf(sp);
    }
    __syncthreads();

    const int wave = tid >> 6, lane = tid & 63;
    if (wave == 0) {                                // c0, ent per state s
        float sum = 0.f;
#pragma unroll
        for (int oo = 0; oo < ODIM; ++oo) sum += ls[lane * 33 + oo];
        c0[n * SDIM + lane]  = -sum - 16.f * LOG2PIF;
        ent[n * SDIM + lane] =  sum + 32.f * (0.5f + 0.5f * LOG2PIF);
    } else if (wave == 1) {                         // log(C + eps)
        float x = thn[69632 + lane];
        float m = wave_max64(x);
        float e = expf(x - m);
        float ssum = wave_sum64(e);
        logC[n * SDIM + lane] = logf(e / ssum + EPSV);
    } else if (wave == 2) {                         // D = softmax(tD)
        float x = thn[69696 + lane];
        float m = wave_max64(x);
        float e = expf(x - m);
        float ssum = wave_sum64(e);
        Dws[n * SDIM + lane] = e / ssum;
    } else {                                        // truncated poisson pdf
        float tt = thn[69760];
        float tau = 60.f / (1.f + expf(-tt)) + 1.f;
        float p = 0.f;
        if (lane < HDIM)
            p = expf((float)lane * logf(tau) - tau - lgammaf((float)lane + 1.f));
        float ssum = wave_sum64(p);
        if (lane < HDIM) pdfws[n * HDIM + lane] = p / ssum;
    }
}

// ---- kernel 2: per-row B softmax stats + reward; optional bf16 B store ----
// bn layout (transposed): bn[((n*K + k)*S + j)*S + i]  (j = output state)
__global__ __launch_bounds__(256) void row_stats_kernel(
    const float* __restrict__ theta, const float* __restrict__ logC,
    const float* __restrict__ ent, float* __restrict__ lse,
    float* __restrict__ rws, __hip_bfloat16* __restrict__ bn)
{
    const int gw = blockIdx.x * 4 + (threadIdx.x >> 6);  // global row (n,k,i)
    const int lane = threadIdx.x & 63;
    const int n = gw >> 10, rl = gw & 1023;
    float x = theta[(size_t)n * NP + 4096 + (size_t)rl * 64 + lane];
    float m = wave_max64(x);
    float e = expf(x - m);
    float ssum = wave_sum64(e);
    float Bj = e / ssum;
    if (bn) {
        const int k = rl >> 6, i = rl & 63;
        bn[(((size_t)n * KDIM + k) * SDIM + lane) * SDIM + i] = __float2bfloat16(Bj);
    }
    float contrib = Bj * (logf(Bj + EPSV) - logC[n * SDIM + lane] + ent[n * SDIM + lane]);
    contrib = wave_sum64(contrib);
    if (lane == 0) {
        lse[gw] = m + logf(ssum);
        rws[gw] = -contrib;
    }
}

// z2 partial for step TT_ into buffer BUF_ (waves 1..4, 8 obs each)
#define Z2PART(TT_, BUF_) do {                                                 \
    const int ob_ = (wave - 1) * 8;                                            \
    const float* om_ = &o_s[(TT_) * ODIM + ob_];                               \
    float zz_ = 0.f;                                                           \
    _Pragma("unroll")                                                          \
    for (int j_ = 0; j_ < 8; ++j_) {                                           \
        float z_ = (om_[j_] - mean_s[lane * 33 + ob_ + j_])                    \
                 * istd_s[lane * 33 + ob_ + j_];                               \
        zz_ += z_ * z_;                                                        \
    }                                                                          \
    z2p_s[BUF_][wave - 1][lane] = zz_;                                         \
} while (0)

// ===================== TIER-1 belief: bf16 B + softmax-free step =====================
// one step; U_ = 5 packed uints holding bf16 B rows for step T_+1
#define BSTEPF(T_, U_) do {                                                    \
    const int cur_ = (T_) & 1, nxt_ = cur_ ^ 1;                                \
    float ecz_ = 0.f, cm_ = 0.f;                                               \
    if (wave >= 1) {                                                           \
        float aA_ = 0.f, aB_ = 0.f;                                            \
        _Pragma("unroll")                                                      \
        for (int ii = 0; ii < 10; ii += 2) {                                   \
            if (ii < nrow)     aA_ += er[ii]     * b_bc[cur_][rbase + ii];     \
            if (ii + 1 < nrow) aB_ += er[ii + 1] * b_bc[cur_][rbase + ii + 1]; \
        }                                                                      \
        part_s[wave - 1][lane] = aA_ + aB_;                                    \
        if (wave == 6) out_b[((size_t)(T_) * NDIM + n) * SDIM + lane] = b_bc[cur_][lane]; \
    } else {                                                                   \
        float z2_ = z2p_s[cur_][0][lane] + z2p_s[cur_][1][lane]                \
                  + z2p_s[cur_][2][lane] + z2p_s[cur_][3][lane];               \
        float c_ = c0_r - 0.5f * z2_;                                          \
        cm_ = wave_max64(c_);                                                  \
        ecz_ = __expf(c_ - cm_);                                               \
    }                                                                          \
    bar_lds();  /* A: parts ready */                                           \
    if (wave == 0) {                                                           \
        float sv_ = part_s[0][lane] + part_s[1][lane] + part_s[2][lane]        \
                  + part_s[3][lane] + part_s[4][lane] + part_s[5][lane]        \
                  + part_s[6][lane];                                           \
        float u_ = (sv_ + EPSV) * ecz_;                                        \
        float S_ = wave_sum64(u_);                                             \
        b_bc[nxt_][lane] = u_ / S_;                                            \
        if (lane == 0) out_lp[(size_t)(T_) * NDIM + n] = cm_ + __logf(S_);     \
    } else {                                                                   \
        if ((T_) + 1 < TDIM) {                                                 \
            _Pragma("unroll")                                                  \
            for (int m_ = 0; m_ < 5; ++m_) {                                   \
                if (2 * m_ < nrow)                                             \
                    er[2 * m_] = __uint_as_float(U_[m_] << 16);                \
                if (2 * m_ + 1 < nrow)                                         \
                    er[2 * m_ + 1] = __uint_as_float(U_[m_] & 0xffff0000u);    \
            }                                                                  \
            if (wave <= 4) Z2PART((T_) + 1, nxt_);                             \
        }                                                                      \
        const int tl_ = ((T_) + 3 < TDIM) ? (T_) + 3 : TDIM - 1;               \
        const uint* up_ = (const uint*)(bnn + (size_t)a_s[tl_] * SDIM * SDIM   \
                                        + (size_t)lane * SDIM + rbase);        \
        _Pragma("unroll")                                                      \
        for (int m_ = 0; m_ < 5; ++m_)                                         \
            if (2 * m_ < nrow) U_[m_] = up_[m_];                               \
    }                                                                          \
    bar_lds();  /* B: b ready */                                               \
} while (0)

__global__ __launch_bounds__(512) void belief_fast_kernel(
    const float* __restrict__ o, const int* __restrict__ a,
    const float* __restrict__ theta, const __hip_bfloat16* __restrict__ bn,
    const float* __restrict__ invstd, const float* __restrict__ c0g,
    const float* __restrict__ Dws,
    float* __restrict__ out_b, float* __restrict__ out_lp)
{
    __shared__ float o_s[TDIM * ODIM];       // 25.6 KB
    __shared__ int   a_s[TDIM];
    __shared__ float mean_s[SDIM * 33];
    __shared__ float istd_s[SDIM * 33];
    __shared__ float c0_sh[SDIM];
    __shared__ __align__(16) float b_bc[2][SDIM];
    __shared__ float part_s[7][68];
    __shared__ float z2p_s[2][4][SDIM];

    const int n = blockIdx.x, tid = threadIdx.x;
    const int wave = tid >> 6, lane = tid & 63;
    const float* thn = theta + (size_t)n * NP;
    const __hip_bfloat16* bnn = bn + (size_t)n * KDIM * SDIM * SDIM;

    for (int idx = tid; idx < TDIM * ODIM; idx += 512)
        o_s[idx] = o[((size_t)(idx >> 5) * NDIM + n) * ODIM + (idx & 31)];
    if (tid < TDIM) a_s[tid] = a[tid * NDIM + n];
    for (int idx = tid; idx < SDIM * ODIM; idx += 512) {
        int s = idx >> 5, oo = idx & 31;
        mean_s[s * 33 + oo] = thn[idx];
        istd_s[s * 33 + oo] = invstd[(size_t)n * SDIM * ODIM + idx];
    }
    if (tid < SDIM) { c0_sh[tid] = c0g[n * SDIM + tid]; b_bc[0][tid] = Dws[n * SDIM + tid]; }
    __syncthreads();

    const float c0_r = (wave == 0) ? c0_sh[lane] : 0.f;
    const int rbase = (wave >= 1) ? (wave - 1) * 10 : 0;
    const int nrow  = (wave >= 1) ? ((SDIM - rbase) < 10 ? (SDIM - rbase) : 10) : 0;

    float er[10];
    uint u0[5], u1[5];
    if (wave >= 1) {
        // er <- B(a_0); u0 <- B(a_1); u1 <- B(a_2)
        const uint* p0 = (const uint*)(bnn + (size_t)a_s[0] * SDIM * SDIM
                                       + (size_t)lane * SDIM + rbase);
#pragma unroll
        for (int m = 0; m < 5; ++m) if (2 * m < nrow) u0[m] = p0[m];
#pragma unroll
        for (int m = 0; m < 5; ++m) {
            if (2 * m < nrow)     er[2 * m]     = __uint_as_float(u0[m] << 16);
            if (2 * m + 1 < nrow) er[2 * m + 1] = __uint_as_float(u0[m] & 0xffff0000u);
        }
        const uint* p1 = (const uint*)(bnn + (size_t)a_s[1] * SDIM * SDIM
                                       + (size_t)lane * SDIM + rbase);
#pragma unroll
        for (int m = 0; m < 5; ++m) if (2 * m < nrow) u0[m] = p1[m];
        const uint* p2 = (const uint*)(bnn + (size_t)a_s[2] * SDIM * SDIM
                                       + (size_t)lane * SDIM + rbase);
#pragma unroll
        for (int m = 0; m < 5; ++m) if (2 * m < nrow) u1[m] = p2[m];
        if (wave <= 4) Z2PART(0, 0);
    }
    __syncthreads();

#pragma unroll 1
    for (int t = 0; t < TDIM; t += 2) {
        BSTEPF(t, u0);
        BSTEPF(t + 1, u1);
    }
}

// ===================== TIER-2 belief (round-6, f32 logits + exp) =====================
#define BSTEP(T_, RAW_) do {                                                   \
    const int cur_ = (T_) & 1, nxt_ = cur_ ^ 1;                                \
    if (wave >= 1) {                                                           \
        float acc_ = 0.f;                                                      \
        _Pragma("unroll")                                                      \
        for (int ii = 0; ii < 10; ++ii)                                        \
            if (ii < nrow) acc_ += er[ii] * b_s[cur_][rbase + ii];             \
        part_s[wave - 1][lane] = acc_;                                         \
        if (wave == 6) out_b[((size_t)(T_) * NDIM + n) * SDIM + lane] = b_s[cur_][lane]; \
    }                                                                          \
    bar_lds();                                                                 \
    if (wave == 0) {                                                           \
        float sv_ = part_s[0][lane] + part_s[1][lane] + part_s[2][lane]        \
                  + part_s[3][lane] + part_s[4][lane] + part_s[5][lane]        \
                  + part_s[6][lane];                                           \
        float z2_ = z2p_s[cur_][0][lane] + z2p_s[cur_][1][lane]                \
                  + z2p_s[cur_][2][lane] + z2p_s[cur_][3][lane];               \
        float joint_ = __logf(sv_ + EPSV) + c0_s[lane] - 0.5f * z2_;           \
        float m_ = wave_max64(joint_);                                         \
        float e_ = __expf(joint_ - m_);                                        \
        float ss_ = wave_sum64(e_);                                            \
        b_s[nxt_][lane] = e_ / ss_;                                            \
        if (lane == 0) out_lp[(size_t)(T_) * NDIM + n] = m_ + __logf(ss_);     \
    } else {                                                                   \
        if ((T_) + 1 < TDIM) {                                                 \
            const int an_ = a_s[(T_) + 1];                                     \
            const float* ln_ = lseA + an_ * SDIM;                              \
            _Pragma("unroll")                                                  \
            for (int ii = 0; ii < 10; ++ii)                                    \
                if (ii < nrow) er[ii] = __expf(RAW_[ii] - ln_[rbase + ii]);    \
            if (wave <= 4) Z2PART((T_) + 1, nxt_);                             \
        }                                                                      \
        const int tl_ = ((T_) + 3 < TDIM) ? (T_) + 3 : TDIM - 1;               \
        const int a3_ = a_s[tl_];                                              \
        const float* X3_ = Xn + (size_t)a3_ * SDIM * SDIM;                     \
        _Pragma("unroll")                                                      \
        for (int ii = 0; ii < 10; ++ii)                                        \
            if (ii < nrow) RAW_[ii] = X3_[(size_t)(rbase + ii) * SDIM + lane]; \
    }                                                                          \
    bar_lds();                                                                 \
} while (0)

__global__ __launch_bounds__(512) void belief_kernel(
    const float* __restrict__ o, const int* __restrict__ a,
    const float* __restrict__ theta, const float* __restrict__ lse,
    const float* __restrict__ invstd, const float* __restrict__ c0g,
    const float* __restrict__ Dws,
    float* __restrict__ out_b, float* __restrict__ out_lp)
{
    __shared__ float o_s[TDIM * ODIM];
    __shared__ int   a_s[TDIM];
    __shared__ float mean_s[SDIM * 33];
    __shared__ float istd_s[SDIM * 33];
    __shared__ float lseA[KDIM * SDIM];
    __shared__ float c0_s[SDIM];
    __shared__ float b_s[2][SDIM];
    __shared__ float part_s[7][68];
    __shared__ float z2p_s[2][4][SDIM];

    const int n = blockIdx.x, tid = threadIdx.x;
    const int wave = tid >> 6, lane = tid & 63;
    const float* thn = theta + (size_t)n * NP;
    const float* Xn  = thn + 4096;

    for (int idx = tid; idx < TDIM * ODIM; idx += 512)
        o_s[idx] = o[((size_t)(idx >> 5) * NDIM + n) * ODIM + (idx & 31)];
    if (tid < TDIM) a_s[tid] = a[tid * NDIM + n];
    for (int idx = tid; idx < SDIM * ODIM; idx += 512) {
        int s = idx >> 5, oo = idx & 31;
        mean_s[s * 33 + oo] = thn[idx];
        istd_s[s * 33 + oo] = invstd[(size_t)n * SDIM * ODIM + idx];
    }
    for (int idx = tid; idx < KDIM * SDIM; idx += 512)
        lseA[idx] = lse[(size_t)n * KDIM * SDIM + idx];
    if (tid < SDIM) { c0_s[tid] = c0g[n * SDIM + tid]; b_s[0][tid] = Dws[n * SDIM + tid]; }
    __syncthreads();

    const int rbase = (wave >= 1) ? (wave - 1) * 10 : 0;
    const int nrow  = (wave >= 1) ? ((SDIM - rbase) < 10 ? (SDIM - rbase) : 10) : 0;

    float er[10], raw0[10], raw1[10];
    if (wave >= 1) {
        const int a0 = a_s[0];
        const float* X0 = Xn + (size_t)a0 * SDIM * SDIM;
        const float* l0 = lseA + a0 * SDIM;
#pragma unroll
        for (int ii = 0; ii < 10; ++ii)
            if (ii < nrow) er[ii] = __expf(X0[(size_t)(rbase + ii) * SDIM + lane] - l0[rbase + ii]);
        const int a1 = a_s[1];
        const float* X1 = Xn + (size_t)a1 * SDIM * SDIM;
#pragma unroll
        for (int ii = 0; ii < 10; ++ii)
            if (ii < nrow) raw0[ii] = X1[(size_t)(rbase + ii) * SDIM + lane];
        const int a2 = a_s[2];
        const float* X2 = Xn + (size_t)a2 * SDIM * SDIM;
#pragma unroll
        for (int ii = 0; ii < 10; ++ii)
            if (ii < nrow) raw1[ii] = X2[(size_t)(rbase + ii) * SDIM + lane];
        if (wave <= 4) Z2PART(0, 0);
    }
    __syncthreads();

#pragma unroll 1
    for (int t = 0; t < TDIM; t += 2) {
        BSTEP(t, raw0);
        BSTEP(t + 1, raw1);
    }
}

// ------- VI: thread-owns-row, q streamed to global workspace -------
__global__ __launch_bounds__(512) void vi_kernel(
    const float* __restrict__ theta, const float* __restrict__ lse,
    const float* __restrict__ rws, float* __restrict__ q_ws)
{
    __shared__ float q_lds[KDIM * 68];
    __shared__ __align__(16) float v_lds[68];
    const int n = blockIdx.x, tid = threadIdx.x;
    const float* Xn = theta + (size_t)n * NP + 4096;

    const float l0  = lse[(size_t)n * 1024 + tid];
    const float l1  = lse[(size_t)n * 1024 + 512 + tid];
    const float rr0 = rws[(size_t)n * 1024 + tid];
    const float rr1 = rws[(size_t)n * 1024 + 512 + tid];

    float4 er0[16], er1[16];
    {
        const float* X0 = Xn + (size_t)tid * 64;
        const float* X1 = Xn + (size_t)(512 + tid) * 64;
#pragma unroll
        for (int j = 0; j < 16; ++j) {
            float4 x = *(const float4*)(X0 + j * 4);
            er0[j] = make_float4(__expf(x.x - l0), __expf(x.y - l0),
                                 __expf(x.z - l0), __expf(x.w - l0));
            float4 y = *(const float4*)(X1 + j * 4);
            er1[j] = make_float4(__expf(y.x - l1), __expf(y.y - l1),
                                 __expf(y.z - l1), __expf(y.w - l1));
        }
    }

    float qr0 = rr0, qr1 = rr1;
    float* qw = q_ws + (size_t)n * HDIM * 1024;
    const int kq0 = tid >> 6, iq = tid & 63;
    qw[tid] = qr0;
    qw[512 + tid] = qr1;
    q_lds[kq0 * 68 + iq] = qr0;
    q_lds[(8 + kq0) * 68 + iq] = qr1;
    __syncthreads();

#pragma unroll 1
    for (int h = 1; h < HDIM; ++h) {
        if (tid < 64) {
            float m = -1e30f;
#pragma unroll
            for (int k = 0; k < KDIM; ++k) m = fmaxf(m, q_lds[k * 68 + tid]);
            float s = 0.f;
#pragma unroll
            for (int k = 0; k < KDIM; ++k) s += __expf(q_lds[k * 68 + tid] - m);
            v_lds[tid] = m + __logf(s);
        }
        bar_lds();
        float a0x = 0.f, a0y = 0.f, a0z = 0.f, a0w = 0.f;
        float a1x = 0.f, a1y = 0.f, a1z = 0.f, a1w = 0.f;
#pragma unroll
        for (int jq = 0; jq < 16; ++jq) {
            const float4 v4 = *(const float4*)&v_lds[jq * 4];
            a0x += er0[jq].x * v4.x; a0y += er0[jq].y * v4.y;
            a0z += er0[jq].z * v4.z; a0w += er0[jq].w * v4.w;
            a1x += er1[jq].x * v4.x; a1y += er1[jq].y * v4.y;
            a1z += er1[jq].z * v4.z; a1w += er1[jq].w * v4.w;
        }
        qr0 = rr0 + ((a0x + a0y) + (a0z + a0w));
        qr1 = rr1 + ((a1x + a1y) + (a1z + a1w));
        qw[(size_t)h * 1024 + tid] = qr0;
        qw[(size_t)h * 1024 + 512 + tid] = qr1;
        q_lds[kq0 * 68 + iq] = qr0;
        q_lds[(8 + kq0) * 68 + iq] = qr1;
        bar_lds();
    }
}

// ------- policy: 4-h LDS tiles, double-buffered, 16 barriers total -------
__global__ __launch_bounds__(256) void policy4_kernel(
    const float* __restrict__ q_ws, const float* __restrict__ out_b_g,
    const float* __restrict__ pdfg, float* __restrict__ out_pi)
{
    __shared__ __align__(16) float qt[2][4 * KDIM * 68];   // 34.8 KB
    __shared__ __align__(16) float bt[32 * 68];            // 8.7 KB
    __shared__ float pdf_s[32];

    const int tch = blockIdx.x, n = blockIdx.y, tid = threadIdx.x;
    const int t0 = tch * 32;
    const int nt = (TDIM - t0) < 32 ? (TDIM - t0) : 32;
    const int tc = tid >> 4, kk = tid & 15;
    const float* qn = q_ws + (size_t)n * HDIM * 1024;

    for (int idx = tid; idx < 32 * 16; idx += 256) {
        const int row = idx >> 4, jq = idx & 15;
        float4 bv = make_float4(0.f, 0.f, 0.f, 0.f);
        if (row < nt)
            bv = *(const float4*)&out_b_g[(((size_t)(t0 + row)) * NDIM + n) * SDIM + jq * 4];
        *(float4*)&bt[row * 68 + jq * 4] = bv;
    }
    if (tid < 32) pdf_s[tid] = (tid < HDIM) ? pdfg[n * HDIM + tid] : 0.f;
    // stage h-block 0 (h = 0..3)
    {
#pragma unroll
        for (int j = 0; j < 4; ++j) {
            const int idx = tid + j * 256;
            const int hh = idx >> 8, rem = idx & 255;
            const float4 qv = *(const float4*)&qn[(size_t)hh * 1024 + rem * 4];
            *(float4*)&qt[0][(hh * KDIM + (rem >> 4)) * 68 + (rem & 15) * 4] = qv;
        }
    }
    __syncthreads();

    float4 bqA[16], bqB[16];
#pragma unroll
    for (int jq = 0; jq < 16; ++jq) {
        bqA[jq] = *(const float4*)&bt[tc * 68 + jq * 4];
        bqB[jq] = *(const float4*)&bt[(tc + 16) * 68 + jq * 4];
    }

    float pikA = 0.f, pikB = 0.f;
#pragma unroll 1
    for (int hb = 0; hb < 8; ++hb) {
        const int cur = hb & 1, nxt = cur ^ 1;
        const int hcount = (HDIM - hb * 4) < 4 ? (HDIM - hb * 4) : 4;
        // issue loads for next h-block into registers
        float4 pre[4];
        const int hb1 = (hb + 1) * 4;
        if (hb1 < HDIM) {
#pragma unroll
            for (int j = 0; j < 4; ++j) {
                const int idx = tid + j * 256;
                const int hh = idx >> 8, rem = idx & 255;
                if (hb1 + hh < HDIM)
                    pre[j] = *(const float4*)&qn[(size_t)(hb1 + hh) * 1024 + rem * 4];
            }
        }
        // compute current block
#pragma unroll
        for (int hh = 0; hh < 4; ++hh) {
            if (hh >= hcount) break;
            const float* qr = &qt[cur][(hh * KDIM + kk) * 68];
            float aAx = 0.f, aAy = 0.f, aAz = 0.f, aAw = 0.f;
            float aBx = 0.f, aBy = 0.f, aBz = 0.f, aBw = 0.f;
#pragma unroll
            for (int jq = 0; jq < 16; ++jq) {
                const float4 q4 = *(const float4*)&qr[jq * 4];
                aAx += q4.x * bqA[jq].x; aAy += q4.y * bqA[jq].y;
                aAz += q4.z * bqA[jq].z; aAw += q4.w * bqA[jq].w;
                aBx += q4.x * bqB[jq].x; aBy += q4.y * bqB[jq].y;
                aBz += q4.z * bqB[jq].z; aBw += q4.w * bqB[jq].w;
            }
            float aA = (aAx + aAy) + (aAz + aAw);
            float aB = (aBx + aBy) + (aBz + aBw);
            float mA = aA, mB = aB;
            mA = fmaxf(mA, __shfl_xor(mA, 1, 64));
            mA = fmaxf(mA, __shfl_xor(mA, 2, 64));
            mA = fmaxf(mA, __shfl_xor(mA, 4, 64));
            mA = fmaxf(mA, __shfl_xor(mA, 8, 64));
            mB = fmaxf(mB, __shfl_xor(mB, 1, 64));
            mB = fmaxf(mB, __shfl_xor(mB, 2, 64));
            mB = fmaxf(mB, __shfl_xor(mB, 4, 64));
            mB = fmaxf(mB, __shfl_xor(mB, 8, 64));
            float eA = __expf(aA - mA), eB = __expf(aB - mB);
            float SA = eA, SB = eB;
            SA += __shfl_xor(SA, 1, 64);
            SA += __shfl_xor(SA, 2, 64);
            SA += __shfl_xor(SA, 4, 64);
            SA += __shfl_xor(SA, 8, 64);
            SB += __shfl_xor(SB, 1, 64);
            SB += __shfl_xor(SB, 2, 64);
            SB += __shfl_xor(SB, 4, 64);
            SB += __shfl_xor(SB, 8, 64);
            const float ph = pdf_s[hb * 4 + hh];
            pikA += ph * eA / SA;
            pikB += ph * eB / SB;
        }
        if (hb1 < HDIM) {
            asm volatile("s_waitcnt vmcnt(0)" ::: "memory");
            bar_lds();
#pragma unroll
            for (int j = 0; j < 4; ++j) {
                const int idx = tid + j * 256;
                const int hh = idx >> 8, rem = idx & 255;
                if (hb1 + hh < HDIM)
                    *(float4*)&qt[nxt][(hh * KDIM + (rem >> 4)) * 68 + (rem & 15) * 4] = pre[j];
            }
            bar_lds();
        }
    }
    if (tc < nt)
        out_pi[(((size_t)(t0 + tc)) * NDIM + n) * KDIM + kk] = pikA;
    if (tc + 16 < nt)
        out_pi[(((size_t)(t0 + tc + 16)) * NDIM + n) * KDIM + kk] = pikB;
}

// ------- tier-3 fallback: fused VI+policy (no extra ws) -------
__global__ __launch_bounds__(512) void vi_policy_kernel(
    const float* __restrict__ theta, const float* __restrict__ lse,
    const float* __restrict__ rws, const float* __restrict__ pdfg,
    const float* __restrict__ out_b_g, float* __restrict__ out_pi)
{
    __shared__ __align__(16) float q_s[HDIM * KDIM * 68];
    __shared__ float r_s[KDIM * SDIM];
    __shared__ float lse_s[KDIM * SDIM];
    __shared__ __align__(16) float v_s[SDIM];
    __shared__ __align__(16) float b_lds[64 * 68];
    __shared__ float pdf_s[32];

    const int n = blockIdx.x, tid = threadIdx.x;
    const int wave = tid >> 6, lane = tid & 63;
    const int sub = lane & 15, rq = lane >> 4;
    const float* Xn = theta + (size_t)n * NP + 4096;

    for (int idx = tid; idx < KDIM * SDIM; idx += 512) {
        r_s[idx]   = rws[(size_t)n * KDIM * SDIM + idx];
        lse_s[idx] = lse[(size_t)n * KDIM * SDIM + idx];
    }
    if (tid < HDIM) pdf_s[tid] = pdfg[n * HDIM + tid];
    __syncthreads();

    for (int idx = tid; idx < KDIM * SDIM; idx += 512)
        q_s[(idx >> 6) * 68 + (idx & 63)] = r_s[idx];

    float4 breg[32];
#pragma unroll
    for (int it = 0; it < 32; ++it) {
        const int row = it * 32 + wave * 4 + rq;
        const float* xr = Xn + (size_t)row * SDIM + sub * 4;
        const float l = lse_s[row];
        breg[it] = make_float4(__expf(xr[0] - l), __expf(xr[1] - l),
                               __expf(xr[2] - l), __expf(xr[3] - l));
    }
    bar_lds();

#pragma unroll 1
    for (int h = 1; h < HDIM; ++h) {
        if (tid < SDIM) {
            const int base = (h - 1) * KDIM;
            float m = -1e30f;
#pragma unroll
            for (int k = 0; k < KDIM; ++k) m = fmaxf(m, q_s[(base + k) * 68 + tid]);
            float ssum = 0.f;
#pragma unroll
            for (int k = 0; k < KDIM; ++k) ssum += __expf(q_s[(base + k) * 68 + tid] - m);
            v_s[tid] = m + __logf(ssum);
        }
        bar_lds();
        const float4 v4 = *(const float4*)&v_s[sub * 4];
#pragma unroll
        for (int it = 0; it < 32; ++it) {
            const int row = it * 32 + wave * 4 + rq;
            float acc = breg[it].x * v4.x + breg[it].y * v4.y
                      + breg[it].z * v4.z + breg[it].w * v4.w;
            acc += __shfl_xor(acc, 1, 64);
            acc += __shfl_xor(acc, 2, 64);
            acc += __shfl_xor(acc, 4, 64);
            acc += __shfl_xor(acc, 8, 64);
            if (sub == 0)
                q_s[(h * KDIM + (row >> 6)) * 68 + (row & 63)] = r_s[row] + acc;
        }
        bar_lds();
    }

    const int tc = tid >> 4, kk = tid & 15;
#pragma unroll 1
    for (int t0 = 0; t0 < TDIM; t0 += 64) {
        const int nt = (TDIM - t0) < 64 ? (TDIM - t0) : 64;
        for (int idx = tid; idx < nt * 16; idx += 512) {
            const int row = idx >> 4, jq = idx & 15;
            *(float4*)&b_lds[row * 68 + jq * 4] =
                *(const float4*)&out_b_g[(((size_t)(t0 + row)) * NDIM + n) * SDIM + jq * 4];
        }
        bar_lds();
        const bool vA = tc < nt, vB = (tc + 32) < nt;
        float4 bqA[16], bqB[16];
        if (vA) {
#pragma unroll
            for (int jq = 0; jq < 16; ++jq)
                bqA[jq] = *(const float4*)&b_lds[tc * 68 + jq * 4];
        }
        if (vB) {
#pragma unroll
            for (int jq = 0; jq < 16; ++jq)
                bqB[jq] = *(const float4*)&b_lds[(tc + 32) * 68 + jq * 4];
        }
        float pikA = 0.f, pikB = 0.f;
#pragma unroll 1
        for (int h = 0; h < HDIM; ++h) {
            const float* qr = &q_s[(h * KDIM + kk) * 68];
            float aA = 0.f, aB = 0.f;
#pragma unroll
            for (int jq = 0; jq < 16; ++jq) {
                const float4 qv = *(const float4*)&qr[jq * 4];
                if (vA) aA += qv.x * bqA[jq].x + qv.y * bqA[jq].y
                            + qv.z * bqA[jq].z + qv.w * bqA[jq].w;
                if (vB) aB += qv.x * bqB[jq].x + qv.y * bqB[jq].y
                            + qv.z * bqB[jq].z + qv.w * bqB[jq].w;
            }
            float mA = aA, mB = aB;
            mA = fmaxf(mA, __shfl_xor(mA, 1, 64));
            mA = fmaxf(mA, __shfl_xor(mA, 2, 64));
            mA = fmaxf(mA, __shfl_xor(mA, 4, 64));
            mA = fmaxf(mA, __shfl_xor(mA, 8, 64));
            mB = fmaxf(mB, __shfl_xor(mB, 1, 64));
            mB = fmaxf(mB, __shfl_xor(mB, 2, 64));
            mB = fmaxf(mB, __shfl_xor(mB, 4, 64));
            mB = fmaxf(mB, __shfl_xor(mB, 8, 64));
            float eA = __expf(aA - mA), eB = __expf(aB - mB);
            float SA = eA, SB = eB;
            SA += __shfl_xor(SA, 1, 64);
            SA += __shfl_xor(SA, 2, 64);
            SA += __shfl_xor(SA, 4, 64);
            SA += __shfl_xor(SA, 8, 64);
            SB += __shfl_xor(SB, 1, 64);
            SB += __shfl_xor(SB, 2, 64);
            SB += __shfl_xor(SB, 4, 64);
            SB += __shfl_xor(SB, 8, 64);
            const float ph = pdf_s[h];
            pikA += ph * eA / SA;
            pikB += ph * eB / SB;
        }
        if (vA) out_pi[(((size_t)(t0 + tc)) * NDIM + n) * KDIM + kk] = pikA;
        if (vB) out_pi[(((size_t)(t0 + 32 + tc)) * NDIM + n) * KDIM + kk] = pikB;
        bar_lds();
    }
}

extern "C" void kernel_launch(void* const* d_in, const int* in_sizes, int n_in,
                              void* d_out, int out_size, void* d_ws, size_t ws_size,
                              hipStream_t stream) {
    (void)in_sizes; (void)n_in; (void)out_size;
    const float* o     = (const float*)d_in[0];
    const int*   a     = (const int*)d_in[1];
    const float* theta = (const float*)d_in[2];
    float* out = (float*)d_out;
    float* ws  = (float*)d_ws;

    float* lse    = ws;                                   // N*K*S
    float* rws    = lse    + (size_t)NDIM * KDIM * SDIM;  // N*K*S
    float* invstd = rws    + (size_t)NDIM * KDIM * SDIM;  // N*S*O
    float* c0     = invstd + (size_t)NDIM * SDIM * ODIM;  // N*S
    float* ent    = c0     + (size_t)NDIM * SDIM;         // N*S
    float* logC   = ent    + (size_t)NDIM * SDIM;         // N*S
    float* Dws    = logC   + (size_t)NDIM * SDIM;         // N*S
    float* pdfws  = Dws    + (size_t)NDIM * SDIM;         // N*H
    float* q_ws   = pdfws  + (size_t)NDIM * HDIM;         // N*H*K*S f32 (63 MB)
    __hip_bfloat16* bn = (__hip_bfloat16*)(q_ws + (size_t)NDIM * HDIM * KDIM * SDIM);

    const size_t f_base = (size_t)NDIM * KDIM * SDIM * 2
                        + (size_t)NDIM * SDIM * ODIM
                        + (size_t)NDIM * SDIM * 4
                        + (size_t)NDIM * HDIM;
    const size_t f_q  = (size_t)NDIM * HDIM * KDIM * SDIM;
    const size_t need2 = (f_base + f_q) * 4;                       // ~72 MB
    const size_t need1 = need2 + (size_t)NDIM * KDIM * SDIM * SDIM * 2; // ~139 MB

    float* out_pi = out;
    float* out_b  = out + (size_t)TDIM * NDIM * KDIM;
    float* out_lp = out + (size_t)TDIM * NDIM * KDIM + (size_t)TDIM * NDIM * SDIM;

    transform_kernel<<<NDIM, 256, 0, stream>>>(theta, invstd, c0, ent, logC, Dws, pdfws);

    if (ws_size >= need1) {
        row_stats_kernel<<<(NDIM * KDIM * SDIM) / 4, 256, 0, stream>>>(
            theta, logC, ent, lse, rws, bn);
        belief_fast_kernel<<<NDIM, 512, 0, stream>>>(
            o, a, theta, bn, invstd, c0, Dws, out_b, out_lp);
        vi_kernel<<<NDIM, 512, 0, stream>>>(theta, lse, rws, q_ws);
        dim3 pgrid(7, NDIM);
        policy4_kernel<<<pgrid, 256, 0, stream>>>(q_ws, out_b, pdfws, out_pi);
    } else if (ws_size >= need2) {
        row_stats_kernel<<<(NDIM * KDIM * SDIM) / 4, 256, 0, stream>>>(
            theta, logC, ent, lse, rws, (__hip_bfloat16*)nullptr);
        belief_kernel<<<NDIM, 512, 0, stream>>>(
            o, a, theta, lse, invstd, c0, Dws, out_b, out_lp);
        vi_kernel<<<NDIM, 512, 0, stream>>>(theta, lse, rws, q_ws);
        dim3 pgrid(7, NDIM);
        policy4_kernel<<<pgrid, 256, 0, stream>>>(q_ws, out_b, pdfws, out_pi);
    } else {
        row_stats_kernel<<<(NDIM * KDIM * SDIM) / 4, 256, 0, stream>>>(
            theta, logC, ent, lse, rws, (__hip_bfloat16*)nullptr);
        belief_kernel<<<NDIM, 512, 0, stream>>>(
            o, a, theta, lse, invstd, c0, Dws, out_b, out_lp);
        vi_policy_kernel<<<NDIM, 512, 0, stream>>>(theta, lse, rws, pdfws, out_b, out_pi);
    }
}

// Round 11
// 758.688 us; speedup vs baseline: 1.5211x; 1.4049x over previous
//
#include <hip/hip_runtime.h>
#include <hip/hip_bf16.h>
#include <math.h>

#define SDIM 64
#define KDIM 16
#define ODIM 32
#define HDIM 30
#define TDIM 200
#define NDIM 512
#define NP 69761
#define EPSV 1e-6f
#define LOG2PIF 1.8378770664093453f

__device__ __forceinline__ float softplusf(float x) {
    return (x > 0.f) ? x + log1pf(expf(-x)) : log1pf(expf(x));
}
__device__ __forceinline__ float wave_max64(float v) {
#pragma unroll
    for (int off = 32; off; off >>= 1) v = fmaxf(v, __shfl_xor(v, off, 64));
    return v;
}
__device__ __forceinline__ float wave_sum64(float v) {
#pragma unroll
    for (int off = 32; off; off >>= 1) v += __shfl_xor(v, off, 64);
    return v;
}
// barrier that waits only on LDS ops — leaves global loads/stores in flight
__device__ __forceinline__ void bar_lds() {
    asm volatile("s_waitcnt lgkmcnt(0)\n\ts_barrier" ::: "memory");
}

// ---------------- kernel 1: per-n parameter transforms ----------------
__global__ __launch_bounds__(256) void transform_kernel(
    const float* __restrict__ theta, float* __restrict__ invstd,
    float* __restrict__ c0, float* __restrict__ ent,
    float* __restrict__ logC, float* __restrict__ Dws,
    float* __restrict__ pdfws)
{
    __shared__ float ls[SDIM * 33];
    const int n = blockIdx.x, tid = threadIdx.x;
    const float* thn = theta + (size_t)n * NP;

    for (int idx = tid; idx < SDIM * ODIM; idx += 256) {
        float x = thn[2048 + idx];
        float sp = softplusf(x) + EPSV;            // A_std
        invstd[(size_t)n * SDIM * ODIM + idx] = 1.f / sp;
        int s = idx >> 5, oo = idx & 31;
        ls[s * 33 + oo] = logf(sp);
    }
    __syncthreads();

    const int wave = tid >> 6, lane = tid & 63;
    if (wave == 0) {                                // c0, ent per state s
        float sum = 0.f;
#pragma unroll
        for (int oo = 0; oo < ODIM; ++oo) sum += ls[lane * 33 + oo];
        c0[n * SDIM + lane]  = -sum - 16.f * LOG2PIF;
        ent[n * SDIM + lane] =  sum + 32.f * (0.5f + 0.5f * LOG2PIF);
    } else if (wave == 1) {                         // log(C + eps)
        float x = thn[69632 + lane];
        float m = wave_max64(x);
        float e = expf(x - m);
        float ssum = wave_sum64(e);
        logC[n * SDIM + lane] = logf(e / ssum + EPSV);
    } else if (wave == 2) {                         // D = softmax(tD)
        float x = thn[69696 + lane];
        float m = wave_max64(x);
        float e = expf(x - m);
        float ssum = wave_sum64(e);
        Dws[n * SDIM + lane] = e / ssum;
    } else {                                        // truncated poisson pdf
        float tt = thn[69760];
        float tau = 60.f / (1.f + expf(-tt)) + 1.f;
        float p = 0.f;
        if (lane < HDIM)
            p = expf((float)lane * logf(tau) - tau - lgammaf((float)lane + 1.f));
        float ssum = wave_sum64(p);
        if (lane < HDIM) pdfws[n * HDIM + lane] = p / ssum;
    }
}

// ---- kernel 2: per-row B softmax stats + reward; optional packed bf16 B ----
// bn packed-pair row-major: uint idx (k*2048 + (i>>1)*64 + j) holds
// {lo = bf16 B[k][i_even][j], hi = bf16 B[k][i_odd][j]} — loads coalesce over j.
__global__ __launch_bounds__(256) void row_stats_kernel(
    const float* __restrict__ theta, const float* __restrict__ logC,
    const float* __restrict__ ent, float* __restrict__ lse,
    float* __restrict__ rws, __hip_bfloat16* __restrict__ bn)
{
    const int gw = blockIdx.x * 4 + (threadIdx.x >> 6);  // global row (n,k,i)
    const int lane = threadIdx.x & 63;
    const int n = gw >> 10, rl = gw & 1023;
    float x = theta[(size_t)n * NP + 4096 + (size_t)rl * 64 + lane];
    float m = wave_max64(x);
    float e = expf(x - m);
    float ssum = wave_sum64(e);
    float Bj = e / ssum;
    if (bn) {
        const int k = rl >> 6, i = rl & 63;
        __hip_bfloat16 h = __float2bfloat16(Bj);
        unsigned short bits;
        __builtin_memcpy(&bits, &h, 2);
        ((unsigned short*)bn)[(size_t)n * KDIM * SDIM * SDIM
            + (size_t)k * 4096 + (size_t)(i >> 1) * 128 + lane * 2 + (i & 1)] = bits;
    }
    float contrib = Bj * (logf(Bj + EPSV) - logC[n * SDIM + lane] + ent[n * SDIM + lane]);
    contrib = wave_sum64(contrib);
    if (lane == 0) {
        lse[gw] = m + logf(ssum);
        rws[gw] = -contrib;
    }
}

// z2 partial for step TT_ into buffer BUF_ (waves 1..4, 8 obs each)
#define Z2PART(TT_, BUF_) do {                                                 \
    const int ob_ = (wave - 1) * 8;                                            \
    const float* om_ = &o_s[(TT_) * ODIM + ob_];                               \
    float zz_ = 0.f;                                                           \
    _Pragma("unroll")                                                          \
    for (int j_ = 0; j_ < 8; ++j_) {                                           \
        float z_ = (om_[j_] - mean_s[lane * 33 + ob_ + j_])                    \
                 * istd_s[lane * 33 + ob_ + j_];                               \
        zz_ += z_ * z_;                                                        \
    }                                                                          \
    z2p_s[BUF_][wave - 1][lane] = zz_;                                         \
} while (0)

// ===================== TIER-1 belief: packed bf16 B + softmax-free step =====================
// one step; U_ = 5 packed uints holding bf16 B row-pairs for step T_+1
#define BSTEPF(T_, U_) do {                                                    \
    const int cur_ = (T_) & 1, nxt_ = cur_ ^ 1;                                \
    float ecz_ = 0.f, cm_ = 0.f;                                               \
    if (wave >= 1) {                                                           \
        float aA_ = 0.f, aB_ = 0.f;                                            \
        _Pragma("unroll")                                                      \
        for (int ii = 0; ii < 10; ii += 2) {                                   \
            if (ii < nrow)     aA_ += er[ii]     * b_bc[cur_][rbase + ii];     \
            if (ii + 1 < nrow) aB_ += er[ii + 1] * b_bc[cur_][rbase + ii + 1]; \
        }                                                                      \
        part_s[wave - 1][lane] = aA_ + aB_;                                    \
        if (wave == 6) out_b[((size_t)(T_) * NDIM + n) * SDIM + lane] = b_bc[cur_][lane]; \
    } else {                                                                   \
        float z2_ = z2p_s[cur_][0][lane] + z2p_s[cur_][1][lane]                \
                  + z2p_s[cur_][2][lane] + z2p_s[cur_][3][lane];               \
        float c_ = c0_r - 0.5f * z2_;                                          \
        cm_ = wave_max64(c_);                                                  \
        ecz_ = __expf(c_ - cm_);                                               \
    }                                                                          \
    bar_lds();  /* A: parts ready */                                           \
    if (wave == 0) {                                                           \
        float sv_ = part_s[0][lane] + part_s[1][lane] + part_s[2][lane]        \
                  + part_s[3][lane] + part_s[4][lane] + part_s[5][lane]        \
                  + part_s[6][lane];                                           \
        float u_ = (sv_ + EPSV) * ecz_;                                        \
        float S_ = wave_sum64(u_);                                             \
        b_bc[nxt_][lane] = u_ / S_;                                            \
        if (lane == 0) out_lp[(size_t)(T_) * NDIM + n] = cm_ + __logf(S_);     \
    } else {                                                                   \
        if ((T_) + 1 < TDIM) {                                                 \
            _Pragma("unroll")                                                  \
            for (int m_ = 0; m_ < 5; ++m_) {                                   \
                if (2 * m_ < nrow)                                             \
                    er[2 * m_] = __uint_as_float(U_[m_] << 16);                \
                if (2 * m_ + 1 < nrow)                                         \
                    er[2 * m_ + 1] = __uint_as_float(U_[m_] & 0xffff0000u);    \
            }                                                                  \
            if (wave <= 4) Z2PART((T_) + 1, nxt_);                             \
        }                                                                      \
        const int tl_ = ((T_) + 3 < TDIM) ? (T_) + 3 : TDIM - 1;               \
        const uint* up_ = bnn32 + (size_t)a_s[tl_] * 2048 + (rbase >> 1) * 64 + lane; \
        _Pragma("unroll")                                                      \
        for (int m_ = 0; m_ < 5; ++m_)                                         \
            if (2 * m_ < nrow) U_[m_] = up_[m_ * 64];                          \
    }                                                                          \
    bar_lds();  /* B: b ready */                                               \
} while (0)

__global__ __launch_bounds__(512) void belief_fast_kernel(
    const float* __restrict__ o, const int* __restrict__ a,
    const float* __restrict__ theta, const __hip_bfloat16* __restrict__ bn,
    const float* __restrict__ invstd, const float* __restrict__ c0g,
    const float* __restrict__ Dws,
    float* __restrict__ out_b, float* __restrict__ out_lp)
{
    __shared__ float o_s[TDIM * ODIM];       // 25.6 KB
    __shared__ int   a_s[TDIM];
    __shared__ float mean_s[SDIM * 33];
    __shared__ float istd_s[SDIM * 33];
    __shared__ float c0_sh[SDIM];
    __shared__ __align__(16) float b_bc[2][SDIM];
    __shared__ float part_s[7][68];
    __shared__ float z2p_s[2][4][SDIM];

    const int n = blockIdx.x, tid = threadIdx.x;
    const int wave = tid >> 6, lane = tid & 63;
    const float* thn = theta + (size_t)n * NP;
    const uint* bnn32 = (const uint*)(bn + (size_t)n * KDIM * SDIM * SDIM);

    for (int idx = tid; idx < TDIM * ODIM; idx += 512)
        o_s[idx] = o[((size_t)(idx >> 5) * NDIM + n) * ODIM + (idx & 31)];
    if (tid < TDIM) a_s[tid] = a[tid * NDIM + n];
    for (int idx = tid; idx < SDIM * ODIM; idx += 512) {
        int s = idx >> 5, oo = idx & 31;
        mean_s[s * 33 + oo] = thn[idx];
        istd_s[s * 33 + oo] = invstd[(size_t)n * SDIM * ODIM + idx];
    }
    if (tid < SDIM) { c0_sh[tid] = c0g[n * SDIM + tid]; b_bc[0][tid] = Dws[n * SDIM + tid]; }
    __syncthreads();

    const float c0_r = (wave == 0) ? c0_sh[lane] : 0.f;
    const int rbase = (wave >= 1) ? (wave - 1) * 10 : 0;
    const int nrow  = (wave >= 1) ? ((SDIM - rbase) < 10 ? (SDIM - rbase) : 10) : 0;

    float er[10];
    uint u0[5], u1[5];
    if (wave >= 1) {
        // er <- B(a_0); u0 <- B(a_1); u1 <- B(a_2)
        const uint* p0 = bnn32 + (size_t)a_s[0] * 2048 + (rbase >> 1) * 64 + lane;
#pragma unroll
        for (int m = 0; m < 5; ++m) if (2 * m < nrow) u0[m] = p0[m * 64];
#pragma unroll
        for (int m = 0; m < 5; ++m) {
            if (2 * m < nrow)     er[2 * m]     = __uint_as_float(u0[m] << 16);
            if (2 * m + 1 < nrow) er[2 * m + 1] = __uint_as_float(u0[m] & 0xffff0000u);
        }
        const uint* p1 = bnn32 + (size_t)a_s[1] * 2048 + (rbase >> 1) * 64 + lane;
#pragma unroll
        for (int m = 0; m < 5; ++m) if (2 * m < nrow) u0[m] = p1[m * 64];
        const uint* p2 = bnn32 + (size_t)a_s[2] * 2048 + (rbase >> 1) * 64 + lane;
#pragma unroll
        for (int m = 0; m < 5; ++m) if (2 * m < nrow) u1[m] = p2[m * 64];
        if (wave <= 4) Z2PART(0, 0);
    }
    __syncthreads();

#pragma unroll 1
    for (int t = 0; t < TDIM; t += 2) {
        BSTEPF(t, u0);
        BSTEPF(t + 1, u1);
    }
}

// ===================== TIER-2 belief (round-6, f32 logits + exp) =====================
#define BSTEP(T_, RAW_) do {                                                   \
    const int cur_ = (T_) & 1, nxt_ = cur_ ^ 1;                                \
    if (wave >= 1) {                                                           \
        float acc_ = 0.f;                                                      \
        _Pragma("unroll")                                                      \
        for (int ii = 0; ii < 10; ++ii)                                        \
            if (ii < nrow) acc_ += er[ii] * b_s[cur_][rbase + ii];             \
        part_s[wave - 1][lane] = acc_;                                         \
        if (wave == 6) out_b[((size_t)(T_) * NDIM + n) * SDIM + lane] = b_s[cur_][lane]; \
    }                                                                          \
    bar_lds();                                                                 \
    if (wave == 0) {                                                           \
        float sv_ = part_s[0][lane] + part_s[1][lane] + part_s[2][lane]        \
                  + part_s[3][lane] + part_s[4][lane] + part_s[5][lane]        \
                  + part_s[6][lane];                                           \
        float z2_ = z2p_s[cur_][0][lane] + z2p_s[cur_][1][lane]                \
                  + z2p_s[cur_][2][lane] + z2p_s[cur_][3][lane];               \
        float joint_ = __logf(sv_ + EPSV) + c0_s[lane] - 0.5f * z2_;           \
        float m_ = wave_max64(joint_);                                         \
        float e_ = __expf(joint_ - m_);                                        \
        float ss_ = wave_sum64(e_);                                            \
        b_s[nxt_][lane] = e_ / ss_;                                            \
        if (lane == 0) out_lp[(size_t)(T_) * NDIM + n] = m_ + __logf(ss_);     \
    } else {                                                                   \
        if ((T_) + 1 < TDIM) {                                                 \
            const int an_ = a_s[(T_) + 1];                                     \
            const float* ln_ = lseA + an_ * SDIM;                              \
            _Pragma("unroll")                                                  \
            for (int ii = 0; ii < 10; ++ii)                                    \
                if (ii < nrow) er[ii] = __expf(RAW_[ii] - ln_[rbase + ii]);    \
            if (wave <= 4) Z2PART((T_) + 1, nxt_);                             \
        }                                                                      \
        const int tl_ = ((T_) + 3 < TDIM) ? (T_) + 3 : TDIM - 1;               \
        const int a3_ = a_s[tl_];                                              \
        const float* X3_ = Xn + (size_t)a3_ * SDIM * SDIM;                     \
        _Pragma("unroll")                                                      \
        for (int ii = 0; ii < 10; ++ii)                                        \
            if (ii < nrow) RAW_[ii] = X3_[(size_t)(rbase + ii) * SDIM + lane]; \
    }                                                                          \
    bar_lds();                                                                 \
} while (0)

__global__ __launch_bounds__(512) void belief_kernel(
    const float* __restrict__ o, const int* __restrict__ a,
    const float* __restrict__ theta, const float* __restrict__ lse,
    const float* __restrict__ invstd, const float* __restrict__ c0g,
    const float* __restrict__ Dws,
    float* __restrict__ out_b, float* __restrict__ out_lp)
{
    __shared__ float o_s[TDIM * ODIM];
    __shared__ int   a_s[TDIM];
    __shared__ float mean_s[SDIM * 33];
    __shared__ float istd_s[SDIM * 33];
    __shared__ float lseA[KDIM * SDIM];
    __shared__ float c0_s[SDIM];
    __shared__ float b_s[2][SDIM];
    __shared__ float part_s[7][68];
    __shared__ float z2p_s[2][4][SDIM];

    const int n = blockIdx.x, tid = threadIdx.x;
    const int wave = tid >> 6, lane = tid & 63;
    const float* thn = theta + (size_t)n * NP;
    const float* Xn  = thn + 4096;

    for (int idx = tid; idx < TDIM * ODIM; idx += 512)
        o_s[idx] = o[((size_t)(idx >> 5) * NDIM + n) * ODIM + (idx & 31)];
    if (tid < TDIM) a_s[tid] = a[tid * NDIM + n];
    for (int idx = tid; idx < SDIM * ODIM; idx += 512) {
        int s = idx >> 5, oo = idx & 31;
        mean_s[s * 33 + oo] = thn[idx];
        istd_s[s * 33 + oo] = invstd[(size_t)n * SDIM * ODIM + idx];
    }
    for (int idx = tid; idx < KDIM * SDIM; idx += 512)
        lseA[idx] = lse[(size_t)n * KDIM * SDIM + idx];
    if (tid < SDIM) { c0_s[tid] = c0g[n * SDIM + tid]; b_s[0][tid] = Dws[n * SDIM + tid]; }
    __syncthreads();

    const int rbase = (wave >= 1) ? (wave - 1) * 10 : 0;
    const int nrow  = (wave >= 1) ? ((SDIM - rbase) < 10 ? (SDIM - rbase) : 10) : 0;

    float er[10], raw0[10], raw1[10];
    if (wave >= 1) {
        const int a0 = a_s[0];
        const float* X0 = Xn + (size_t)a0 * SDIM * SDIM;
        const float* l0 = lseA + a0 * SDIM;
#pragma unroll
        for (int ii = 0; ii < 10; ++ii)
            if (ii < nrow) er[ii] = __expf(X0[(size_t)(rbase + ii) * SDIM + lane] - l0[rbase + ii]);
        const int a1 = a_s[1];
        const float* X1 = Xn + (size_t)a1 * SDIM * SDIM;
#pragma unroll
        for (int ii = 0; ii < 10; ++ii)
            if (ii < nrow) raw0[ii] = X1[(size_t)(rbase + ii) * SDIM + lane];
        const int a2 = a_s[2];
        const float* X2 = Xn + (size_t)a2 * SDIM * SDIM;
#pragma unroll
        for (int ii = 0; ii < 10; ++ii)
            if (ii < nrow) raw1[ii] = X2[(size_t)(rbase + ii) * SDIM + lane];
        if (wave <= 4) Z2PART(0, 0);
    }
    __syncthreads();

#pragma unroll 1
    for (int t = 0; t < TDIM; t += 2) {
        BSTEP(t, raw0);
        BSTEP(t + 1, raw1);
    }
}

// ------- VI: thread-owns-row, q streamed to global workspace -------
__global__ __launch_bounds__(512) void vi_kernel(
    const float* __restrict__ theta, const float* __restrict__ lse,
    const float* __restrict__ rws, float* __restrict__ q_ws)
{
    __shared__ float q_lds[KDIM * 68];
    __shared__ __align__(16) float v_lds[68];
    const int n = blockIdx.x, tid = threadIdx.x;
    const float* Xn = theta + (size_t)n * NP + 4096;

    const float l0  = lse[(size_t)n * 1024 + tid];
    const float l1  = lse[(size_t)n * 1024 + 512 + tid];
    const float rr0 = rws[(size_t)n * 1024 + tid];
    const float rr1 = rws[(size_t)n * 1024 + 512 + tid];

    float4 er0[16], er1[16];
    {
        const float* X0 = Xn + (size_t)tid * 64;
        const float* X1 = Xn + (size_t)(512 + tid) * 64;
#pragma unroll
        for (int j = 0; j < 16; ++j) {
            float4 x = *(const float4*)(X0 + j * 4);
            er0[j] = make_float4(__expf(x.x - l0), __expf(x.y - l0),
                                 __expf(x.z - l0), __expf(x.w - l0));
            float4 y = *(const float4*)(X1 + j * 4);
            er1[j] = make_float4(__expf(y.x - l1), __expf(y.y - l1),
                                 __expf(y.z - l1), __expf(y.w - l1));
        }
    }

    float qr0 = rr0, qr1 = rr1;
    float* qw = q_ws + (size_t)n * HDIM * 1024;
    const int kq0 = tid >> 6, iq = tid & 63;
    qw[tid] = qr0;
    qw[512 + tid] = qr1;
    q_lds[kq0 * 68 + iq] = qr0;
    q_lds[(8 + kq0) * 68 + iq] = qr1;
    __syncthreads();

#pragma unroll 1
    for (int h = 1; h < HDIM; ++h) {
        if (tid < 64) {
            float m = -1e30f;
#pragma unroll
            for (int k = 0; k < KDIM; ++k) m = fmaxf(m, q_lds[k * 68 + tid]);
            float s = 0.f;
#pragma unroll
            for (int k = 0; k < KDIM; ++k) s += __expf(q_lds[k * 68 + tid] - m);
            v_lds[tid] = m + __logf(s);
        }
        bar_lds();
        float a0x = 0.f, a0y = 0.f, a0z = 0.f, a0w = 0.f;
        float a1x = 0.f, a1y = 0.f, a1z = 0.f, a1w = 0.f;
#pragma unroll
        for (int jq = 0; jq < 16; ++jq) {
            const float4 v4 = *(const float4*)&v_lds[jq * 4];
            a0x += er0[jq].x * v4.x; a0y += er0[jq].y * v4.y;
            a0z += er0[jq].z * v4.z; a0w += er0[jq].w * v4.w;
            a1x += er1[jq].x * v4.x; a1y += er1[jq].y * v4.y;
            a1z += er1[jq].z * v4.z; a1w += er1[jq].w * v4.w;
        }
        qr0 = rr0 + ((a0x + a0y) + (a0z + a0w));
        qr1 = rr1 + ((a1x + a1y) + (a1z + a1w));
        qw[(size_t)h * 1024 + tid] = qr0;
        qw[(size_t)h * 1024 + 512 + tid] = qr1;
        q_lds[kq0 * 68 + iq] = qr0;
        q_lds[(8 + kq0) * 68 + iq] = qr1;
        bar_lds();
    }
}

// ------- policy: 4-h LDS tiles, double-buffered, 16 barriers total -------
__global__ __launch_bounds__(256) void policy4_kernel(
    const float* __restrict__ q_ws, const float* __restrict__ out_b_g,
    const float* __restrict__ pdfg, float* __restrict__ out_pi)
{
    __shared__ __align__(16) float qt[2][4 * KDIM * 68];   // 34.8 KB
    __shared__ __align__(16) float bt[32 * 68];            // 8.7 KB
    __shared__ float pdf_s[32];

    const int tch = blockIdx.x, n = blockIdx.y, tid = threadIdx.x;
    const int t0 = tch * 32;
    const int nt = (TDIM - t0) < 32 ? (TDIM - t0) : 32;
    const int tc = tid >> 4, kk = tid & 15;
    const float* qn = q_ws + (size_t)n * HDIM * 1024;

    for (int idx = tid; idx < 32 * 16; idx += 256) {
        const int row = idx >> 4, jq = idx & 15;
        float4 bv = make_float4(0.f, 0.f, 0.f, 0.f);
        if (row < nt)
            bv = *(const float4*)&out_b_g[(((size_t)(t0 + row)) * NDIM + n) * SDIM + jq * 4];
        *(float4*)&bt[row * 68 + jq * 4] = bv;
    }
    if (tid < 32) pdf_s[tid] = (tid < HDIM) ? pdfg[n * HDIM + tid] : 0.f;
    // stage h-block 0 (h = 0..3)
    {
#pragma unroll
        for (int j = 0; j < 4; ++j) {
            const int idx = tid + j * 256;
            const int hh = idx >> 8, rem = idx & 255;
            const float4 qv = *(const float4*)&qn[(size_t)hh * 1024 + rem * 4];
            *(float4*)&qt[0][(hh * KDIM + (rem >> 4)) * 68 + (rem & 15) * 4] = qv;
        }
    }
    __syncthreads();

    float4 bqA[16], bqB[16];
#pragma unroll
    for (int jq = 0; jq < 16; ++jq) {
        bqA[jq] = *(const float4*)&bt[tc * 68 + jq * 4];
        bqB[jq] = *(const float4*)&bt[(tc + 16) * 68 + jq * 4];
    }

    float pikA = 0.f, pikB = 0.f;
#pragma unroll 1
    for (int hb = 0; hb < 8; ++hb) {
        const int cur = hb & 1, nxt = cur ^ 1;
        const int hcount = (HDIM - hb * 4) < 4 ? (HDIM - hb * 4) : 4;
        // issue loads for next h-block into registers
        float4 pre[4];
        const int hb1 = (hb + 1) * 4;
        if (hb1 < HDIM) {
#pragma unroll
            for (int j = 0; j < 4; ++j) {
                const int idx = tid + j * 256;
                const int hh = idx >> 8, rem = idx & 255;
                if (hb1 + hh < HDIM)
                    pre[j] = *(const float4*)&qn[(size_t)(hb1 + hh) * 1024 + rem * 4];
            }
        }
        // compute current block
#pragma unroll
        for (int hh = 0; hh < 4; ++hh) {
            if (hh >= hcount) break;
            const float* qr = &qt[cur][(hh * KDIM + kk) * 68];
            float aAx = 0.f, aAy = 0.f, aAz = 0.f, aAw = 0.f;
            float aBx = 0.f, aBy = 0.f, aBz = 0.f, aBw = 0.f;
#pragma unroll
            for (int jq = 0; jq < 16; ++jq) {
                const float4 q4 = *(const float4*)&qr[jq * 4];
                aAx += q4.x * bqA[jq].x; aAy += q4.y * bqA[jq].y;
                aAz += q4.z * bqA[jq].z; aAw += q4.w * bqA[jq].w;
                aBx += q4.x * bqB[jq].x; aBy += q4.y * bqB[jq].y;
                aBz += q4.z * bqB[jq].z; aBw += q4.w * bqB[jq].w;
            }
            float aA = (aAx + aAy) + (aAz + aAw);
            float aB = (aBx + aBy) + (aBz + aBw);
            float mA = aA, mB = aB;
            mA = fmaxf(mA, __shfl_xor(mA, 1, 64));
            mA = fmaxf(mA, __shfl_xor(mA, 2, 64));
            mA = fmaxf(mA, __shfl_xor(mA, 4, 64));
            mA = fmaxf(mA, __shfl_xor(mA, 8, 64));
            mB = fmaxf(mB, __shfl_xor(mB, 1, 64));
            mB = fmaxf(mB, __shfl_xor(mB, 2, 64));
            mB = fmaxf(mB, __shfl_xor(mB, 4, 64));
            mB = fmaxf(mB, __shfl_xor(mB, 8, 64));
            float eA = __expf(aA - mA), eB = __expf(aB - mB);
            float SA = eA, SB = eB;
            SA += __shfl_xor(SA, 1, 64);
            SA += __shfl_xor(SA, 2, 64);
            SA += __shfl_xor(SA, 4, 64);
            SA += __shfl_xor(SA, 8, 64);
            SB += __shfl_xor(SB, 1, 64);
            SB += __shfl_xor(SB, 2, 64);
            SB += __shfl_xor(SB, 4, 64);
            SB += __shfl_xor(SB, 8, 64);
            const float ph = pdf_s[hb * 4 + hh];
            pikA += ph * eA / SA;
            pikB += ph * eB / SB;
        }
        if (hb1 < HDIM) {
            asm volatile("s_waitcnt vmcnt(0)" ::: "memory");
            bar_lds();
#pragma unroll
            for (int j = 0; j < 4; ++j) {
                const int idx = tid + j * 256;
                const int hh = idx >> 8, rem = idx & 255;
                if (hb1 + hh < HDIM)
                    *(float4*)&qt[nxt][(hh * KDIM + (rem >> 4)) * 68 + (rem & 15) * 4] = pre[j];
            }
            bar_lds();
        }
    }
    if (tc < nt)
        out_pi[(((size_t)(t0 + tc)) * NDIM + n) * KDIM + kk] = pikA;
    if (tc + 16 < nt)
        out_pi[(((size_t)(t0 + tc + 16)) * NDIM + n) * KDIM + kk] = pikB;
}

// ------- tier-3 fallback: fused VI+policy (no extra ws) -------
__global__ __launch_bounds__(512) void vi_policy_kernel(
    const float* __restrict__ theta, const float* __restrict__ lse,
    const float* __restrict__ rws, const float* __restrict__ pdfg,
    const float* __restrict__ out_b_g, float* __restrict__ out_pi)
{
    __shared__ __align__(16) float q_s[HDIM * KDIM * 68];
    __shared__ float r_s[KDIM * SDIM];
    __shared__ float lse_s[KDIM * SDIM];
    __shared__ __align__(16) float v_s[SDIM];
    __shared__ __align__(16) float b_lds[64 * 68];
    __shared__ float pdf_s[32];

    const int n = blockIdx.x, tid = threadIdx.x;
    const int wave = tid >> 6, lane = tid & 63;
    const int sub = lane & 15, rq = lane >> 4;
    const float* Xn = theta + (size_t)n * NP + 4096;

    for (int idx = tid; idx < KDIM * SDIM; idx += 512) {
        r_s[idx]   = rws[(size_t)n * KDIM * SDIM + idx];
        lse_s[idx] = lse[(size_t)n * KDIM * SDIM + idx];
    }
    if (tid < HDIM) pdf_s[tid] = pdfg[n * HDIM + tid];
    __syncthreads();

    for (int idx = tid; idx < KDIM * SDIM; idx += 512)
        q_s[(idx >> 6) * 68 + (idx & 63)] = r_s[idx];

    float4 breg[32];
#pragma unroll
    for (int it = 0; it < 32; ++it) {
        const int row = it * 32 + wave * 4 + rq;
        const float* xr = Xn + (size_t)row * SDIM + sub * 4;
        const float l = lse_s[row];
        breg[it] = make_float4(__expf(xr[0] - l), __expf(xr[1] - l),
                               __expf(xr[2] - l), __expf(xr[3] - l));
    }
    bar_lds();

#pragma unroll 1
    for (int h = 1; h < HDIM; ++h) {
        if (tid < SDIM) {
            const int base = (h - 1) * KDIM;
            float m = -1e30f;
#pragma unroll
            for (int k = 0; k < KDIM; ++k) m = fmaxf(m, q_s[(base + k) * 68 + tid]);
            float ssum = 0.f;
#pragma unroll
            for (int k = 0; k < KDIM; ++k) ssum += __expf(q_s[(base + k) * 68 + tid] - m);
            v_s[tid] = m + __logf(ssum);
        }
        bar_lds();
        const float4 v4 = *(const float4*)&v_s[sub * 4];
#pragma unroll
        for (int it = 0; it < 32; ++it) {
            const int row = it * 32 + wave * 4 + rq;
            float acc = breg[it].x * v4.x + breg[it].y * v4.y
                      + breg[it].z * v4.z + breg[it].w * v4.w;
            acc += __shfl_xor(acc, 1, 64);
            acc += __shfl_xor(acc, 2, 64);
            acc += __shfl_xor(acc, 4, 64);
            acc += __shfl_xor(acc, 8, 64);
            if (sub == 0)
                q_s[(h * KDIM + (row >> 6)) * 68 + (row & 63)] = r_s[row] + acc;
        }
        bar_lds();
    }

    const int tc = tid >> 4, kk = tid & 15;
#pragma unroll 1
    for (int t0 = 0; t0 < TDIM; t0 += 64) {
        const int nt = (TDIM - t0) < 64 ? (TDIM - t0) : 64;
        for (int idx = tid; idx < nt * 16; idx += 512) {
            const int row = idx >> 4, jq = idx & 15;
            *(float4*)&b_lds[row * 68 + jq * 4] =
                *(const float4*)&out_b_g[(((size_t)(t0 + row)) * NDIM + n) * SDIM + jq * 4];
        }
        bar_lds();
        const bool vA = tc < nt, vB = (tc + 32) < nt;
        float4 bqA[16], bqB[16];
        if (vA) {
#pragma unroll
            for (int jq = 0; jq < 16; ++jq)
                bqA[jq] = *(const float4*)&b_lds[tc * 68 + jq * 4];
        }
        if (vB) {
#pragma unroll
            for (int jq = 0; jq < 16; ++jq)
                bqB[jq] = *(const float4*)&b_lds[(tc + 32) * 68 + jq * 4];
        }
        float pikA = 0.f, pikB = 0.f;
#pragma unroll 1
        for (int h = 0; h < HDIM; ++h) {
            const float* qr = &q_s[(h * KDIM + kk) * 68];
            float aA = 0.f, aB = 0.f;
#pragma unroll
            for (int jq = 0; jq < 16; ++jq) {
                const float4 qv = *(const float4*)&qr[jq * 4];
                if (vA) aA += qv.x * bqA[jq].x + qv.y * bqA[jq].y
                            + qv.z * bqA[jq].z + qv.w * bqA[jq].w;
                if (vB) aB += qv.x * bqB[jq].x + qv.y * bqB[jq].y
                            + qv.z * bqB[jq].z + qv.w * bqB[jq].w;
            }
            float mA = aA, mB = aB;
            mA = fmaxf(mA, __shfl_xor(mA, 1, 64));
            mA = fmaxf(mA, __shfl_xor(mA, 2, 64));
            mA = fmaxf(mA, __shfl_xor(mA, 4, 64));
            mA = fmaxf(mA, __shfl_xor(mA, 8, 64));
            mB = fmaxf(mB, __shfl_xor(mB, 1, 64));
            mB = fmaxf(mB, __shfl_xor(mB, 2, 64));
            mB = fmaxf(mB, __shfl_xor(mB, 4, 64));
            mB = fmaxf(mB, __shfl_xor(mB, 8, 64));
            float eA = __expf(aA - mA), eB = __expf(aB - mB);
            float SA = eA, SB = eB;
            SA += __shfl_xor(SA, 1, 64);
            SA += __shfl_xor(SA, 2, 64);
            SA += __shfl_xor(SA, 4, 64);
            SA += __shfl_xor(SA, 8, 64);
            SB += __shfl_xor(SB, 1, 64);
            SB += __shfl_xor(SB, 2, 64);
            SB += __shfl_xor(SB, 4, 64);
            SB += __shfl_xor(SB, 8, 64);
            const float ph = pdf_s[h];
            pikA += ph * eA / SA;
            pikB += ph * eB / SB;
        }
        if (vA) out_pi[(((size_t)(t0 + tc)) * NDIM + n) * KDIM + kk] = pikA;
        if (vB) out_pi[(((size_t)(t0 + 32 + tc)) * NDIM + n) * KDIM + kk] = pikB;
        bar_lds();
    }
}

extern "C" void kernel_launch(void* const* d_in, const int* in_sizes, int n_in,
                              void* d_out, int out_size, void* d_ws, size_t ws_size,
                              hipStream_t stream) {
    (void)in_sizes; (void)n_in; (void)out_size;
    const float* o     = (const float*)d_in[0];
    const int*   a     = (const int*)d_in[1];
    const float* theta = (const float*)d_in[2];
    float* out = (float*)d_out;
    float* ws  = (float*)d_ws;

    float* lse    = ws;                                   // N*K*S
    float* rws    = lse    + (size_t)NDIM * KDIM * SDIM;  // N*K*S
    float* invstd = rws    + (size_t)NDIM * KDIM * SDIM;  // N*S*O
    float* c0     = invstd + (size_t)NDIM * SDIM * ODIM;  // N*S
    float* ent    = c0     + (size_t)NDIM * SDIM;         // N*S
    float* logC   = ent    + (size_t)NDIM * SDIM;         // N*S
    float* Dws    = logC   + (size_t)NDIM * SDIM;         // N*S
    float* pdfws  = Dws    + (size_t)NDIM * SDIM;         // N*H
    float* q_ws   = pdfws  + (size_t)NDIM * HDIM;         // N*H*K*S f32 (63 MB)
    __hip_bfloat16* bn = (__hip_bfloat16*)(q_ws + (size_t)NDIM * HDIM * KDIM * SDIM);

    const size_t f_base = (size_t)NDIM * KDIM * SDIM * 2
                        + (size_t)NDIM * SDIM * ODIM
                        + (size_t)NDIM * SDIM * 4
                        + (size_t)NDIM * HDIM;
    const size_t f_q  = (size_t)NDIM * HDIM * KDIM * SDIM;
    const size_t need2 = (f_base + f_q) * 4;                       // ~72 MB
    const size_t need1 = need2 + (size_t)NDIM * KDIM * SDIM * SDIM * 2; // ~139 MB

    float* out_pi = out;
    float* out_b  = out + (size_t)TDIM * NDIM * KDIM;
    float* out_lp = out + (size_t)TDIM * NDIM * KDIM + (size_t)TDIM * NDIM * SDIM;

    transform_kernel<<<NDIM, 256, 0, stream>>>(theta, invstd, c0, ent, logC, Dws, pdfws);

    if (ws_size >= need1) {
        row_stats_kernel<<<(NDIM * KDIM * SDIM) / 4, 256, 0, stream>>>(
            theta, logC, ent, lse, rws, bn);
        belief_fast_kernel<<<NDIM, 512, 0, stream>>>(
            o, a, theta, bn, invstd, c0, Dws, out_b, out_lp);
        vi_kernel<<<NDIM, 512, 0, stream>>>(theta, lse, rws, q_ws);
        dim3 pgrid(7, NDIM);
        policy4_kernel<<<pgrid, 256, 0, stream>>>(q_ws, out_b, pdfws, out_pi);
    } else if (ws_size >= need2) {
        row_stats_kernel<<<(NDIM * KDIM * SDIM) / 4, 256, 0, stream>>>(
            theta, logC, ent, lse, rws, (__hip_bfloat16*)nullptr);
        belief_kernel<<<NDIM, 512, 0, stream>>>(
            o, a, theta, lse, invstd, c0, Dws, out_b, out_lp);
        vi_kernel<<<NDIM, 512, 0, stream>>>(theta, lse, rws, q_ws);
        dim3 pgrid(7, NDIM);
        policy4_kernel<<<pgrid, 256, 0, stream>>>(q_ws, out_b, pdfws, out_pi);
    } else {
        row_stats_kernel<<<(NDIM * KDIM * SDIM) / 4, 256, 0, stream>>>(
            theta, logC, ent, lse, rws, (__hip_bfloat16*)nullptr);
        belief_kernel<<<NDIM, 512, 0, stream>>>(
            o, a, theta, lse, invstd, c0, Dws, out_b, out_lp);
        vi_policy_kernel<<<NDIM, 512, 0, stream>>>(theta, lse, rws, pdfws, out_b, out_pi);
    }
}

// Round 12
// 757.051 us; speedup vs baseline: 1.5244x; 1.0022x over previous
//
#include <hip/hip_runtime.h>
#include <hip/hip_bf16.h>
#include <math.h>

#define SDIM 64
#define KDIM 16
#define ODIM 32
#define HDIM 30
#define TDIM 200
#define NDIM 512
#define NP 69761
#define EPSV 1e-6f
#define LOG2PIF 1.8378770664093453f

__device__ __forceinline__ float softplusf(float x) {
    return (x > 0.f) ? x + log1pf(expf(-x)) : log1pf(expf(x));
}
__device__ __forceinline__ float wave_max64(float v) {
#pragma unroll
    for (int off = 32; off; off >>= 1) v = fmaxf(v, __shfl_xor(v, off, 64));
    return v;
}
__device__ __forceinline__ float wave_sum64(float v) {
#pragma unroll
    for (int off = 32; off; off >>= 1) v += __shfl_xor(v, off, 64);
    return v;
}
// barrier that waits only on LDS ops — leaves global loads/stores in flight
__device__ __forceinline__ void bar_lds() {
    asm volatile("s_waitcnt lgkmcnt(0)\n\ts_barrier" ::: "memory");
}

// ---------------- kernel 1: per-n parameter transforms ----------------
__global__ __launch_bounds__(256) void transform_kernel(
    const float* __restrict__ theta, float* __restrict__ invstd,
    float* __restrict__ c0, float* __restrict__ ent,
    float* __restrict__ logC, float* __restrict__ Dws,
    float* __restrict__ pdfws)
{
    __shared__ float ls[SDIM * 33];
    const int n = blockIdx.x, tid = threadIdx.x;
    const float* thn = theta + (size_t)n * NP;

    for (int idx = tid; idx < SDIM * ODIM; idx += 256) {
        float x = thn[2048 + idx];
        float sp = softplusf(x) + EPSV;            // A_std
        invstd[(size_t)n * SDIM * ODIM + idx] = 1.f / sp;
        int s = idx >> 5, oo = idx & 31;
        ls[s * 33 + oo] = logf(sp);
    }
    __syncthreads();

    const int wave = tid >> 6, lane = tid & 63;
    if (wave == 0) {                                // c0, ent per state s
        float sum = 0.f;
#pragma unroll
        for (int oo = 0; oo < ODIM; ++oo) sum += ls[lane * 33 + oo];
        c0[n * SDIM + lane]  = -sum - 16.f * LOG2PIF;
        ent[n * SDIM + lane] =  sum + 32.f * (0.5f + 0.5f * LOG2PIF);
    } else if (wave == 1) {                         // log(C + eps)
        float x = thn[69632 + lane];
        float m = wave_max64(x);
        float e = expf(x - m);
        float ssum = wave_sum64(e);
        logC[n * SDIM + lane] = logf(e / ssum + EPSV);
    } else if (wave == 2) {                         // D = softmax(tD)
        float x = thn[69696 + lane];
        float m = wave_max64(x);
        float e = expf(x - m);
        float ssum = wave_sum64(e);
        Dws[n * SDIM + lane] = e / ssum;
    } else {                                        // truncated poisson pdf
        float tt = thn[69760];
        float tau = 60.f / (1.f + expf(-tt)) + 1.f;
        float p = 0.f;
        if (lane < HDIM)
            p = expf((float)lane * logf(tau) - tau - lgammaf((float)lane + 1.f));
        float ssum = wave_sum64(p);
        if (lane < HDIM) pdfws[n * HDIM + lane] = p / ssum;
    }
}

// ---- kernel 2: per-row B softmax stats + reward; optional packed bf16 B ----
// bn packed-pair row-major: uint idx (k*2048 + (i>>1)*64 + j) holds
// {lo = bf16 B[k][i_even][j], hi = bf16 B[k][i_odd][j]} — loads coalesce over j.
__global__ __launch_bounds__(256) void row_stats_kernel(
    const float* __restrict__ theta, const float* __restrict__ logC,
    const float* __restrict__ ent, float* __restrict__ lse,
    float* __restrict__ rws, __hip_bfloat16* __restrict__ bn)
{
    const int gw = blockIdx.x * 4 + (threadIdx.x >> 6);  // global row (n,k,i)
    const int lane = threadIdx.x & 63;
    const int n = gw >> 10, rl = gw & 1023;
    float x = theta[(size_t)n * NP + 4096 + (size_t)rl * 64 + lane];
    float m = wave_max64(x);
    float e = expf(x - m);
    float ssum = wave_sum64(e);
    float Bj = e / ssum;
    if (bn) {
        const int k = rl >> 6, i = rl & 63;
        __hip_bfloat16 h = __float2bfloat16(Bj);
        unsigned short bits;
        __builtin_memcpy(&bits, &h, 2);
        ((unsigned short*)bn)[(size_t)n * KDIM * SDIM * SDIM
            + (size_t)k * 4096 + (size_t)(i >> 1) * 128 + lane * 2 + (i & 1)] = bits;
    }
    float contrib = Bj * (logf(Bj + EPSV) - logC[n * SDIM + lane] + ent[n * SDIM + lane]);
    contrib = wave_sum64(contrib);
    if (lane == 0) {
        lse[gw] = m + logf(ssum);
        rws[gw] = -contrib;
    }
}

// z2 partial for step TT_ into buffer BUF_ (waves 1..4, 8 obs each)
#define Z2PART(TT_, BUF_) do {                                                 \
    const int ob_ = (wave - 1) * 8;                                            \
    const float* om_ = &o_s[(TT_) * ODIM + ob_];                               \
    float zz_ = 0.f;                                                           \
    _Pragma("unroll")                                                          \
    for (int j_ = 0; j_ < 8; ++j_) {                                           \
        float z_ = (om_[j_] - mean_s[lane * 33 + ob_ + j_])                    \
                 * istd_s[lane * 33 + ob_ + j_];                               \
        zz_ += z_ * z_;                                                        \
    }                                                                          \
    z2p_s[BUF_][wave - 1][lane] = zz_;                                         \
} while (0)

// ===================== TIER-1 belief: packed bf16 B + softmax-free step =====================
// one step; U_ = 5 packed uints holding bf16 B row-pairs for step T_+1
#define BSTEPF(T_, U_) do {                                                    \
    const int cur_ = (T_) & 1, nxt_ = cur_ ^ 1;                                \
    float ecz_ = 0.f, cm_ = 0.f;                                               \
    if (wave >= 1) {                                                           \
        float aA_ = 0.f, aB_ = 0.f;                                            \
        _Pragma("unroll")                                                      \
        for (int ii = 0; ii < 10; ii += 2) {                                   \
            if (ii < nrow)     aA_ += er[ii]     * b_bc[cur_][rbase + ii];     \
            if (ii + 1 < nrow) aB_ += er[ii + 1] * b_bc[cur_][rbase + ii + 1]; \
        }                                                                      \
        part_s[wave - 1][lane] = aA_ + aB_;                                    \
        if (wave == 6) out_b[((size_t)(T_) * NDIM + n) * SDIM + lane] = b_bc[cur_][lane]; \
    } else {                                                                   \
        float z2_ = z2p_s[cur_][0][lane] + z2p_s[cur_][1][lane]                \
                  + z2p_s[cur_][2][lane] + z2p_s[cur_][3][lane];               \
        float c_ = c0_r - 0.5f * z2_;                                          \
        cm_ = wave_max64(c_);                                                  \
        ecz_ = __expf(c_ - cm_);                                               \
    }                                                                          \
    bar_lds();  /* A: parts ready */                                           \
    if (wave == 0) {                                                           \
        float sv_ = part_s[0][lane] + part_s[1][lane] + part_s[2][lane]        \
                  + part_s[3][lane] + part_s[4][lane] + part_s[5][lane]        \
                  + part_s[6][lane];                                           \
        float u_ = (sv_ + EPSV) * ecz_;                                        \
        float S_ = wave_sum64(u_);                                             \
        b_bc[nxt_][lane] = u_ / S_;                                            \
        if (lane == 0) out_lp[(size_t)(T_) * NDIM + n] = cm_ + __logf(S_);     \
    } else {                                                                   \
        if ((T_) + 1 < TDIM) {                                                 \
            _Pragma("unroll")                                                  \
            for (int m_ = 0; m_ < 5; ++m_) {                                   \
                if (2 * m_ < nrow)                                             \
                    er[2 * m_] = __uint_as_float(U_[m_] << 16);                \
                if (2 * m_ + 1 < nrow)                                         \
                    er[2 * m_ + 1] = __uint_as_float(U_[m_] & 0xffff0000u);    \
            }                                                                  \
            if (wave <= 4) Z2PART((T_) + 1, nxt_);                             \
        }                                                                      \
        const int tl_ = ((T_) + 3 < TDIM) ? (T_) + 3 : TDIM - 1;               \
        const uint* up_ = bnn32 + (size_t)a_s[tl_] * 2048 + (rbase >> 1) * 64 + lane; \
        _Pragma("unroll")                                                      \
        for (int m_ = 0; m_ < 5; ++m_)                                         \
            if (2 * m_ < nrow) U_[m_] = up_[m_ * 64];                          \
    }                                                                          \
    bar_lds();  /* B: b ready */                                               \
} while (0)

__global__ __launch_bounds__(512) void belief_fast_kernel(
    const float* __restrict__ o, const int* __restrict__ a,
    const float* __restrict__ theta, const __hip_bfloat16* __restrict__ bn,
    const float* __restrict__ invstd, const float* __restrict__ c0g,
    const float* __restrict__ Dws,
    float* __restrict__ out_b, float* __restrict__ out_lp)
{
    __shared__ float o_s[TDIM * ODIM];       // 25.6 KB
    __shared__ int   a_s[TDIM];
    __shared__ float mean_s[SDIM * 33];
    __shared__ float istd_s[SDIM * 33];
    __shared__ float c0_sh[SDIM];
    __shared__ __align__(16) float b_bc[2][SDIM];
    __shared__ float part_s[7][68];
    __shared__ float z2p_s[2][4][SDIM];

    const int n = blockIdx.x, tid = threadIdx.x;
    const int wave = tid >> 6, lane = tid & 63;
    const float* thn = theta + (size_t)n * NP;
    const uint* bnn32 = (const uint*)(bn + (size_t)n * KDIM * SDIM * SDIM);

    for (int idx = tid; idx < TDIM * ODIM; idx += 512)
        o_s[idx] = o[((size_t)(idx >> 5) * NDIM + n) * ODIM + (idx & 31)];
    if (tid < TDIM) a_s[tid] = a[tid * NDIM + n];
    for (int idx = tid; idx < SDIM * ODIM; idx += 512) {
        int s = idx >> 5, oo = idx & 31;
        mean_s[s * 33 + oo] = thn[idx];
        istd_s[s * 33 + oo] = invstd[(size_t)n * SDIM * ODIM + idx];
    }
    if (tid < SDIM) { c0_sh[tid] = c0g[n * SDIM + tid]; b_bc[0][tid] = Dws[n * SDIM + tid]; }
    __syncthreads();

    const float c0_r = (wave == 0) ? c0_sh[lane] : 0.f;
    const int rbase = (wave >= 1) ? (wave - 1) * 10 : 0;
    const int nrow  = (wave >= 1) ? ((SDIM - rbase) < 10 ? (SDIM - rbase) : 10) : 0;

    float er[10];
    uint u0[5], u1[5];
    if (wave >= 1) {
        // er <- B(a_0); u0 <- B(a_1); u1 <- B(a_2)
        const uint* p0 = bnn32 + (size_t)a_s[0] * 2048 + (rbase >> 1) * 64 + lane;
#pragma unroll
        for (int m = 0; m < 5; ++m) if (2 * m < nrow) u0[m] = p0[m * 64];
#pragma unroll
        for (int m = 0; m < 5; ++m) {
            if (2 * m < nrow)     er[2 * m]     = __uint_as_float(u0[m] << 16);
            if (2 * m + 1 < nrow) er[2 * m + 1] = __uint_as_float(u0[m] & 0xffff0000u);
        }
        const uint* p1 = bnn32 + (size_t)a_s[1] * 2048 + (rbase >> 1) * 64 + lane;
#pragma unroll
        for (int m = 0; m < 5; ++m) if (2 * m < nrow) u0[m] = p1[m * 64];
        const uint* p2 = bnn32 + (size_t)a_s[2] * 2048 + (rbase >> 1) * 64 + lane;
#pragma unroll
        for (int m = 0; m < 5; ++m) if (2 * m < nrow) u1[m] = p2[m * 64];
        if (wave <= 4) Z2PART(0, 0);
    }
    __syncthreads();

#pragma unroll 1
    for (int t = 0; t < TDIM; t += 2) {
        BSTEPF(t, u0);
        BSTEPF(t + 1, u1);
    }
}

// ===================== TIER-2 belief (round-6, f32 logits + exp) =====================
#define BSTEP(T_, RAW_) do {                                                   \
    const int cur_ = (T_) & 1, nxt_ = cur_ ^ 1;                                \
    if (wave >= 1) {                                                           \
        float acc_ = 0.f;                                                      \
        _Pragma("unroll")                                                      \
        for (int ii = 0; ii < 10; ++ii)                                        \
            if (ii < nrow) acc_ += er[ii] * b_s[cur_][rbase + ii];             \
        part_s[wave - 1][lane] = acc_;                                         \
        if (wave == 6) out_b[((size_t)(T_) * NDIM + n) * SDIM + lane] = b_s[cur_][lane]; \
    }                                                                          \
    bar_lds();                                                                 \
    if (wave == 0) {                                                           \
        float sv_ = part_s[0][lane] + part_s[1][lane] + part_s[2][lane]        \
                  + part_s[3][lane] + part_s[4][lane] + part_s[5][lane]        \
                  + part_s[6][lane];                                           \
        float z2_ = z2p_s[cur_][0][lane] + z2p_s[cur_][1][lane]                \
                  + z2p_s[cur_][2][lane] + z2p_s[cur_][3][lane];               \
        float joint_ = __logf(sv_ + EPSV) + c0_s[lane] - 0.5f * z2_;           \
        float m_ = wave_max64(joint_);                                         \
        float e_ = __expf(joint_ - m_);                                        \
        float ss_ = wave_sum64(e_);                                            \
        b_s[nxt_][lane] = e_ / ss_;                                            \
        if (lane == 0) out_lp[(size_t)(T_) * NDIM + n] = m_ + __logf(ss_);     \
    } else {                                                                   \
        if ((T_) + 1 < TDIM) {                                                 \
            const int an_ = a_s[(T_) + 1];                                     \
            const float* ln_ = lseA + an_ * SDIM;                              \
            _Pragma("unroll")                                                  \
            for (int ii = 0; ii < 10; ++ii)                                    \
                if (ii < nrow) er[ii] = __expf(RAW_[ii] - ln_[rbase + ii]);    \
            if (wave <= 4) Z2PART((T_) + 1, nxt_);                             \
        }                                                                      \
        const int tl_ = ((T_) + 3 < TDIM) ? (T_) + 3 : TDIM - 1;               \
        const int a3_ = a_s[tl_];                                              \
        const float* X3_ = Xn + (size_t)a3_ * SDIM * SDIM;                     \
        _Pragma("unroll")                                                      \
        for (int ii = 0; ii < 10; ++ii)                                        \
            if (ii < nrow) RAW_[ii] = X3_[(size_t)(rbase + ii) * SDIM + lane]; \
    }                                                                          \
    bar_lds();                                                                 \
} while (0)

__global__ __launch_bounds__(512) void belief_kernel(
    const float* __restrict__ o, const int* __restrict__ a,
    const float* __restrict__ theta, const float* __restrict__ lse,
    const float* __restrict__ invstd, const float* __restrict__ c0g,
    const float* __restrict__ Dws,
    float* __restrict__ out_b, float* __restrict__ out_lp)
{
    __shared__ float o_s[TDIM * ODIM];
    __shared__ int   a_s[TDIM];
    __shared__ float mean_s[SDIM * 33];
    __shared__ float istd_s[SDIM * 33];
    __shared__ float lseA[KDIM * SDIM];
    __shared__ float c0_s[SDIM];
    __shared__ float b_s[2][SDIM];
    __shared__ float part_s[7][68];
    __shared__ float z2p_s[2][4][SDIM];

    const int n = blockIdx.x, tid = threadIdx.x;
    const int wave = tid >> 6, lane = tid & 63;
    const float* thn = theta + (size_t)n * NP;
    const float* Xn  = thn + 4096;

    for (int idx = tid; idx < TDIM * ODIM; idx += 512)
        o_s[idx] = o[((size_t)(idx >> 5) * NDIM + n) * ODIM + (idx & 31)];
    if (tid < TDIM) a_s[tid] = a[tid * NDIM + n];
    for (int idx = tid; idx < SDIM * ODIM; idx += 512) {
        int s = idx >> 5, oo = idx & 31;
        mean_s[s * 33 + oo] = thn[idx];
        istd_s[s * 33 + oo] = invstd[(size_t)n * SDIM * ODIM + idx];
    }
    for (int idx = tid; idx < KDIM * SDIM; idx += 512)
        lseA[idx] = lse[(size_t)n * KDIM * SDIM + idx];
    if (tid < SDIM) { c0_s[tid] = c0g[n * SDIM + tid]; b_s[0][tid] = Dws[n * SDIM + tid]; }
    __syncthreads();

    const int rbase = (wave >= 1) ? (wave - 1) * 10 : 0;
    const int nrow  = (wave >= 1) ? ((SDIM - rbase) < 10 ? (SDIM - rbase) : 10) : 0;

    float er[10], raw0[10], raw1[10];
    if (wave >= 1) {
        const int a0 = a_s[0];
        const float* X0 = Xn + (size_t)a0 * SDIM * SDIM;
        const float* l0 = lseA + a0 * SDIM;
#pragma unroll
        for (int ii = 0; ii < 10; ++ii)
            if (ii < nrow) er[ii] = __expf(X0[(size_t)(rbase + ii) * SDIM + lane] - l0[rbase + ii]);
        const int a1 = a_s[1];
        const float* X1 = Xn + (size_t)a1 * SDIM * SDIM;
#pragma unroll
        for (int ii = 0; ii < 10; ++ii)
            if (ii < nrow) raw0[ii] = X1[(size_t)(rbase + ii) * SDIM + lane];
        const int a2 = a_s[2];
        const float* X2 = Xn + (size_t)a2 * SDIM * SDIM;
#pragma unroll
        for (int ii = 0; ii < 10; ++ii)
            if (ii < nrow) raw1[ii] = X2[(size_t)(rbase + ii) * SDIM + lane];
        if (wave <= 4) Z2PART(0, 0);
    }
    __syncthreads();

#pragma unroll 1
    for (int t = 0; t < TDIM; t += 2) {
        BSTEP(t, raw0);
        BSTEP(t + 1, raw1);
    }
}

// ------- VI: thread-owns-row, q streamed to global workspace -------
__global__ __launch_bounds__(512) void vi_kernel(
    const float* __restrict__ theta, const float* __restrict__ lse,
    const float* __restrict__ rws, float* __restrict__ q_ws)
{
    __shared__ float q_lds[KDIM * 68];
    __shared__ __align__(16) float v_lds[68];
    const int n = blockIdx.x, tid = threadIdx.x;
    const float* Xn = theta + (size_t)n * NP + 4096;

    const float l0  = lse[(size_t)n * 1024 + tid];
    const float l1  = lse[(size_t)n * 1024 + 512 + tid];
    const float rr0 = rws[(size_t)n * 1024 + tid];
    const float rr1 = rws[(size_t)n * 1024 + 512 + tid];

    float4 er0[16], er1[16];
    {
        const float* X0 = Xn + (size_t)tid * 64;
        const float* X1 = Xn + (size_t)(512 + tid) * 64;
#pragma unroll
        for (int j = 0; j < 16; ++j) {
            float4 x = *(const float4*)(X0 + j * 4);
            er0[j] = make_float4(__expf(x.x - l0), __expf(x.y - l0),
                                 __expf(x.z - l0), __expf(x.w - l0));
            float4 y = *(const float4*)(X1 + j * 4);
            er1[j] = make_float4(__expf(y.x - l1), __expf(y.y - l1),
                                 __expf(y.z - l1), __expf(y.w - l1));
        }
    }

    float qr0 = rr0, qr1 = rr1;
    float* qw = q_ws + (size_t)n * HDIM * 1024;
    const int kq0 = tid >> 6, iq = tid & 63;
    qw[tid] = qr0;
    qw[512 + tid] = qr1;
    q_lds[kq0 * 68 + iq] = qr0;
    q_lds[(8 + kq0) * 68 + iq] = qr1;
    __syncthreads();

#pragma unroll 1
    for (int h = 1; h < HDIM; ++h) {
        if (tid < 64) {
            float m = -1e30f;
#pragma unroll
            for (int k = 0; k < KDIM; ++k) m = fmaxf(m, q_lds[k * 68 + tid]);
            float s = 0.f;
#pragma unroll
            for (int k = 0; k < KDIM; ++k) s += __expf(q_lds[k * 68 + tid] - m);
            v_lds[tid] = m + __logf(s);
        }
        bar_lds();
        float a0x = 0.f, a0y = 0.f, a0z = 0.f, a0w = 0.f;
        float a1x = 0.f, a1y = 0.f, a1z = 0.f, a1w = 0.f;
#pragma unroll
        for (int jq = 0; jq < 16; ++jq) {
            const float4 v4 = *(const float4*)&v_lds[jq * 4];
            a0x += er0[jq].x * v4.x; a0y += er0[jq].y * v4.y;
            a0z += er0[jq].z * v4.z; a0w += er0[jq].w * v4.w;
            a1x += er1[jq].x * v4.x; a1y += er1[jq].y * v4.y;
            a1z += er1[jq].z * v4.z; a1w += er1[jq].w * v4.w;
        }
        qr0 = rr0 + ((a0x + a0y) + (a0z + a0w));
        qr1 = rr1 + ((a1x + a1y) + (a1z + a1w));
        qw[(size_t)h * 1024 + tid] = qr0;
        qw[(size_t)h * 1024 + 512 + tid] = qr1;
        q_lds[kq0 * 68 + iq] = qr0;
        q_lds[(8 + kq0) * 68 + iq] = qr1;
        bar_lds();
    }
}

// ------- policy: 4-h LDS tiles, double-buffered; b-tiles register-resident -------
// __launch_bounds__(256, 1): relax VGPR cap so bqA/bqB (128 VGPR) stay resident.
// grid x = n (consecutive blocks share chunk -> each q_n HBM-fetched once, L3 reuse).
__global__ __launch_bounds__(256, 1) void policy4_kernel(
    const float* __restrict__ q_ws, const float* __restrict__ out_b_g,
    const float* __restrict__ pdfg, float* __restrict__ out_pi)
{
    __shared__ __align__(16) float qt[2][4 * KDIM * 68];   // 34.8 KB
    __shared__ __align__(16) float bt[32 * 68];            // 8.7 KB
    __shared__ float pdf_s[32];

    const int n = blockIdx.x, tch = blockIdx.y, tid = threadIdx.x;
    const int t0 = tch * 32;
    const int nt = (TDIM - t0) < 32 ? (TDIM - t0) : 32;
    const int tc = tid >> 4, kk = tid & 15;
    const float* qn = q_ws + (size_t)n * HDIM * 1024;

    for (int idx = tid; idx < 32 * 16; idx += 256) {
        const int row = idx >> 4, jq = idx & 15;
        float4 bv = make_float4(0.f, 0.f, 0.f, 0.f);
        if (row < nt)
            bv = *(const float4*)&out_b_g[(((size_t)(t0 + row)) * NDIM + n) * SDIM + jq * 4];
        *(float4*)&bt[row * 68 + jq * 4] = bv;
    }
    if (tid < 32) pdf_s[tid] = (tid < HDIM) ? pdfg[n * HDIM + tid] : 0.f;
    // stage h-block 0 (h = 0..3)
    {
#pragma unroll
        for (int j = 0; j < 4; ++j) {
            const int idx = tid + j * 256;
            const int hh = idx >> 8, rem = idx & 255;
            const float4 qv = *(const float4*)&qn[(size_t)hh * 1024 + rem * 4];
            *(float4*)&qt[0][(hh * KDIM + (rem >> 4)) * 68 + (rem & 15) * 4] = qv;
        }
    }
    __syncthreads();

    float4 bqA[16], bqB[16];
#pragma unroll
    for (int jq = 0; jq < 16; ++jq) {
        bqA[jq] = *(const float4*)&bt[tc * 68 + jq * 4];
        bqB[jq] = *(const float4*)&bt[(tc + 16) * 68 + jq * 4];
    }

    float pikA = 0.f, pikB = 0.f;
#pragma unroll 1
    for (int hb = 0; hb < 8; ++hb) {
        const int cur = hb & 1, nxt = cur ^ 1;
        const int hcount = (HDIM - hb * 4) < 4 ? (HDIM - hb * 4) : 4;
        // issue loads for next h-block into registers
        float4 pre[4];
        const int hb1 = (hb + 1) * 4;
        if (hb1 < HDIM) {
#pragma unroll
            for (int j = 0; j < 4; ++j) {
                const int idx = tid + j * 256;
                const int hh = idx >> 8, rem = idx & 255;
                if (hb1 + hh < HDIM)
                    pre[j] = *(const float4*)&qn[(size_t)(hb1 + hh) * 1024 + rem * 4];
            }
        }
        // compute current block
#pragma unroll
        for (int hh = 0; hh < 4; ++hh) {
            if (hh >= hcount) break;
            const float* qr = &qt[cur][(hh * KDIM + kk) * 68];
            float aAx = 0.f, aAy = 0.f, aAz = 0.f, aAw = 0.f;
            float aBx = 0.f, aBy = 0.f, aBz = 0.f, aBw = 0.f;
#pragma unroll
            for (int jq = 0; jq < 16; ++jq) {
                const float4 q4 = *(const float4*)&qr[jq * 4];
                aAx += q4.x * bqA[jq].x; aAy += q4.y * bqA[jq].y;
                aAz += q4.z * bqA[jq].z; aAw += q4.w * bqA[jq].w;
                aBx += q4.x * bqB[jq].x; aBy += q4.y * bqB[jq].y;
                aBz += q4.z * bqB[jq].z; aBw += q4.w * bqB[jq].w;
            }
            float aA = (aAx + aAy) + (aAz + aAw);
            float aB = (aBx + aBy) + (aBz + aBw);
            float mA = aA, mB = aB;
            mA = fmaxf(mA, __shfl_xor(mA, 1, 64));
            mA = fmaxf(mA, __shfl_xor(mA, 2, 64));
            mA = fmaxf(mA, __shfl_xor(mA, 4, 64));
            mA = fmaxf(mA, __shfl_xor(mA, 8, 64));
            mB = fmaxf(mB, __shfl_xor(mB, 1, 64));
            mB = fmaxf(mB, __shfl_xor(mB, 2, 64));
            mB = fmaxf(mB, __shfl_xor(mB, 4, 64));
            mB = fmaxf(mB, __shfl_xor(mB, 8, 64));
            float eA = __expf(aA - mA), eB = __expf(aB - mB);
            float SA = eA, SB = eB;
            SA += __shfl_xor(SA, 1, 64);
            SA += __shfl_xor(SA, 2, 64);
            SA += __shfl_xor(SA, 4, 64);
            SA += __shfl_xor(SA, 8, 64);
            SB += __shfl_xor(SB, 1, 64);
            SB += __shfl_xor(SB, 2, 64);
            SB += __shfl_xor(SB, 4, 64);
            SB += __shfl_xor(SB, 8, 64);
            const float ph = pdf_s[hb * 4 + hh];
            pikA += ph * eA / SA;
            pikB += ph * eB / SB;
        }
        if (hb1 < HDIM) {
            asm volatile("s_waitcnt vmcnt(0)" ::: "memory");
            bar_lds();
#pragma unroll
            for (int j = 0; j < 4; ++j) {
                const int idx = tid + j * 256;
                const int hh = idx >> 8, rem = idx & 255;
                if (hb1 + hh < HDIM)
                    *(float4*)&qt[nxt][(hh * KDIM + (rem >> 4)) * 68 + (rem & 15) * 4] = pre[j];
            }
            bar_lds();
        }
    }
    if (tc < nt)
        out_pi[(((size_t)(t0 + tc)) * NDIM + n) * KDIM + kk] = pikA;
    if (tc + 16 < nt)
        out_pi[(((size_t)(t0 + tc + 16)) * NDIM + n) * KDIM + kk] = pikB;
}

// ------- tier-3 fallback: fused VI+policy (no extra ws) -------
__global__ __launch_bounds__(512) void vi_policy_kernel(
    const float* __restrict__ theta, const float* __restrict__ lse,
    const float* __restrict__ rws, const float* __restrict__ pdfg,
    const float* __restrict__ out_b_g, float* __restrict__ out_pi)
{
    __shared__ __align__(16) float q_s[HDIM * KDIM * 68];
    __shared__ float r_s[KDIM * SDIM];
    __shared__ float lse_s[KDIM * SDIM];
    __shared__ __align__(16) float v_s[SDIM];
    __shared__ __align__(16) float b_lds[64 * 68];
    __shared__ float pdf_s[32];

    const int n = blockIdx.x, tid = threadIdx.x;
    const int wave = tid >> 6, lane = tid & 63;
    const int sub = lane & 15, rq = lane >> 4;
    const float* Xn = theta + (size_t)n * NP + 4096;

    for (int idx = tid; idx < KDIM * SDIM; idx += 512) {
        r_s[idx]   = rws[(size_t)n * KDIM * SDIM + idx];
        lse_s[idx] = lse[(size_t)n * KDIM * SDIM + idx];
    }
    if (tid < HDIM) pdf_s[tid] = pdfg[n * HDIM + tid];
    __syncthreads();

    for (int idx = tid; idx < KDIM * SDIM; idx += 512)
        q_s[(idx >> 6) * 68 + (idx & 63)] = r_s[idx];

    float4 breg[32];
#pragma unroll
    for (int it = 0; it < 32; ++it) {
        const int row = it * 32 + wave * 4 + rq;
        const float* xr = Xn + (size_t)row * SDIM + sub * 4;
        const float l = lse_s[row];
        breg[it] = make_float4(__expf(xr[0] - l), __expf(xr[1] - l),
                               __expf(xr[2] - l), __expf(xr[3] - l));
    }
    bar_lds();

#pragma unroll 1
    for (int h = 1; h < HDIM; ++h) {
        if (tid < SDIM) {
            const int base = (h - 1) * KDIM;
            float m = -1e30f;
#pragma unroll
            for (int k = 0; k < KDIM; ++k) m = fmaxf(m, q_s[(base + k) * 68 + tid]);
            float ssum = 0.f;
#pragma unroll
            for (int k = 0; k < KDIM; ++k) ssum += __expf(q_s[(base + k) * 68 + tid] - m);
            v_s[tid] = m + __logf(ssum);
        }
        bar_lds();
        const float4 v4 = *(const float4*)&v_s[sub * 4];
#pragma unroll
        for (int it = 0; it < 32; ++it) {
            const int row = it * 32 + wave * 4 + rq;
            float acc = breg[it].x * v4.x + breg[it].y * v4.y
                      + breg[it].z * v4.z + breg[it].w * v4.w;
            acc += __shfl_xor(acc, 1, 64);
            acc += __shfl_xor(acc, 2, 64);
            acc += __shfl_xor(acc, 4, 64);
            acc += __shfl_xor(acc, 8, 64);
            if (sub == 0)
                q_s[(h * KDIM + (row >> 6)) * 68 + (row & 63)] = r_s[row] + acc;
        }
        bar_lds();
    }

    const int tc = tid >> 4, kk = tid & 15;
#pragma unroll 1
    for (int t0 = 0; t0 < TDIM; t0 += 64) {
        const int nt = (TDIM - t0) < 64 ? (TDIM - t0) : 64;
        for (int idx = tid; idx < nt * 16; idx += 512) {
            const int row = idx >> 4, jq = idx & 15;
            *(float4*)&b_lds[row * 68 + jq * 4] =
                *(const float4*)&out_b_g[(((size_t)(t0 + row)) * NDIM + n) * SDIM + jq * 4];
        }
        bar_lds();
        const bool vA = tc < nt, vB = (tc + 32) < nt;
        float4 bqA[16], bqB[16];
        if (vA) {
#pragma unroll
            for (int jq = 0; jq < 16; ++jq)
                bqA[jq] = *(const float4*)&b_lds[tc * 68 + jq * 4];
        }
        if (vB) {
#pragma unroll
            for (int jq = 0; jq < 16; ++jq)
                bqB[jq] = *(const float4*)&b_lds[(tc + 32) * 68 + jq * 4];
        }
        float pikA = 0.f, pikB = 0.f;
#pragma unroll 1
        for (int h = 0; h < HDIM; ++h) {
            const float* qr = &q_s[(h * KDIM + kk) * 68];
            float aA = 0.f, aB = 0.f;
#pragma unroll
            for (int jq = 0; jq < 16; ++jq) {
                const float4 qv = *(const float4*)&qr[jq * 4];
                if (vA) aA += qv.x * bqA[jq].x + qv.y * bqA[jq].y
                            + qv.z * bqA[jq].z + qv.w * bqA[jq].w;
                if (vB) aB += qv.x * bqB[jq].x + qv.y * bqB[jq].y
                            + qv.z * bqB[jq].z + qv.w * bqB[jq].w;
            }
            float mA = aA, mB = aB;
            mA = fmaxf(mA, __shfl_xor(mA, 1, 64));
            mA = fmaxf(mA, __shfl_xor(mA, 2, 64));
            mA = fmaxf(mA, __shfl_xor(mA, 4, 64));
            mA = fmaxf(mA, __shfl_xor(mA, 8, 64));
            mB = fmaxf(mB, __shfl_xor(mB, 1, 64));
            mB = fmaxf(mB, __shfl_xor(mB, 2, 64));
            mB = fmaxf(mB, __shfl_xor(mB, 4, 64));
            mB = fmaxf(mB, __shfl_xor(mB, 8, 64));
            float eA = __expf(aA - mA), eB = __expf(aB - mB);
            float SA = eA, SB = eB;
            SA += __shfl_xor(SA, 1, 64);
            SA += __shfl_xor(SA, 2, 64);
            SA += __shfl_xor(SA, 4, 64);
            SA += __shfl_xor(SA, 8, 64);
            SB += __shfl_xor(SB, 1, 64);
            SB += __shfl_xor(SB, 2, 64);
            SB += __shfl_xor(SB, 4, 64);
            SB += __shfl_xor(SB, 8, 64);
            const float ph = pdf_s[h];
            pikA += ph * eA / SA;
            pikB += ph * eB / SB;
        }
        if (vA) out_pi[(((size_t)(t0 + tc)) * NDIM + n) * KDIM + kk] = pikA;
        if (vB) out_pi[(((size_t)(t0 + 32 + tc)) * NDIM + n) * KDIM + kk] = pikB;
        bar_lds();
    }
}

extern "C" void kernel_launch(void* const* d_in, const int* in_sizes, int n_in,
                              void* d_out, int out_size, void* d_ws, size_t ws_size,
                              hipStream_t stream) {
    (void)in_sizes; (void)n_in; (void)out_size;
    const float* o     = (const float*)d_in[0];
    const int*   a     = (const int*)d_in[1];
    const float* theta = (const float*)d_in[2];
    float* out = (float*)d_out;
    float* ws  = (float*)d_ws;

    float* lse    = ws;                                   // N*K*S
    float* rws    = lse    + (size_t)NDIM * KDIM * SDIM;  // N*K*S
    float* invstd = rws    + (size_t)NDIM * KDIM * SDIM;  // N*S*O
    float* c0     = invstd + (size_t)NDIM * SDIM * ODIM;  // N*S
    float* ent    = c0     + (size_t)NDIM * SDIM;         // N*S
    float* logC   = ent    + (size_t)NDIM * SDIM;         // N*S
    float* Dws    = logC   + (size_t)NDIM * SDIM;         // N*S
    float* pdfws  = Dws    + (size_t)NDIM * SDIM;         // N*H
    float* q_ws   = pdfws  + (size_t)NDIM * HDIM;         // N*H*K*S f32 (63 MB)
    __hip_bfloat16* bn = (__hip_bfloat16*)(q_ws + (size_t)NDIM * HDIM * KDIM * SDIM);

    const size_t f_base = (size_t)NDIM * KDIM * SDIM * 2
                        + (size_t)NDIM * SDIM * ODIM
                        + (size_t)NDIM * SDIM * 4
                        + (size_t)NDIM * HDIM;
    const size_t f_q  = (size_t)NDIM * HDIM * KDIM * SDIM;
    const size_t need2 = (f_base + f_q) * 4;                       // ~72 MB
    const size_t need1 = need2 + (size_t)NDIM * KDIM * SDIM * SDIM * 2; // ~139 MB

    float* out_pi = out;
    float* out_b  = out + (size_t)TDIM * NDIM * KDIM;
    float* out_lp = out + (size_t)TDIM * NDIM * KDIM + (size_t)TDIM * NDIM * SDIM;

    transform_kernel<<<NDIM, 256, 0, stream>>>(theta, invstd, c0, ent, logC, Dws, pdfws);

    if (ws_size >= need1) {
        row_stats_kernel<<<(NDIM * KDIM * SDIM) / 4, 256, 0, stream>>>(
            theta, logC, ent, lse, rws, bn);
        belief_fast_kernel<<<NDIM, 512, 0, stream>>>(
            o, a, theta, bn, invstd, c0, Dws, out_b, out_lp);
        vi_kernel<<<NDIM, 512, 0, stream>>>(theta, lse, rws, q_ws);
        dim3 pgrid(NDIM, 7);
        policy4_kernel<<<pgrid, 256, 0, stream>>>(q_ws, out_b, pdfws, out_pi);
    } else if (ws_size >= need2) {
        row_stats_kernel<<<(NDIM * KDIM * SDIM) / 4, 256, 0, stream>>>(
            theta, logC, ent, lse, rws, (__hip_bfloat16*)nullptr);
        belief_kernel<<<NDIM, 512, 0, stream>>>(
            o, a, theta, lse, invstd, c0, Dws, out_b, out_lp);
        vi_kernel<<<NDIM, 512, 0, stream>>>(theta, lse, rws, q_ws);
        dim3 pgrid(NDIM, 7);
        policy4_kernel<<<pgrid, 256, 0, stream>>>(q_ws, out_b, pdfws, out_pi);
    } else {
        row_stats_kernel<<<(NDIM * KDIM * SDIM) / 4, 256, 0, stream>>>(
            theta, logC, ent, lse, rws, (__hip_bfloat16*)nullptr);
        belief_kernel<<<NDIM, 512, 0, stream>>>(
            o, a, theta, lse, invstd, c0, Dws, out_b, out_lp);
        vi_policy_kernel<<<NDIM, 512, 0, stream>>>(theta, lse, rws, pdfws, out_b, out_pi);
    }
}

// Round 13
// 671.260 us; speedup vs baseline: 1.7192x; 1.1278x over previous
//
#include <hip/hip_runtime.h>
#include <hip/hip_bf16.h>
#include <math.h>

#define SDIM 64
#define KDIM 16
#define ODIM 32
#define HDIM 30
#define TDIM 200
#define NDIM 512
#define NP 69761
#define EPSV 1e-6f
#define LOG2PIF 1.8378770664093453f

__device__ __forceinline__ float softplusf(float x) {
    return (x > 0.f) ? x + log1pf(expf(-x)) : log1pf(expf(x));
}
__device__ __forceinline__ float wave_max64(float v) {
#pragma unroll
    for (int off = 32; off; off >>= 1) v = fmaxf(v, __shfl_xor(v, off, 64));
    return v;
}
__device__ __forceinline__ float wave_sum64(float v) {
#pragma unroll
    for (int off = 32; off; off >>= 1) v += __shfl_xor(v, off, 64);
    return v;
}
// barrier that waits only on LDS ops — leaves global loads/stores in flight
__device__ __forceinline__ void bar_lds() {
    asm volatile("s_waitcnt lgkmcnt(0)\n\ts_barrier" ::: "memory");
}

// ---------------- kernel 1: per-n parameter transforms ----------------
__global__ __launch_bounds__(256) void transform_kernel(
    const float* __restrict__ theta, float* __restrict__ invstd,
    float* __restrict__ c0, float* __restrict__ ent,
    float* __restrict__ logC, float* __restrict__ Dws,
    float* __restrict__ pdfws)
{
    __shared__ float ls[SDIM * 33];
    const int n = blockIdx.x, tid = threadIdx.x;
    const float* thn = theta + (size_t)n * NP;

    for (int idx = tid; idx < SDIM * ODIM; idx += 256) {
        float x = thn[2048 + idx];
        float sp = softplusf(x) + EPSV;            // A_std
        invstd[(size_t)n * SDIM * ODIM + idx] = 1.f / sp;
        int s = idx >> 5, oo = idx & 31;
        ls[s * 33 + oo] = logf(sp);
    }
    __syncthreads();

    const int wave = tid >> 6, lane = tid & 63;
    if (wave == 0) {                                // c0, ent per state s
        float sum = 0.f;
#pragma unroll
        for (int oo = 0; oo < ODIM; ++oo) sum += ls[lane * 33 + oo];
        c0[n * SDIM + lane]  = -sum - 16.f * LOG2PIF;
        ent[n * SDIM + lane] =  sum + 32.f * (0.5f + 0.5f * LOG2PIF);
    } else if (wave == 1) {                         // log(C + eps)
        float x = thn[69632 + lane];
        float m = wave_max64(x);
        float e = expf(x - m);
        float ssum = wave_sum64(e);
        logC[n * SDIM + lane] = logf(e / ssum + EPSV);
    } else if (wave == 2) {                         // D = softmax(tD)
        float x = thn[69696 + lane];
        float m = wave_max64(x);
        float e = expf(x - m);
        float ssum = wave_sum64(e);
        Dws[n * SDIM + lane] = e / ssum;
    } else {                                        // truncated poisson pdf
        float tt = thn[69760];
        float tau = 60.f / (1.f + expf(-tt)) + 1.f;
        float p = 0.f;
        if (lane < HDIM)
            p = expf((float)lane * logf(tau) - tau - lgammaf((float)lane + 1.f));
        float ssum = wave_sum64(p);
        if (lane < HDIM) pdfws[n * HDIM + lane] = p / ssum;
    }
}

// ---- kernel 2: per-row B softmax stats + reward; optional packed bf16 B ----
// bn packed-pair row-major: uint idx (k*2048 + (i>>1)*64 + j) holds
// {lo = bf16 B[k][i_even][j], hi = bf16 B[k][i_odd][j]} — loads coalesce over j.
__global__ __launch_bounds__(256) void row_stats_kernel(
    const float* __restrict__ theta, const float* __restrict__ logC,
    const float* __restrict__ ent, float* __restrict__ lse,
    float* __restrict__ rws, __hip_bfloat16* __restrict__ bn)
{
    const int gw = blockIdx.x * 4 + (threadIdx.x >> 6);  // global row (n,k,i)
    const int lane = threadIdx.x & 63;
    const int n = gw >> 10, rl = gw & 1023;
    float x = theta[(size_t)n * NP + 4096 + (size_t)rl * 64 + lane];
    float m = wave_max64(x);
    float e = expf(x - m);
    float ssum = wave_sum64(e);
    float Bj = e / ssum;
    if (bn) {
        const int k = rl >> 6, i = rl & 63;
        __hip_bfloat16 h = __float2bfloat16(Bj);
        unsigned short bits;
        __builtin_memcpy(&bits, &h, 2);
        ((unsigned short*)bn)[(size_t)n * KDIM * SDIM * SDIM
            + (size_t)k * 4096 + (size_t)(i >> 1) * 128 + lane * 2 + (i & 1)] = bits;
    }
    float contrib = Bj * (logf(Bj + EPSV) - logC[n * SDIM + lane] + ent[n * SDIM + lane]);
    contrib = wave_sum64(contrib);
    if (lane == 0) {
        lse[gw] = m + logf(ssum);
        rws[gw] = -contrib;
    }
}

// z2 partial for step TT_ into buffer BUF_ (waves 1..4, 8 obs each)
#define Z2PART(TT_, BUF_) do {                                                 \
    const int ob_ = (wave - 1) * 8;                                            \
    const float* om_ = &o_s[(TT_) * ODIM + ob_];                               \
    float zz_ = 0.f;                                                           \
    _Pragma("unroll")                                                          \
    for (int j_ = 0; j_ < 8; ++j_) {                                           \
        float z_ = (om_[j_] - mean_s[lane * 33 + ob_ + j_])                    \
                 * istd_s[lane * 33 + ob_ + j_];                               \
        zz_ += z_ * z_;                                                        \
    }                                                                          \
    z2p_s[BUF_][wave - 1][lane] = zz_;                                         \
} while (0)

// ===================== TIER-1 belief: packed bf16 B + softmax-free step =====================
#define BSTEPF(T_, U_) do {                                                    \
    const int cur_ = (T_) & 1, nxt_ = cur_ ^ 1;                                \
    float ecz_ = 0.f, cm_ = 0.f;                                               \
    if (wave >= 1) {                                                           \
        float aA_ = 0.f, aB_ = 0.f;                                            \
        _Pragma("unroll")                                                      \
        for (int ii = 0; ii < 10; ii += 2) {                                   \
            if (ii < nrow)     aA_ += er[ii]     * b_bc[cur_][rbase + ii];     \
            if (ii + 1 < nrow) aB_ += er[ii + 1] * b_bc[cur_][rbase + ii + 1]; \
        }                                                                      \
        part_s[wave - 1][lane] = aA_ + aB_;                                    \
        if (wave == 6) out_b[((size_t)(T_) * NDIM + n) * SDIM + lane] = b_bc[cur_][lane]; \
    } else {                                                                   \
        float z2_ = z2p_s[cur_][0][lane] + z2p_s[cur_][1][lane]                \
                  + z2p_s[cur_][2][lane] + z2p_s[cur_][3][lane];               \
        float c_ = c0_r - 0.5f * z2_;                                          \
        cm_ = wave_max64(c_);                                                  \
        ecz_ = __expf(c_ - cm_);                                               \
    }                                                                          \
    bar_lds();  /* A: parts ready */                                           \
    if (wave == 0) {                                                           \
        float sv_ = part_s[0][lane] + part_s[1][lane] + part_s[2][lane]        \
                  + part_s[3][lane] + part_s[4][lane] + part_s[5][lane]        \
                  + part_s[6][lane];                                           \
        float u_ = (sv_ + EPSV) * ecz_;                                        \
        float S_ = wave_sum64(u_);                                             \
        b_bc[nxt_][lane] = u_ / S_;                                            \
        if (lane == 0) out_lp[(size_t)(T_) * NDIM + n] = cm_ + __logf(S_);     \
    } else {                                                                   \
        if ((T_) + 1 < TDIM) {                                                 \
            _Pragma("unroll")                                                  \
            for (int m_ = 0; m_ < 5; ++m_) {                                   \
                if (2 * m_ < nrow)                                             \
                    er[2 * m_] = __uint_as_float(U_[m_] << 16);                \
                if (2 * m_ + 1 < nrow)                                         \
                    er[2 * m_ + 1] = __uint_as_float(U_[m_] & 0xffff0000u);    \
            }                                                                  \
            if (wave <= 4) Z2PART((T_) + 1, nxt_);                             \
        }                                                                      \
        const int tl_ = ((T_) + 3 < TDIM) ? (T_) + 3 : TDIM - 1;               \
        const uint* up_ = bnn32 + (size_t)a_s[tl_] * 2048 + (rbase >> 1) * 64 + lane; \
        _Pragma("unroll")                                                      \
        for (int m_ = 0; m_ < 5; ++m_)                                         \
            if (2 * m_ < nrow) U_[m_] = up_[m_ * 64];                          \
    }                                                                          \
    bar_lds();  /* B: b ready */                                               \
} while (0)

__global__ __launch_bounds__(512) void belief_fast_kernel(
    const float* __restrict__ o, const int* __restrict__ a,
    const float* __restrict__ theta, const __hip_bfloat16* __restrict__ bn,
    const float* __restrict__ invstd, const float* __restrict__ c0g,
    const float* __restrict__ Dws,
    float* __restrict__ out_b, float* __restrict__ out_lp)
{
    __shared__ float o_s[TDIM * ODIM];       // 25.6 KB
    __shared__ int   a_s[TDIM];
    __shared__ float mean_s[SDIM * 33];
    __shared__ float istd_s[SDIM * 33];
    __shared__ float c0_sh[SDIM];
    __shared__ __align__(16) float b_bc[2][SDIM];
    __shared__ float part_s[7][68];
    __shared__ float z2p_s[2][4][SDIM];

    const int n = blockIdx.x, tid = threadIdx.x;
    const int wave = tid >> 6, lane = tid & 63;
    const float* thn = theta + (size_t)n * NP;
    const uint* bnn32 = (const uint*)(bn + (size_t)n * KDIM * SDIM * SDIM);

    for (int idx = tid; idx < TDIM * ODIM; idx += 512)
        o_s[idx] = o[((size_t)(idx >> 5) * NDIM + n) * ODIM + (idx & 31)];
    if (tid < TDIM) a_s[tid] = a[tid * NDIM + n];
    for (int idx = tid; idx < SDIM * ODIM; idx += 512) {
        int s = idx >> 5, oo = idx & 31;
        mean_s[s * 33 + oo] = thn[idx];
        istd_s[s * 33 + oo] = invstd[(size_t)n * SDIM * ODIM + idx];
    }
    if (tid < SDIM) { c0_sh[tid] = c0g[n * SDIM + tid]; b_bc[0][tid] = Dws[n * SDIM + tid]; }
    __syncthreads();

    const float c0_r = (wave == 0) ? c0_sh[lane] : 0.f;
    const int rbase = (wave >= 1) ? (wave - 1) * 10 : 0;
    const int nrow  = (wave >= 1) ? ((SDIM - rbase) < 10 ? (SDIM - rbase) : 10) : 0;

    float er[10];
    uint u0[5], u1[5];
    if (wave >= 1) {
        const uint* p0 = bnn32 + (size_t)a_s[0] * 2048 + (rbase >> 1) * 64 + lane;
#pragma unroll
        for (int m = 0; m < 5; ++m) if (2 * m < nrow) u0[m] = p0[m * 64];
#pragma unroll
        for (int m = 0; m < 5; ++m) {
            if (2 * m < nrow)     er[2 * m]     = __uint_as_float(u0[m] << 16);
            if (2 * m + 1 < nrow) er[2 * m + 1] = __uint_as_float(u0[m] & 0xffff0000u);
        }
        const uint* p1 = bnn32 + (size_t)a_s[1] * 2048 + (rbase >> 1) * 64 + lane;
#pragma unroll
        for (int m = 0; m < 5; ++m) if (2 * m < nrow) u0[m] = p1[m * 64];
        const uint* p2 = bnn32 + (size_t)a_s[2] * 2048 + (rbase >> 1) * 64 + lane;
#pragma unroll
        for (int m = 0; m < 5; ++m) if (2 * m < nrow) u1[m] = p2[m * 64];
        if (wave <= 4) Z2PART(0, 0);
    }
    __syncthreads();

#pragma unroll 1
    for (int t = 0; t < TDIM; t += 2) {
        BSTEPF(t, u0);
        BSTEPF(t + 1, u1);
    }
}

// ===================== TIER-2/3 belief (f32 logits + exp) =====================
#define BSTEP(T_, RAW_) do {                                                   \
    const int cur_ = (T_) & 1, nxt_ = cur_ ^ 1;                                \
    if (wave >= 1) {                                                           \
        float acc_ = 0.f;                                                      \
        _Pragma("unroll")                                                      \
        for (int ii = 0; ii < 10; ++ii)                                        \
            if (ii < nrow) acc_ += er[ii] * b_s[cur_][rbase + ii];             \
        part_s[wave - 1][lane] = acc_;                                         \
        if (wave == 6) out_b[((size_t)(T_) * NDIM + n) * SDIM + lane] = b_s[cur_][lane]; \
    }                                                                          \
    bar_lds();                                                                 \
    if (wave == 0) {                                                           \
        float sv_ = part_s[0][lane] + part_s[1][lane] + part_s[2][lane]        \
                  + part_s[3][lane] + part_s[4][lane] + part_s[5][lane]        \
                  + part_s[6][lane];                                           \
        float z2_ = z2p_s[cur_][0][lane] + z2p_s[cur_][1][lane]                \
                  + z2p_s[cur_][2][lane] + z2p_s[cur_][3][lane];               \
        float joint_ = __logf(sv_ + EPSV) + c0_s[lane] - 0.5f * z2_;           \
        float m_ = wave_max64(joint_);                                         \
        float e_ = __expf(joint_ - m_);                                        \
        float ss_ = wave_sum64(e_);                                            \
        b_s[nxt_][lane] = e_ / ss_;                                            \
        if (lane == 0) out_lp[(size_t)(T_) * NDIM + n] = m_ + __logf(ss_);     \
    } else {                                                                   \
        if ((T_) + 1 < TDIM) {                                                 \
            const int an_ = a_s[(T_) + 1];                                     \
            const float* ln_ = lseA + an_ * SDIM;                              \
            _Pragma("unroll")                                                  \
            for (int ii = 0; ii < 10; ++ii)                                    \
                if (ii < nrow) er[ii] = __expf(RAW_[ii] - ln_[rbase + ii]);    \
            if (wave <= 4) Z2PART((T_) + 1, nxt_);                             \
        }                                                                      \
        const int tl_ = ((T_) + 3 < TDIM) ? (T_) + 3 : TDIM - 1;               \
        const int a3_ = a_s[tl_];                                              \
        const float* X3_ = Xn + (size_t)a3_ * SDIM * SDIM;                     \
        _Pragma("unroll")                                                      \
        for (int ii = 0; ii < 10; ++ii)                                        \
            if (ii < nrow) RAW_[ii] = X3_[(size_t)(rbase + ii) * SDIM + lane]; \
    }                                                                          \
    bar_lds();                                                                 \
} while (0)

__global__ __launch_bounds__(512) void belief_kernel(
    const float* __restrict__ o, const int* __restrict__ a,
    const float* __restrict__ theta, const float* __restrict__ lse,
    const float* __restrict__ invstd, const float* __restrict__ c0g,
    const float* __restrict__ Dws,
    float* __restrict__ out_b, float* __restrict__ out_lp)
{
    __shared__ float o_s[TDIM * ODIM];
    __shared__ int   a_s[TDIM];
    __shared__ float mean_s[SDIM * 33];
    __shared__ float istd_s[SDIM * 33];
    __shared__ float lseA[KDIM * SDIM];
    __shared__ float c0_s[SDIM];
    __shared__ float b_s[2][SDIM];
    __shared__ float part_s[7][68];
    __shared__ float z2p_s[2][4][SDIM];

    const int n = blockIdx.x, tid = threadIdx.x;
    const int wave = tid >> 6, lane = tid & 63;
    const float* thn = theta + (size_t)n * NP;
    const float* Xn  = thn + 4096;

    for (int idx = tid; idx < TDIM * ODIM; idx += 512)
        o_s[idx] = o[((size_t)(idx >> 5) * NDIM + n) * ODIM + (idx & 31)];
    if (tid < TDIM) a_s[tid] = a[tid * NDIM + n];
    for (int idx = tid; idx < SDIM * ODIM; idx += 512) {
        int s = idx >> 5, oo = idx & 31;
        mean_s[s * 33 + oo] = thn[idx];
        istd_s[s * 33 + oo] = invstd[(size_t)n * SDIM * ODIM + idx];
    }
    for (int idx = tid; idx < KDIM * SDIM; idx += 512)
        lseA[idx] = lse[(size_t)n * KDIM * SDIM + idx];
    if (tid < SDIM) { c0_s[tid] = c0g[n * SDIM + tid]; b_s[0][tid] = Dws[n * SDIM + tid]; }
    __syncthreads();

    const int rbase = (wave >= 1) ? (wave - 1) * 10 : 0;
    const int nrow  = (wave >= 1) ? ((SDIM - rbase) < 10 ? (SDIM - rbase) : 10) : 0;

    float er[10], raw0[10], raw1[10];
    if (wave >= 1) {
        const int a0 = a_s[0];
        const float* X0 = Xn + (size_t)a0 * SDIM * SDIM;
        const float* l0 = lseA + a0 * SDIM;
#pragma unroll
        for (int ii = 0; ii < 10; ++ii)
            if (ii < nrow) er[ii] = __expf(X0[(size_t)(rbase + ii) * SDIM + lane] - l0[rbase + ii]);
        const int a1 = a_s[1];
        const float* X1 = Xn + (size_t)a1 * SDIM * SDIM;
#pragma unroll
        for (int ii = 0; ii < 10; ++ii)
            if (ii < nrow) raw0[ii] = X1[(size_t)(rbase + ii) * SDIM + lane];
        const int a2 = a_s[2];
        const float* X2 = Xn + (size_t)a2 * SDIM * SDIM;
#pragma unroll
        for (int ii = 0; ii < 10; ++ii)
            if (ii < nrow) raw1[ii] = X2[(size_t)(rbase + ii) * SDIM + lane];
        if (wave <= 4) Z2PART(0, 0);
    }
    __syncthreads();

#pragma unroll 1
    for (int t = 0; t < TDIM; t += 2) {
        BSTEP(t, raw0);
        BSTEP(t + 1, raw1);
    }
}

// ------- VI: thread-owns-row, q streamed to global workspace -------
__global__ __launch_bounds__(512) void vi_kernel(
    const float* __restrict__ theta, const float* __restrict__ lse,
    const float* __restrict__ rws, float* __restrict__ q_ws)
{
    __shared__ float q_lds[KDIM * 68];
    __shared__ __align__(16) float v_lds[68];
    const int n = blockIdx.x, tid = threadIdx.x;
    const float* Xn = theta + (size_t)n * NP + 4096;

    const float l0  = lse[(size_t)n * 1024 + tid];
    const float l1  = lse[(size_t)n * 1024 + 512 + tid];
    const float rr0 = rws[(size_t)n * 1024 + tid];
    const float rr1 = rws[(size_t)n * 1024 + 512 + tid];

    float4 er0[16], er1[16];
    {
        const float* X0 = Xn + (size_t)tid * 64;
        const float* X1 = Xn + (size_t)(512 + tid) * 64;
#pragma unroll
        for (int j = 0; j < 16; ++j) {
            float4 x = *(const float4*)(X0 + j * 4);
            er0[j] = make_float4(__expf(x.x - l0), __expf(x.y - l0),
                                 __expf(x.z - l0), __expf(x.w - l0));
            float4 y = *(const float4*)(X1 + j * 4);
            er1[j] = make_float4(__expf(y.x - l1), __expf(y.y - l1),
                                 __expf(y.z - l1), __expf(y.w - l1));
        }
    }

    float qr0 = rr0, qr1 = rr1;
    float* qw = q_ws + (size_t)n * HDIM * 1024;
    const int kq0 = tid >> 6, iq = tid & 63;
    qw[tid] = qr0;
    qw[512 + tid] = qr1;
    q_lds[kq0 * 68 + iq] = qr0;
    q_lds[(8 + kq0) * 68 + iq] = qr1;
    __syncthreads();

#pragma unroll 1
    for (int h = 1; h < HDIM; ++h) {
        if (tid < 64) {
            float m = -1e30f;
#pragma unroll
            for (int k = 0; k < KDIM; ++k) m = fmaxf(m, q_lds[k * 68 + tid]);
            float s = 0.f;
#pragma unroll
            for (int k = 0; k < KDIM; ++k) s += __expf(q_lds[k * 68 + tid] - m);
            v_lds[tid] = m + __logf(s);
        }
        bar_lds();
        float a0x = 0.f, a0y = 0.f, a0z = 0.f, a0w = 0.f;
        float a1x = 0.f, a1y = 0.f, a1z = 0.f, a1w = 0.f;
#pragma unroll
        for (int jq = 0; jq < 16; ++jq) {
            const float4 v4 = *(const float4*)&v_lds[jq * 4];
            a0x += er0[jq].x * v4.x; a0y += er0[jq].y * v4.y;
            a0z += er0[jq].z * v4.z; a0w += er0[jq].w * v4.w;
            a1x += er1[jq].x * v4.x; a1y += er1[jq].y * v4.y;
            a1z += er1[jq].z * v4.z; a1w += er1[jq].w * v4.w;
        }
        qr0 = rr0 + ((a0x + a0y) + (a0z + a0w));
        qr1 = rr1 + ((a1x + a1y) + (a1z + a1w));
        qw[(size_t)h * 1024 + tid] = qr0;
        qw[(size_t)h * 1024 + 512 + tid] = qr1;
        q_lds[kq0 * 68 + iq] = qr0;
        q_lds[(8 + kq0) * 68 + iq] = qr1;
        bar_lds();
    }
}

// ------- policy (broadcast): block per n, thread (h,k) owns q-row in regs -------
// b rows staged once in LDS; per-t reads are wave-uniform (LDS broadcast, free).
// h-sum via 2 shuffles + 8x16 partials, double-buffered; 1 barrier per t.
__global__ __launch_bounds__(512, 1) void policy_bc_kernel(
    const float* __restrict__ q_ws, const float* __restrict__ out_b_g,
    const float* __restrict__ pdfg, float* __restrict__ out_pi)
{
    __shared__ __align__(16) float b_all[TDIM * SDIM];   // 51,200 B
    __shared__ float part[2][8][16];
    __shared__ float pdf_s[32];

    const int n = blockIdx.x, tid = threadIdx.x;
    const int w = tid >> 6, lane = tid & 63;
    const int hl = lane >> 4, kk = lane & 15;
    const int hown = w * 4 + hl;                 // 0..31 (30,31 pad)
    const float* qn = q_ws + (size_t)n * HDIM * 1024;

    for (int idx = tid; idx < TDIM * 16; idx += 512) {
        const int t = idx >> 4, jq = idx & 15;
        *(float4*)&b_all[t * SDIM + jq * 4] =
            *(const float4*)&out_b_g[((size_t)t * NDIM + n) * SDIM + jq * 4];
    }
    if (tid < 32) pdf_s[tid] = (tid < HDIM) ? pdfg[n * HDIM + tid] : 0.f;

    float4 qrow[16];
    if (hown < HDIM) {
#pragma unroll
        for (int jq = 0; jq < 16; ++jq)
            qrow[jq] = *(const float4*)&qn[(size_t)hown * 1024 + kk * 64 + jq * 4];
    } else {
#pragma unroll
        for (int jq = 0; jq < 16; ++jq)
            qrow[jq] = make_float4(0.f, 0.f, 0.f, 0.f);
    }
    __syncthreads();
    const float pdfh = pdf_s[hown];

#pragma unroll 1
    for (int t = 0; t < TDIM; ++t) {
        const int cur = t & 1;
        const float* br = &b_all[t * SDIM];
        float ax = 0.f, ay = 0.f, az = 0.f, aw = 0.f;
#pragma unroll
        for (int jq = 0; jq < 16; ++jq) {
            const float4 b4 = *(const float4*)&br[jq * 4];   // wave-uniform: broadcast
            ax += qrow[jq].x * b4.x; ay += qrow[jq].y * b4.y;
            az += qrow[jq].z * b4.z; aw += qrow[jq].w * b4.w;
        }
        float acc = (ax + ay) + (az + aw);
        float m = acc;
        m = fmaxf(m, __shfl_xor(m, 1, 64));
        m = fmaxf(m, __shfl_xor(m, 2, 64));
        m = fmaxf(m, __shfl_xor(m, 4, 64));
        m = fmaxf(m, __shfl_xor(m, 8, 64));
        float e = __expf(acc - m);
        float S = e;
        S += __shfl_xor(S, 1, 64);
        S += __shfl_xor(S, 2, 64);
        S += __shfl_xor(S, 4, 64);
        S += __shfl_xor(S, 8, 64);
        float val = pdfh * e / S;
        val += __shfl_xor(val, 16, 64);          // sum over hl (lane bits 4,5)
        val += __shfl_xor(val, 32, 64);
        if (lane < 16) part[cur][w][lane] = val;
        if (w == 0 && t > 0 && lane < 16) {      // emit previous t (part stable)
            const int prv = cur ^ 1;
            float s8 = 0.f;
#pragma unroll
            for (int ww = 0; ww < 8; ++ww) s8 += part[prv][ww][lane];
            out_pi[((size_t)(t - 1) * NDIM + n) * KDIM + lane] = s8;
        }
        bar_lds();
    }
    if (w == 0 && lane < 16) {
        float s8 = 0.f;
#pragma unroll
        for (int ww = 0; ww < 8; ++ww) s8 += part[(TDIM - 1) & 1][ww][lane];
        out_pi[((size_t)(TDIM - 1) * NDIM + n) * KDIM + lane] = s8;
    }
}

// ------- tier-3 fallback: fused VI+policy (no extra ws) -------
__global__ __launch_bounds__(512) void vi_policy_kernel(
    const float* __restrict__ theta, const float* __restrict__ lse,
    const float* __restrict__ rws, const float* __restrict__ pdfg,
    const float* __restrict__ out_b_g, float* __restrict__ out_pi)
{
    __shared__ __align__(16) float q_s[HDIM * KDIM * 68];
    __shared__ float r_s[KDIM * SDIM];
    __shared__ float lse_s[KDIM * SDIM];
    __shared__ __align__(16) float v_s[SDIM];
    __shared__ __align__(16) float b_lds[64 * 68];
    __shared__ float pdf_s[32];

    const int n = blockIdx.x, tid = threadIdx.x;
    const int wave = tid >> 6, lane = tid & 63;
    const int sub = lane & 15, rq = lane >> 4;
    const float* Xn = theta + (size_t)n * NP + 4096;

    for (int idx = tid; idx < KDIM * SDIM; idx += 512) {
        r_s[idx]   = rws[(size_t)n * KDIM * SDIM + idx];
        lse_s[idx] = lse[(size_t)n * KDIM * SDIM + idx];
    }
    if (tid < HDIM) pdf_s[tid] = pdfg[n * HDIM + tid];
    __syncthreads();

    for (int idx = tid; idx < KDIM * SDIM; idx += 512)
        q_s[(idx >> 6) * 68 + (idx & 63)] = r_s[idx];

    float4 breg[32];
#pragma unroll
    for (int it = 0; it < 32; ++it) {
        const int row = it * 32 + wave * 4 + rq;
        const float* xr = Xn + (size_t)row * SDIM + sub * 4;
        const float l = lse_s[row];
        breg[it] = make_float4(__expf(xr[0] - l), __expf(xr[1] - l),
                               __expf(xr[2] - l), __expf(xr[3] - l));
    }
    bar_lds();

#pragma unroll 1
    for (int h = 1; h < HDIM; ++h) {
        if (tid < SDIM) {
            const int base = (h - 1) * KDIM;
            float m = -1e30f;
#pragma unroll
            for (int k = 0; k < KDIM; ++k) m = fmaxf(m, q_s[(base + k) * 68 + tid]);
            float ssum = 0.f;
#pragma unroll
            for (int k = 0; k < KDIM; ++k) ssum += __expf(q_s[(base + k) * 68 + tid] - m);
            v_s[tid] = m + __logf(ssum);
        }
        bar_lds();
        const float4 v4 = *(const float4*)&v_s[sub * 4];
#pragma unroll
        for (int it = 0; it < 32; ++it) {
            const int row = it * 32 + wave * 4 + rq;
            float acc = breg[it].x * v4.x + breg[it].y * v4.y
                      + breg[it].z * v4.z + breg[it].w * v4.w;
            acc += __shfl_xor(acc, 1, 64);
            acc += __shfl_xor(acc, 2, 64);
            acc += __shfl_xor(acc, 4, 64);
            acc += __shfl_xor(acc, 8, 64);
            if (sub == 0)
                q_s[(h * KDIM + (row >> 6)) * 68 + (row & 63)] = r_s[row] + acc;
        }
        bar_lds();
    }

    const int tc = tid >> 4, kk = tid & 15;
#pragma unroll 1
    for (int t0 = 0; t0 < TDIM; t0 += 64) {
        const int nt = (TDIM - t0) < 64 ? (TDIM - t0) : 64;
        for (int idx = tid; idx < nt * 16; idx += 512) {
            const int row = idx >> 4, jq = idx & 15;
            *(float4*)&b_lds[row * 68 + jq * 4] =
                *(const float4*)&out_b_g[(((size_t)(t0 + row)) * NDIM + n) * SDIM + jq * 4];
        }
        bar_lds();
        const bool vA = tc < nt, vB = (tc + 32) < nt;
        float4 bqA[16], bqB[16];
        if (vA) {
#pragma unroll
            for (int jq = 0; jq < 16; ++jq)
                bqA[jq] = *(const float4*)&b_lds[tc * 68 + jq * 4];
        }
        if (vB) {
#pragma unroll
            for (int jq = 0; jq < 16; ++jq)
                bqB[jq] = *(const float4*)&b_lds[(tc + 32) * 68 + jq * 4];
        }
        float pikA = 0.f, pikB = 0.f;
#pragma unroll 1
        for (int h = 0; h < HDIM; ++h) {
            const float* qr = &q_s[(h * KDIM + kk) * 68];
            float aA = 0.f, aB = 0.f;
#pragma unroll
            for (int jq = 0; jq < 16; ++jq) {
                const float4 qv = *(const float4*)&qr[jq * 4];
                if (vA) aA += qv.x * bqA[jq].x + qv.y * bqA[jq].y
                            + qv.z * bqA[jq].z + qv.w * bqA[jq].w;
                if (vB) aB += qv.x * bqB[jq].x + qv.y * bqB[jq].y
                            + qv.z * bqB[jq].z + qv.w * bqB[jq].w;
            }
            float mA = aA, mB = aB;
            mA = fmaxf(mA, __shfl_xor(mA, 1, 64));
            mA = fmaxf(mA, __shfl_xor(mA, 2, 64));
            mA = fmaxf(mA, __shfl_xor(mA, 4, 64));
            mA = fmaxf(mA, __shfl_xor(mA, 8, 64));
            mB = fmaxf(mB, __shfl_xor(mB, 1, 64));
            mB = fmaxf(mB, __shfl_xor(mB, 2, 64));
            mB = fmaxf(mB, __shfl_xor(mB, 4, 64));
            mB = fmaxf(mB, __shfl_xor(mB, 8, 64));
            float eA = __expf(aA - mA), eB = __expf(aB - mB);
            float SA = eA, SB = eB;
            SA += __shfl_xor(SA, 1, 64);
            SA += __shfl_xor(SA, 2, 64);
            SA += __shfl_xor(SA, 4, 64);
            SA += __shfl_xor(SA, 8, 64);
            SB += __shfl_xor(SB, 1, 64);
            SB += __shfl_xor(SB, 2, 64);
            SB += __shfl_xor(SB, 4, 64);
            SB += __shfl_xor(SB, 8, 64);
            const float ph = pdf_s[h];
            pikA += ph * eA / SA;
            pikB += ph * eB / SB;
        }
        if (vA) out_pi[(((size_t)(t0 + tc)) * NDIM + n) * KDIM + kk] = pikA;
        if (vB) out_pi[(((size_t)(t0 + 32 + tc)) * NDIM + n) * KDIM + kk] = pikB;
        bar_lds();
    }
}

extern "C" void kernel_launch(void* const* d_in, const int* in_sizes, int n_in,
                              void* d_out, int out_size, void* d_ws, size_t ws_size,
                              hipStream_t stream) {
    (void)in_sizes; (void)n_in; (void)out_size;
    const float* o     = (const float*)d_in[0];
    const int*   a     = (const int*)d_in[1];
    const float* theta = (const float*)d_in[2];
    float* out = (float*)d_out;
    float* ws  = (float*)d_ws;

    float* lse    = ws;                                   // N*K*S
    float* rws    = lse    + (size_t)NDIM * KDIM * SDIM;  // N*K*S
    float* invstd = rws    + (size_t)NDIM * KDIM * SDIM;  // N*S*O
    float* c0     = invstd + (size_t)NDIM * SDIM * ODIM;  // N*S
    float* ent    = c0     + (size_t)NDIM * SDIM;         // N*S
    float* logC   = ent    + (size_t)NDIM * SDIM;         // N*S
    float* Dws    = logC   + (size_t)NDIM * SDIM;         // N*S
    float* pdfws  = Dws    + (size_t)NDIM * SDIM;         // N*H
    float* q_ws   = pdfws  + (size_t)NDIM * HDIM;         // N*H*K*S f32 (63 MB)
    __hip_bfloat16* bn = (__hip_bfloat16*)(q_ws + (size_t)NDIM * HDIM * KDIM * SDIM);

    const size_t f_base = (size_t)NDIM * KDIM * SDIM * 2
                        + (size_t)NDIM * SDIM * ODIM
                        + (size_t)NDIM * SDIM * 4
                        + (size_t)NDIM * HDIM;
    const size_t f_q  = (size_t)NDIM * HDIM * KDIM * SDIM;
    const size_t need2 = (f_base + f_q) * 4;                       // ~72 MB
    const size_t need1 = need2 + (size_t)NDIM * KDIM * SDIM * SDIM * 2; // ~139 MB

    float* out_pi = out;
    float* out_b  = out + (size_t)TDIM * NDIM * KDIM;
    float* out_lp = out + (size_t)TDIM * NDIM * KDIM + (size_t)TDIM * NDIM * SDIM;

    transform_kernel<<<NDIM, 256, 0, stream>>>(theta, invstd, c0, ent, logC, Dws, pdfws);

    if (ws_size >= need1) {
        row_stats_kernel<<<(NDIM * KDIM * SDIM) / 4, 256, 0, stream>>>(
            theta, logC, ent, lse, rws, bn);
        belief_fast_kernel<<<NDIM, 512, 0, stream>>>(
            o, a, theta, bn, invstd, c0, Dws, out_b, out_lp);
        vi_kernel<<<NDIM, 512, 0, stream>>>(theta, lse, rws, q_ws);
        policy_bc_kernel<<<NDIM, 512, 0, stream>>>(q_ws, out_b, pdfws, out_pi);
    } else if (ws_size >= need2) {
        row_stats_kernel<<<(NDIM * KDIM * SDIM) / 4, 256, 0, stream>>>(
            theta, logC, ent, lse, rws, (__hip_bfloat16*)nullptr);
        belief_kernel<<<NDIM, 512, 0, stream>>>(
            o, a, theta, lse, invstd, c0, Dws, out_b, out_lp);
        vi_kernel<<<NDIM, 512, 0, stream>>>(theta, lse, rws, q_ws);
        policy_bc_kernel<<<NDIM, 512, 0, stream>>>(q_ws, out_b, pdfws, out_pi);
    } else {
        row_stats_kernel<<<(NDIM * KDIM * SDIM) / 4, 256, 0, stream>>>(
            theta, logC, ent, lse, rws, (__hip_bfloat16*)nullptr);
        belief_kernel<<<NDIM, 512, 0, stream>>>(
            o, a, theta, lse, invstd, c0, Dws, out_b, out_lp);
        vi_policy_kernel<<<NDIM, 512, 0, stream>>>(theta, lse, rws, pdfws, out_b, out_pi);
    }
}

// Round 14
// 659.000 us; speedup vs baseline: 1.7512x; 1.0186x over previous
//
#include <hip/hip_runtime.h>
#include <hip/hip_bf16.h>
#include <math.h>

#define SDIM 64
#define KDIM 16
#define ODIM 32
#define HDIM 30
#define TDIM 200
#define NDIM 512
#define NP 69761
#define EPSV 1e-6f
#define LOG2PIF 1.8378770664093453f

__device__ __forceinline__ float softplusf(float x) {
    return (x > 0.f) ? x + log1pf(expf(-x)) : log1pf(expf(x));
}
__device__ __forceinline__ float wave_max64(float v) {
#pragma unroll
    for (int off = 32; off; off >>= 1) v = fmaxf(v, __shfl_xor(v, off, 64));
    return v;
}
__device__ __forceinline__ float wave_sum64(float v) {
#pragma unroll
    for (int off = 32; off; off >>= 1) v += __shfl_xor(v, off, 64);
    return v;
}
// barrier that waits only on LDS ops — leaves global loads/stores in flight
__device__ __forceinline__ void bar_lds() {
    asm volatile("s_waitcnt lgkmcnt(0)\n\ts_barrier" ::: "memory");
}

// ---------------- kernel 1: per-n parameter transforms ----------------
__global__ __launch_bounds__(256) void transform_kernel(
    const float* __restrict__ theta, float* __restrict__ invstd,
    float* __restrict__ c0, float* __restrict__ ent,
    float* __restrict__ logC, float* __restrict__ Dws,
    float* __restrict__ pdfws)
{
    __shared__ float ls[SDIM * 33];
    const int n = blockIdx.x, tid = threadIdx.x;
    const float* thn = theta + (size_t)n * NP;

    for (int idx = tid; idx < SDIM * ODIM; idx += 256) {
        float x = thn[2048 + idx];
        float sp = softplusf(x) + EPSV;            // A_std
        invstd[(size_t)n * SDIM * ODIM + idx] = 1.f / sp;
        int s = idx >> 5, oo = idx & 31;
        ls[s * 33 + oo] = logf(sp);
    }
    __syncthreads();

    const int wave = tid >> 6, lane = tid & 63;
    if (wave == 0) {                                // c0, ent per state s
        float sum = 0.f;
#pragma unroll
        for (int oo = 0; oo < ODIM; ++oo) sum += ls[lane * 33 + oo];
        c0[n * SDIM + lane]  = -sum - 16.f * LOG2PIF;
        ent[n * SDIM + lane] =  sum + 32.f * (0.5f + 0.5f * LOG2PIF);
    } else if (wave == 1) {                         // log(C + eps)
        float x = thn[69632 + lane];
        float m = wave_max64(x);
        float e = expf(x - m);
        float ssum = wave_sum64(e);
        logC[n * SDIM + lane] = logf(e / ssum + EPSV);
    } else if (wave == 2) {                         // D = softmax(tD)
        float x = thn[69696 + lane];
        float m = wave_max64(x);
        float e = expf(x - m);
        float ssum = wave_sum64(e);
        Dws[n * SDIM + lane] = e / ssum;
    } else {                                        // truncated poisson pdf
        float tt = thn[69760];
        float tau = 60.f / (1.f + expf(-tt)) + 1.f;
        float p = 0.f;
        if (lane < HDIM)
            p = expf((float)lane * logf(tau) - tau - lgammaf((float)lane + 1.f));
        float ssum = wave_sum64(p);
        if (lane < HDIM) pdfws[n * HDIM + lane] = p / ssum;
    }
}

// ---- kernel 2: per-row B softmax stats + reward; optional packed bf16 B ----
// bn packed-pair row-major: uint idx (k*2048 + (i>>1)*64 + j) holds
// {lo = bf16 B[k][i_even][j], hi = bf16 B[k][i_odd][j]} — loads coalesce over j.
__global__ __launch_bounds__(256) void row_stats_kernel(
    const float* __restrict__ theta, const float* __restrict__ logC,
    const float* __restrict__ ent, float* __restrict__ lse,
    float* __restrict__ rws, __hip_bfloat16* __restrict__ bn)
{
    const int gw = blockIdx.x * 4 + (threadIdx.x >> 6);  // global row (n,k,i)
    const int lane = threadIdx.x & 63;
    const int n = gw >> 10, rl = gw & 1023;
    float x = theta[(size_t)n * NP + 4096 + (size_t)rl * 64 + lane];
    float m = wave_max64(x);
    float e = expf(x - m);
    float ssum = wave_sum64(e);
    float Bj = e / ssum;
    if (bn) {
        const int k = rl >> 6, i = rl & 63;
        __hip_bfloat16 h = __float2bfloat16(Bj);
        unsigned short bits;
        __builtin_memcpy(&bits, &h, 2);
        ((unsigned short*)bn)[(size_t)n * KDIM * SDIM * SDIM
            + (size_t)k * 4096 + (size_t)(i >> 1) * 128 + lane * 2 + (i & 1)] = bits;
    }
    float contrib = Bj * (logf(Bj + EPSV) - logC[n * SDIM + lane] + ent[n * SDIM + lane]);
    contrib = wave_sum64(contrib);
    if (lane == 0) {
        lse[gw] = m + logf(ssum);
        rws[gw] = -contrib;
    }
}

// ============== TIER-1 belief: symmetric 8 waves, ONE barrier per step ==============
// wave w owns rows w*8..w*8+7 (bf16 packed); after the barrier every wave
// redundantly computes the belief update into its OWN b_buf copy (no 2nd barrier).
// ecz/cm chain runs pre-barrier (z2p[cur] ready since previous barrier).
#define BSYM(T_, U_) do {                                                      \
    const int cur_ = (T_) & 1, nxt_ = cur_ ^ 1;                                \
    {   /* matvec for step T_ from own b copy (broadcast reads) */             \
        const float4 b0_ = *(const float4*)&b_buf[wave][rbase];                \
        const float4 b1_ = *(const float4*)&b_buf[wave][rbase + 4];            \
        float accA_ = er[0] * b0_.x + er[1] * b0_.y + er[2] * b0_.z + er[3] * b0_.w; \
        float accB_ = er[4] * b1_.x + er[5] * b1_.y + er[6] * b1_.z + er[7] * b1_.w; \
        part_s[cur_][wave][lane] = accA_ + accB_;                              \
    }                                                                          \
    if (wave == 7) out_b[((size_t)(T_) * NDIM + n) * SDIM + lane] = b_buf[7][lane]; \
    if ((T_) + 1 < TDIM && wave < 4) {   /* z2 partial for t+1 */              \
        const int ob_ = wave * 8;                                              \
        const float* om_ = &o_s[((T_) + 1) * ODIM + ob_];                      \
        float zz_ = 0.f;                                                       \
        _Pragma("unroll")                                                      \
        for (int j_ = 0; j_ < 8; ++j_) {                                       \
            float z_ = (om_[j_] - mean_s[lane * 33 + ob_ + j_])                \
                     * istd_s[lane * 33 + ob_ + j_];                           \
            zz_ += z_ * z_;                                                    \
        }                                                                      \
        z2p_s[nxt_][wave][lane] = zz_;                                         \
    }                                                                          \
    /* pre-barrier: ecz for step T_ (z2p[cur] stable since prev barrier) */    \
    const float z2_ = z2p_s[cur_][0][lane] + z2p_s[cur_][1][lane]              \
                    + z2p_s[cur_][2][lane] + z2p_s[cur_][3][lane];             \
    const float c_ = c0_r - 0.5f * z2_;                                        \
    const float cm_ = wave_max64(c_);                                          \
    const float ecz_ = __expf(c_ - cm_);                                       \
    if ((T_) + 1 < TDIM) {               /* unpack next-step B rows */         \
        _Pragma("unroll")                                                      \
        for (int m_ = 0; m_ < 4; ++m_) {                                       \
            er[2 * m_]     = __uint_as_float(U_[m_] << 16);                    \
            er[2 * m_ + 1] = __uint_as_float(U_[m_] & 0xffff0000u);            \
        }                                                                      \
    }                                                                          \
    {   /* prefetch B(a_{T+3}) */                                              \
        const int tl_ = ((T_) + 3 < TDIM) ? (T_) + 3 : TDIM - 1;               \
        const uint* up_ = bnn32 + (size_t)a_s[tl_] * 2048 + (rbase >> 1) * 64 + lane; \
        _Pragma("unroll")                                                      \
        for (int m_ = 0; m_ < 4; ++m_) U_[m_] = up_[m_ * 64];                  \
    }                                                                          \
    bar_lds();                           /* the ONE barrier */                 \
    {   /* redundant belief update, per wave */                                \
        float sv_ = part_s[cur_][0][lane] + part_s[cur_][1][lane]              \
                  + part_s[cur_][2][lane] + part_s[cur_][3][lane]              \
                  + part_s[cur_][4][lane] + part_s[cur_][5][lane]              \
                  + part_s[cur_][6][lane] + part_s[cur_][7][lane];             \
        float u_ = (sv_ + EPSV) * ecz_;                                        \
        float S_ = wave_sum64(u_);                                             \
        b_buf[wave][lane] = u_ / S_;                                           \
        if (wave == 0 && lane == 0)                                            \
            out_lp[(size_t)(T_) * NDIM + n] = cm_ + __logf(S_);                \
    }                                                                          \
} while (0)

__global__ __launch_bounds__(512) void belief_sym_kernel(
    const float* __restrict__ o, const int* __restrict__ a,
    const float* __restrict__ theta, const __hip_bfloat16* __restrict__ bn,
    const float* __restrict__ invstd, const float* __restrict__ c0g,
    const float* __restrict__ Dws,
    float* __restrict__ out_b, float* __restrict__ out_lp)
{
    __shared__ float o_s[TDIM * ODIM];       // 25.6 KB
    __shared__ int   a_s[TDIM];
    __shared__ float mean_s[SDIM * 33];
    __shared__ float istd_s[SDIM * 33];
    __shared__ float c0_sh[SDIM];
    __shared__ __align__(16) float b_buf[8][SDIM];   // per-wave private b
    __shared__ float part_s[2][8][68];
    __shared__ float z2p_s[2][4][SDIM];

    const int n = blockIdx.x, tid = threadIdx.x;
    const int wave = tid >> 6, lane = tid & 63;
    const int rbase = wave * 8;
    const float* thn = theta + (size_t)n * NP;
    const uint* bnn32 = (const uint*)(bn + (size_t)n * KDIM * SDIM * SDIM);

    for (int idx = tid; idx < TDIM * ODIM; idx += 512)
        o_s[idx] = o[((size_t)(idx >> 5) * NDIM + n) * ODIM + (idx & 31)];
    if (tid < TDIM) a_s[tid] = a[tid * NDIM + n];
    for (int idx = tid; idx < SDIM * ODIM; idx += 512) {
        int s = idx >> 5, oo = idx & 31;
        mean_s[s * 33 + oo] = thn[idx];
        istd_s[s * 33 + oo] = invstd[(size_t)n * SDIM * ODIM + idx];
    }
    if (tid < SDIM) c0_sh[tid] = c0g[n * SDIM + tid];
    b_buf[wave][lane] = Dws[n * SDIM + lane];
    __syncthreads();

    const float c0_r = c0_sh[lane];

    float er[8];
    uint u0[4], u1[4];
    {   // prologue: er <- B(a_0); u0 <- B(a_1); u1 <- B(a_2); z2 for t=0
        const uint* p0 = bnn32 + (size_t)a_s[0] * 2048 + (rbase >> 1) * 64 + lane;
#pragma unroll
        for (int m = 0; m < 4; ++m) u0[m] = p0[m * 64];
#pragma unroll
        for (int m = 0; m < 4; ++m) {
            er[2 * m]     = __uint_as_float(u0[m] << 16);
            er[2 * m + 1] = __uint_as_float(u0[m] & 0xffff0000u);
        }
        const uint* p1 = bnn32 + (size_t)a_s[1] * 2048 + (rbase >> 1) * 64 + lane;
#pragma unroll
        for (int m = 0; m < 4; ++m) u0[m] = p1[m * 64];
        const uint* p2 = bnn32 + (size_t)a_s[2] * 2048 + (rbase >> 1) * 64 + lane;
#pragma unroll
        for (int m = 0; m < 4; ++m) u1[m] = p2[m * 64];
        if (wave < 4) {
            const int ob = wave * 8;
            const float* om = &o_s[ob];
            float zz = 0.f;
#pragma unroll
            for (int j = 0; j < 8; ++j) {
                float z = (om[j] - mean_s[lane * 33 + ob + j]) * istd_s[lane * 33 + ob + j];
                zz += z * z;
            }
            z2p_s[0][wave][lane] = zz;
        }
    }
    __syncthreads();

#pragma unroll 1
    for (int t = 0; t < TDIM; t += 2) {
        BSYM(t, u0);
        BSYM(t + 1, u1);
    }
}

// ===================== TIER-2/3 belief (f32 logits + exp) =====================
#define Z2PART(TT_, BUF_) do {                                                 \
    const int ob_ = (wave - 1) * 8;                                            \
    const float* om_ = &o_s[(TT_) * ODIM + ob_];                               \
    float zz_ = 0.f;                                                           \
    _Pragma("unroll")                                                          \
    for (int j_ = 0; j_ < 8; ++j_) {                                           \
        float z_ = (om_[j_] - mean_s[lane * 33 + ob_ + j_])                    \
                 * istd_s[lane * 33 + ob_ + j_];                               \
        zz_ += z_ * z_;                                                        \
    }                                                                          \
    z2p_s[BUF_][wave - 1][lane] = zz_;                                         \
} while (0)

#define BSTEP(T_, RAW_) do {                                                   \
    const int cur_ = (T_) & 1, nxt_ = cur_ ^ 1;                                \
    if (wave >= 1) {                                                           \
        float acc_ = 0.f;                                                      \
        _Pragma("unroll")                                                      \
        for (int ii = 0; ii < 10; ++ii)                                        \
            if (ii < nrow) acc_ += er[ii] * b_s[cur_][rbase + ii];             \
        part_s[wave - 1][lane] = acc_;                                         \
        if (wave == 6) out_b[((size_t)(T_) * NDIM + n) * SDIM + lane] = b_s[cur_][lane]; \
    }                                                                          \
    bar_lds();                                                                 \
    if (wave == 0) {                                                           \
        float sv_ = part_s[0][lane] + part_s[1][lane] + part_s[2][lane]        \
                  + part_s[3][lane] + part_s[4][lane] + part_s[5][lane]        \
                  + part_s[6][lane];                                           \
        float z2_ = z2p_s[cur_][0][lane] + z2p_s[cur_][1][lane]                \
                  + z2p_s[cur_][2][lane] + z2p_s[cur_][3][lane];               \
        float joint_ = __logf(sv_ + EPSV) + c0_s[lane] - 0.5f * z2_;           \
        float m_ = wave_max64(joint_);                                         \
        float e_ = __expf(joint_ - m_);                                        \
        float ss_ = wave_sum64(e_);                                            \
        b_s[nxt_][lane] = e_ / ss_;                                            \
        if (lane == 0) out_lp[(size_t)(T_) * NDIM + n] = m_ + __logf(ss_);     \
    } else {                                                                   \
        if ((T_) + 1 < TDIM) {                                                 \
            const int an_ = a_s[(T_) + 1];                                     \
            const float* ln_ = lseA + an_ * SDIM;                              \
            _Pragma("unroll")                                                  \
            for (int ii = 0; ii < 10; ++ii)                                    \
                if (ii < nrow) er[ii] = __expf(RAW_[ii] - ln_[rbase + ii]);    \
            if (wave <= 4) Z2PART((T_) + 1, nxt_);                             \
        }                                                                      \
        const int tl_ = ((T_) + 3 < TDIM) ? (T_) + 3 : TDIM - 1;               \
        const int a3_ = a_s[tl_];                                              \
        const float* X3_ = Xn + (size_t)a3_ * SDIM * SDIM;                     \
        _Pragma("unroll")                                                      \
        for (int ii = 0; ii < 10; ++ii)                                        \
            if (ii < nrow) RAW_[ii] = X3_[(size_t)(rbase + ii) * SDIM + lane]; \
    }                                                                          \
    bar_lds();                                                                 \
} while (0)

__global__ __launch_bounds__(512) void belief_kernel(
    const float* __restrict__ o, const int* __restrict__ a,
    const float* __restrict__ theta, const float* __restrict__ lse,
    const float* __restrict__ invstd, const float* __restrict__ c0g,
    const float* __restrict__ Dws,
    float* __restrict__ out_b, float* __restrict__ out_lp)
{
    __shared__ float o_s[TDIM * ODIM];
    __shared__ int   a_s[TDIM];
    __shared__ float mean_s[SDIM * 33];
    __shared__ float istd_s[SDIM * 33];
    __shared__ float lseA[KDIM * SDIM];
    __shared__ float c0_s[SDIM];
    __shared__ float b_s[2][SDIM];
    __shared__ float part_s[7][68];
    __shared__ float z2p_s[2][4][SDIM];

    const int n = blockIdx.x, tid = threadIdx.x;
    const int wave = tid >> 6, lane = tid & 63;
    const float* thn = theta + (size_t)n * NP;
    const float* Xn  = thn + 4096;

    for (int idx = tid; idx < TDIM * ODIM; idx += 512)
        o_s[idx] = o[((size_t)(idx >> 5) * NDIM + n) * ODIM + (idx & 31)];
    if (tid < TDIM) a_s[tid] = a[tid * NDIM + n];
    for (int idx = tid; idx < SDIM * ODIM; idx += 512) {
        int s = idx >> 5, oo = idx & 31;
        mean_s[s * 33 + oo] = thn[idx];
        istd_s[s * 33 + oo] = invstd[(size_t)n * SDIM * ODIM + idx];
    }
    for (int idx = tid; idx < KDIM * SDIM; idx += 512)
        lseA[idx] = lse[(size_t)n * KDIM * SDIM + idx];
    if (tid < SDIM) { c0_s[tid] = c0g[n * SDIM + tid]; b_s[0][tid] = Dws[n * SDIM + tid]; }
    __syncthreads();

    const int rbase = (wave >= 1) ? (wave - 1) * 10 : 0;
    const int nrow  = (wave >= 1) ? ((SDIM - rbase) < 10 ? (SDIM - rbase) : 10) : 0;

    float er[10], raw0[10], raw1[10];
    if (wave >= 1) {
        const int a0 = a_s[0];
        const float* X0 = Xn + (size_t)a0 * SDIM * SDIM;
        const float* l0 = lseA + a0 * SDIM;
#pragma unroll
        for (int ii = 0; ii < 10; ++ii)
            if (ii < nrow) er[ii] = __expf(X0[(size_t)(rbase + ii) * SDIM + lane] - l0[rbase + ii]);
        const int a1 = a_s[1];
        const float* X1 = Xn + (size_t)a1 * SDIM * SDIM;
#pragma unroll
        for (int ii = 0; ii < 10; ++ii)
            if (ii < nrow) raw0[ii] = X1[(size_t)(rbase + ii) * SDIM + lane];
        const int a2 = a_s[2];
        const float* X2 = Xn + (size_t)a2 * SDIM * SDIM;
#pragma unroll
        for (int ii = 0; ii < 10; ++ii)
            if (ii < nrow) raw1[ii] = X2[(size_t)(rbase + ii) * SDIM + lane];
        if (wave <= 4) Z2PART(0, 0);
    }
    __syncthreads();

#pragma unroll 1
    for (int t = 0; t < TDIM; t += 2) {
        BSTEP(t, raw0);
        BSTEP(t + 1, raw1);
    }
}

// ------- VI: thread-owns-row, q streamed to global workspace -------
__global__ __launch_bounds__(512) void vi_kernel(
    const float* __restrict__ theta, const float* __restrict__ lse,
    const float* __restrict__ rws, float* __restrict__ q_ws)
{
    __shared__ float q_lds[KDIM * 68];
    __shared__ __align__(16) float v_lds[68];
    const int n = blockIdx.x, tid = threadIdx.x;
    const float* Xn = theta + (size_t)n * NP + 4096;

    const float l0  = lse[(size_t)n * 1024 + tid];
    const float l1  = lse[(size_t)n * 1024 + 512 + tid];
    const float rr0 = rws[(size_t)n * 1024 + tid];
    const float rr1 = rws[(size_t)n * 1024 + 512 + tid];

    float4 er0[16], er1[16];
    {
        const float* X0 = Xn + (size_t)tid * 64;
        const float* X1 = Xn + (size_t)(512 + tid) * 64;
#pragma unroll
        for (int j = 0; j < 16; ++j) {
            float4 x = *(const float4*)(X0 + j * 4);
            er0[j] = make_float4(__expf(x.x - l0), __expf(x.y - l0),
                                 __expf(x.z - l0), __expf(x.w - l0));
            float4 y = *(const float4*)(X1 + j * 4);
            er1[j] = make_float4(__expf(y.x - l1), __expf(y.y - l1),
                                 __expf(y.z - l1), __expf(y.w - l1));
        }
    }

    float qr0 = rr0, qr1 = rr1;
    float* qw = q_ws + (size_t)n * HDIM * 1024;
    const int kq0 = tid >> 6, iq = tid & 63;
    qw[tid] = qr0;
    qw[512 + tid] = qr1;
    q_lds[kq0 * 68 + iq] = qr0;
    q_lds[(8 + kq0) * 68 + iq] = qr1;
    __syncthreads();

#pragma unroll 1
    for (int h = 1; h < HDIM; ++h) {
        if (tid < 64) {
            float m = -1e30f;
#pragma unroll
            for (int k = 0; k < KDIM; ++k) m = fmaxf(m, q_lds[k * 68 + tid]);
            float s = 0.f;
#pragma unroll
            for (int k = 0; k < KDIM; ++k) s += __expf(q_lds[k * 68 + tid] - m);
            v_lds[tid] = m + __logf(s);
        }
        bar_lds();
        float a0x = 0.f, a0y = 0.f, a0z = 0.f, a0w = 0.f;
        float a1x = 0.f, a1y = 0.f, a1z = 0.f, a1w = 0.f;
#pragma unroll
        for (int jq = 0; jq < 16; ++jq) {
            const float4 v4 = *(const float4*)&v_lds[jq * 4];
            a0x += er0[jq].x * v4.x; a0y += er0[jq].y * v4.y;
            a0z += er0[jq].z * v4.z; a0w += er0[jq].w * v4.w;
            a1x += er1[jq].x * v4.x; a1y += er1[jq].y * v4.y;
            a1z += er1[jq].z * v4.z; a1w += er1[jq].w * v4.w;
        }
        qr0 = rr0 + ((a0x + a0y) + (a0z + a0w));
        qr1 = rr1 + ((a1x + a1y) + (a1z + a1w));
        qw[(size_t)h * 1024 + tid] = qr0;
        qw[(size_t)h * 1024 + 512 + tid] = qr1;
        q_lds[kq0 * 68 + iq] = qr0;
        q_lds[(8 + kq0) * 68 + iq] = qr1;
        bar_lds();
    }
}

// ------- policy (broadcast): block per n, thread (h,k) owns q-row in regs -------
// 2 t per barrier; waves 0-1 emit both t's same-iteration from double-buffered parts.
__global__ __launch_bounds__(512, 1) void policy_bc_kernel(
    const float* __restrict__ q_ws, const float* __restrict__ out_b_g,
    const float* __restrict__ pdfg, float* __restrict__ out_pi)
{
    __shared__ __align__(16) float b_all[TDIM * SDIM];   // 51,200 B
    __shared__ float part[2][2][8][16];
    __shared__ float pdf_s[32];

    const int n = blockIdx.x, tid = threadIdx.x;
    const int w = tid >> 6, lane = tid & 63;
    const int hl = lane >> 4, kk = lane & 15;
    const int hown = w * 4 + hl;                 // 0..31 (30,31 pad)
    const float* qn = q_ws + (size_t)n * HDIM * 1024;

    for (int idx = tid; idx < TDIM * 16; idx += 512) {
        const int t = idx >> 4, jq = idx & 15;
        *(float4*)&b_all[t * SDIM + jq * 4] =
            *(const float4*)&out_b_g[((size_t)t * NDIM + n) * SDIM + jq * 4];
    }
    if (tid < 32) pdf_s[tid] = (tid < HDIM) ? pdfg[n * HDIM + tid] : 0.f;

    float4 qrow[16];
    if (hown < HDIM) {
#pragma unroll
        for (int jq = 0; jq < 16; ++jq)
            qrow[jq] = *(const float4*)&qn[(size_t)hown * 1024 + kk * 64 + jq * 4];
    } else {
#pragma unroll
        for (int jq = 0; jq < 16; ++jq)
            qrow[jq] = make_float4(0.f, 0.f, 0.f, 0.f);
    }
    __syncthreads();
    const float pdfh = pdf_s[hown];

#define PVAL(T_, OUTV_) do {                                                   \
    const float* br_ = &b_all[(T_) * SDIM];                                    \
    float ax_ = 0.f, ay_ = 0.f, az_ = 0.f, aw_ = 0.f;                          \
    _Pragma("unroll")                                                          \
    for (int jq_ = 0; jq_ < 16; ++jq_) {                                       \
        const float4 b4_ = *(const float4*)&br_[jq_ * 4];                      \
        ax_ += qrow[jq_].x * b4_.x; ay_ += qrow[jq_].y * b4_.y;                \
        az_ += qrow[jq_].z * b4_.z; aw_ += qrow[jq_].w * b4_.w;                \
    }                                                                          \
    float acc_ = (ax_ + ay_) + (az_ + aw_);                                    \
    float m_ = acc_;                                                           \
    m_ = fmaxf(m_, __shfl_xor(m_, 1, 64));                                     \
    m_ = fmaxf(m_, __shfl_xor(m_, 2, 64));                                     \
    m_ = fmaxf(m_, __shfl_xor(m_, 4, 64));                                     \
    m_ = fmaxf(m_, __shfl_xor(m_, 8, 64));                                     \
    float e_ = __expf(acc_ - m_);                                              \
    float S_ = e_;                                                             \
    S_ += __shfl_xor(S_, 1, 64);                                               \
    S_ += __shfl_xor(S_, 2, 64);                                               \
    S_ += __shfl_xor(S_, 4, 64);                                               \
    S_ += __shfl_xor(S_, 8, 64);                                               \
    float v_ = pdfh * e_ / S_;                                                 \
    v_ += __shfl_xor(v_, 16, 64);                                              \
    v_ += __shfl_xor(v_, 32, 64);                                              \
    OUTV_ = v_;                                                                \
} while (0)

#pragma unroll 1
    for (int t0 = 0; t0 < TDIM; t0 += 2) {
        const int buf = (t0 >> 1) & 1;
        float v0, v1;
        PVAL(t0, v0);
        PVAL(t0 + 1, v1);
        if (lane < 16) {
            part[buf][0][w][lane] = v0;
            part[buf][1][w][lane] = v1;
        }
        bar_lds();
        if (w < 2 && lane < 16) {
            float s8 = 0.f;
#pragma unroll
            for (int ww = 0; ww < 8; ++ww) s8 += part[buf][w][ww][lane];
            out_pi[((size_t)(t0 + w) * NDIM + n) * KDIM + lane] = s8;
        }
    }
#undef PVAL
}

// ------- tier-3 fallback: fused VI+policy (no extra ws) -------
__global__ __launch_bounds__(512) void vi_policy_kernel(
    const float* __restrict__ theta, const float* __restrict__ lse,
    const float* __restrict__ rws, const float* __restrict__ pdfg,
    const float* __restrict__ out_b_g, float* __restrict__ out_pi)
{
    __shared__ __align__(16) float q_s[HDIM * KDIM * 68];
    __shared__ float r_s[KDIM * SDIM];
    __shared__ float lse_s[KDIM * SDIM];
    __shared__ __align__(16) float v_s[SDIM];
    __shared__ __align__(16) float b_lds[64 * 68];
    __shared__ float pdf_s[32];

    const int n = blockIdx.x, tid = threadIdx.x;
    const int wave = tid >> 6, lane = tid & 63;
    const int sub = lane & 15, rq = lane >> 4;
    const float* Xn = theta + (size_t)n * NP + 4096;

    for (int idx = tid; idx < KDIM * SDIM; idx += 512) {
        r_s[idx]   = rws[(size_t)n * KDIM * SDIM + idx];
        lse_s[idx] = lse[(size_t)n * KDIM * SDIM + idx];
    }
    if (tid < HDIM) pdf_s[tid] = pdfg[n * HDIM + tid];
    __syncthreads();

    for (int idx = tid; idx < KDIM * SDIM; idx += 512)
        q_s[(idx >> 6) * 68 + (idx & 63)] = r_s[idx];

    float4 breg[32];
#pragma unroll
    for (int it = 0; it < 32; ++it) {
        const int row = it * 32 + wave * 4 + rq;
        const float* xr = Xn + (size_t)row * SDIM + sub * 4;
        const float l = lse_s[row];
        breg[it] = make_float4(__expf(xr[0] - l), __expf(xr[1] - l),
                               __expf(xr[2] - l), __expf(xr[3] - l));
    }
    bar_lds();

#pragma unroll 1
    for (int h = 1; h < HDIM; ++h) {
        if (tid < SDIM) {
            const int base = (h - 1) * KDIM;
            float m = -1e30f;
#pragma unroll
            for (int k = 0; k < KDIM; ++k) m = fmaxf(m, q_s[(base + k) * 68 + tid]);
            float ssum = 0.f;
#pragma unroll
            for (int k = 0; k < KDIM; ++k) ssum += __expf(q_s[(base + k) * 68 + tid] - m);
            v_s[tid] = m + __logf(ssum);
        }
        bar_lds();
        const float4 v4 = *(const float4*)&v_s[sub * 4];
#pragma unroll
        for (int it = 0; it < 32; ++it) {
            const int row = it * 32 + wave * 4 + rq;
            float acc = breg[it].x * v4.x + breg[it].y * v4.y
                      + breg[it].z * v4.z + breg[it].w * v4.w;
            acc += __shfl_xor(acc, 1, 64);
            acc += __shfl_xor(acc, 2, 64);
            acc += __shfl_xor(acc, 4, 64);
            acc += __shfl_xor(acc, 8, 64);
            if (sub == 0)
                q_s[(h * KDIM + (row >> 6)) * 68 + (row & 63)] = r_s[row] + acc;
        }
        bar_lds();
    }

    const int tc = tid >> 4, kk = tid & 15;
#pragma unroll 1
    for (int t0 = 0; t0 < TDIM; t0 += 64) {
        const int nt = (TDIM - t0) < 64 ? (TDIM - t0) : 64;
        for (int idx = tid; idx < nt * 16; idx += 512) {
            const int row = idx >> 4, jq = idx & 15;
            *(float4*)&b_lds[row * 68 + jq * 4] =
                *(const float4*)&out_b_g[(((size_t)(t0 + row)) * NDIM + n) * SDIM + jq * 4];
        }
        bar_lds();
        const bool vA = tc < nt, vB = (tc + 32) < nt;
        float4 bqA[16], bqB[16];
        if (vA) {
#pragma unroll
            for (int jq = 0; jq < 16; ++jq)
                bqA[jq] = *(const float4*)&b_lds[tc * 68 + jq * 4];
        }
        if (vB) {
#pragma unroll
            for (int jq = 0; jq < 16; ++jq)
                bqB[jq] = *(const float4*)&b_lds[(tc + 32) * 68 + jq * 4];
        }
        float pikA = 0.f, pikB = 0.f;
#pragma unroll 1
        for (int h = 0; h < HDIM; ++h) {
            const float* qr = &q_s[(h * KDIM + kk) * 68];
            float aA = 0.f, aB = 0.f;
#pragma unroll
            for (int jq = 0; jq < 16; ++jq) {
                const float4 qv = *(const float4*)&qr[jq * 4];
                if (vA) aA += qv.x * bqA[jq].x + qv.y * bqA[jq].y
                            + qv.z * bqA[jq].z + qv.w * bqA[jq].w;
                if (vB) aB += qv.x * bqB[jq].x + qv.y * bqB[jq].y
                            + qv.z * bqB[jq].z + qv.w * bqB[jq].w;
            }
            float mA = aA, mB = aB;
            mA = fmaxf(mA, __shfl_xor(mA, 1, 64));
            mA = fmaxf(mA, __shfl_xor(mA, 2, 64));
            mA = fmaxf(mA, __shfl_xor(mA, 4, 64));
            mA = fmaxf(mA, __shfl_xor(mA, 8, 64));
            mB = fmaxf(mB, __shfl_xor(mB, 1, 64));
            mB = fmaxf(mB, __shfl_xor(mB, 2, 64));
            mB = fmaxf(mB, __shfl_xor(mB, 4, 64));
            mB = fmaxf(mB, __shfl_xor(mB, 8, 64));
            float eA = __expf(aA - mA), eB = __expf(aB - mB);
            float SA = eA, SB = eB;
            SA += __shfl_xor(SA, 1, 64);
            SA += __shfl_xor(SA, 2, 64);
            SA += __shfl_xor(SA, 4, 64);
            SA += __shfl_xor(SA, 8, 64);
            SB += __shfl_xor(SB, 1, 64);
            SB += __shfl_xor(SB, 2, 64);
            SB += __shfl_xor(SB, 4, 64);
            SB += __shfl_xor(SB, 8, 64);
            const float ph = pdf_s[h];
            pikA += ph * eA / SA;
            pikB += ph * eB / SB;
        }
        if (vA) out_pi[(((size_t)(t0 + tc)) * NDIM + n) * KDIM + kk] = pikA;
        if (vB) out_pi[(((size_t)(t0 + 32 + tc)) * NDIM + n) * KDIM + kk] = pikB;
        bar_lds();
    }
}

extern "C" void kernel_launch(void* const* d_in, const int* in_sizes, int n_in,
                              void* d_out, int out_size, void* d_ws, size_t ws_size,
                              hipStream_t stream) {
    (void)in_sizes; (void)n_in; (void)out_size;
    const float* o     = (const float*)d_in[0];
    const int*   a     = (const int*)d_in[1];
    const float* theta = (const float*)d_in[2];
    float* out = (float*)d_out;
    float* ws  = (float*)d_ws;

    float* lse    = ws;                                   // N*K*S
    float* rws    = lse    + (size_t)NDIM * KDIM * SDIM;  // N*K*S
    float* invstd = rws    + (size_t)NDIM * KDIM * SDIM;  // N*S*O
    float* c0     = invstd + (size_t)NDIM * SDIM * ODIM;  // N*S
    float* ent    = c0     + (size_t)NDIM * SDIM;         // N*S
    float* logC   = ent    + (size_t)NDIM * SDIM;         // N*S
    float* Dws    = logC   + (size_t)NDIM * SDIM;         // N*S
    float* pdfws  = Dws    + (size_t)NDIM * SDIM;         // N*H
    float* q_ws   = pdfws  + (size_t)NDIM * HDIM;         // N*H*K*S f32 (63 MB)
    __hip_bfloat16* bn = (__hip_bfloat16*)(q_ws + (size_t)NDIM * HDIM * KDIM * SDIM);

    const size_t f_base = (size_t)NDIM * KDIM * SDIM * 2
                        + (size_t)NDIM * SDIM * ODIM
                        + (size_t)NDIM * SDIM * 4
                        + (size_t)NDIM * HDIM;
    const size_t f_q  = (size_t)NDIM * HDIM * KDIM * SDIM;
    const size_t need2 = (f_base + f_q) * 4;                       // ~72 MB
    const size_t need1 = need2 + (size_t)NDIM * KDIM * SDIM * SDIM * 2; // ~139 MB

    float* out_pi = out;
    float* out_b  = out + (size_t)TDIM * NDIM * KDIM;
    float* out_lp = out + (size_t)TDIM * NDIM * KDIM + (size_t)TDIM * NDIM * SDIM;

    transform_kernel<<<NDIM, 256, 0, stream>>>(theta, invstd, c0, ent, logC, Dws, pdfws);

    if (ws_size >= need1) {
        row_stats_kernel<<<(NDIM * KDIM * SDIM) / 4, 256, 0, stream>>>(
            theta, logC, ent, lse, rws, bn);
        belief_sym_kernel<<<NDIM, 512, 0, stream>>>(
            o, a, theta, bn, invstd, c0, Dws, out_b, out_lp);
        vi_kernel<<<NDIM, 512, 0, stream>>>(theta, lse, rws, q_ws);
        policy_bc_kernel<<<NDIM, 512, 0, stream>>>(q_ws, out_b, pdfws, out_pi);
    } else if (ws_size >= need2) {
        row_stats_kernel<<<(NDIM * KDIM * SDIM) / 4, 256, 0, stream>>>(
            theta, logC, ent, lse, rws, (__hip_bfloat16*)nullptr);
        belief_kernel<<<NDIM, 512, 0, stream>>>(
            o, a, theta, lse, invstd, c0, Dws, out_b, out_lp);
        vi_kernel<<<NDIM, 512, 0, stream>>>(theta, lse, rws, q_ws);
        policy_bc_kernel<<<NDIM, 512, 0, stream>>>(q_ws, out_b, pdfws, out_pi);
    } else {
        row_stats_kernel<<<(NDIM * KDIM * SDIM) / 4, 256, 0, stream>>>(
            theta, logC, ent, lse, rws, (__hip_bfloat16*)nullptr);
        belief_kernel<<<NDIM, 512, 0, stream>>>(
            o, a, theta, lse, invstd, c0, Dws, out_b, out_lp);
        vi_policy_kernel<<<NDIM, 512, 0, stream>>>(theta, lse, rws, pdfws, out_b, out_pi);
    }
}

// Round 15
// 643.404 us; speedup vs baseline: 1.7936x; 1.0242x over previous
//
#include <hip/hip_runtime.h>
#include <hip/hip_bf16.h>
#include <math.h>

#define SDIM 64
#define KDIM 16
#define ODIM 32
#define HDIM 30
#define TDIM 200
#define NDIM 512
#define NP 69761
#define EPSV 1e-6f
#define LOG2PIF 1.8378770664093453f

__device__ __forceinline__ float softplusf(float x) {
    return (x > 0.f) ? x + log1pf(expf(-x)) : log1pf(expf(x));
}
__device__ __forceinline__ float wave_max64(float v) {
#pragma unroll
    for (int off = 32; off; off >>= 1) v = fmaxf(v, __shfl_xor(v, off, 64));
    return v;
}
__device__ __forceinline__ float wave_sum64(float v) {
#pragma unroll
    for (int off = 32; off; off >>= 1) v += __shfl_xor(v, off, 64);
    return v;
}
// barrier that waits only on LDS ops — leaves global loads/stores in flight
__device__ __forceinline__ void bar_lds() {
    asm volatile("s_waitcnt lgkmcnt(0)\n\ts_barrier" ::: "memory");
}

// ---------------- kernel 1: per-n parameter transforms ----------------
__global__ __launch_bounds__(256) void transform_kernel(
    const float* __restrict__ theta, float* __restrict__ invstd,
    float* __restrict__ c0, float* __restrict__ ent,
    float* __restrict__ logC, float* __restrict__ Dws,
    float* __restrict__ pdfws)
{
    __shared__ float ls[SDIM * 33];
    const int n = blockIdx.x, tid = threadIdx.x;
    const float* thn = theta + (size_t)n * NP;

    for (int idx = tid; idx < SDIM * ODIM; idx += 256) {
        float x = thn[2048 + idx];
        float sp = softplusf(x) + EPSV;            // A_std
        invstd[(size_t)n * SDIM * ODIM + idx] = 1.f / sp;
        int s = idx >> 5, oo = idx & 31;
        ls[s * 33 + oo] = logf(sp);
    }
    __syncthreads();

    const int wave = tid >> 6, lane = tid & 63;
    if (wave == 0) {                                // c0, ent per state s
        float sum = 0.f;
#pragma unroll
        for (int oo = 0; oo < ODIM; ++oo) sum += ls[lane * 33 + oo];
        c0[n * SDIM + lane]  = -sum - 16.f * LOG2PIF;
        ent[n * SDIM + lane] =  sum + 32.f * (0.5f + 0.5f * LOG2PIF);
    } else if (wave == 1) {                         // log(C + eps)
        float x = thn[69632 + lane];
        float m = wave_max64(x);
        float e = expf(x - m);
        float ssum = wave_sum64(e);
        logC[n * SDIM + lane] = logf(e / ssum + EPSV);
    } else if (wave == 2) {                         // D = softmax(tD)
        float x = thn[69696 + lane];
        float m = wave_max64(x);
        float e = expf(x - m);
        float ssum = wave_sum64(e);
        Dws[n * SDIM + lane] = e / ssum;
    } else {                                        // truncated poisson pdf
        float tt = thn[69760];
        float tau = 60.f / (1.f + expf(-tt)) + 1.f;
        float p = 0.f;
        if (lane < HDIM)
            p = expf((float)lane * logf(tau) - tau - lgammaf((float)lane + 1.f));
        float ssum = wave_sum64(p);
        if (lane < HDIM) pdfws[n * HDIM + lane] = p / ssum;
    }
}

// ---- kernel 2: per-row B softmax stats + reward; optional packed bf16 B ----
__global__ __launch_bounds__(256) void row_stats_kernel(
    const float* __restrict__ theta, const float* __restrict__ logC,
    const float* __restrict__ ent, float* __restrict__ lse,
    float* __restrict__ rws, __hip_bfloat16* __restrict__ bn)
{
    const int gw = blockIdx.x * 4 + (threadIdx.x >> 6);  // global row (n,k,i)
    const int lane = threadIdx.x & 63;
    const int n = gw >> 10, rl = gw & 1023;
    float x = theta[(size_t)n * NP + 4096 + (size_t)rl * 64 + lane];
    float m = wave_max64(x);
    float e = expf(x - m);
    float ssum = wave_sum64(e);
    float Bj = e / ssum;
    if (bn) {
        const int k = rl >> 6, i = rl & 63;
        __hip_bfloat16 h = __float2bfloat16(Bj);
        unsigned short bits;
        __builtin_memcpy(&bits, &h, 2);
        ((unsigned short*)bn)[(size_t)n * KDIM * SDIM * SDIM
            + (size_t)k * 4096 + (size_t)(i >> 1) * 128 + lane * 2 + (i & 1)] = bits;
    }
    float contrib = Bj * (logf(Bj + EPSV) - logC[n * SDIM + lane] + ent[n * SDIM + lane]);
    contrib = wave_sum64(contrib);
    if (lane == 0) {
        lse[gw] = m + logf(ssum);
        rws[gw] = -contrib;
    }
}

// ===== TIER-1 belief: 4 waves, b register-redundant (shfl), 1 barrier/step =====
// wave owns rows rbase..rbase+15; ecz pipelined one step ahead (off arrival path).
#define BS4(T_, U_) do {                                                       \
    const int cur_ = (T_) & 1, nxt_ = cur_ ^ 1;                                \
    if (wave == 3) out_b[((size_t)(T_) * NDIM + n) * SDIM + lane] = bval;      \
    {   /* matvec via shfl-distributed b (b_t in regs, no LDS round-trip) */   \
        float a0_ = 0.f, a1_ = 0.f, a2_ = 0.f, a3_ = 0.f;                      \
        _Pragma("unroll")                                                      \
        for (int j_ = 0; j_ < 4; ++j_) {                                       \
            a0_ += er[4 * j_ + 0] * __shfl(bval, rbase + 4 * j_ + 0, 64);      \
            a1_ += er[4 * j_ + 1] * __shfl(bval, rbase + 4 * j_ + 1, 64);      \
            a2_ += er[4 * j_ + 2] * __shfl(bval, rbase + 4 * j_ + 2, 64);      \
            a3_ += er[4 * j_ + 3] * __shfl(bval, rbase + 4 * j_ + 3, 64);      \
        }                                                                      \
        part_s[cur_][wave][lane] = (a0_ + a1_) + (a2_ + a3_);                  \
    }                                                                          \
    if ((T_) + 1 < TDIM) {               /* z2 partial for t+1 */              \
        const float* om_ = &o_s[((T_) + 1) * ODIM + ob];                       \
        float zz_ = 0.f;                                                       \
        _Pragma("unroll")                                                      \
        for (int j_ = 0; j_ < 8; ++j_) {                                       \
            float z_ = (om_[j_] - mean_r[j_]) * istd_r[j_];                    \
            zz_ += z_ * z_;                                                    \
        }                                                                      \
        z2p_s[nxt_][wave][lane] = zz_;                                         \
    }                                                                          \
    _Pragma("unroll")                     /* unpack next-step B rows */        \
    for (int m_ = 0; m_ < 8; ++m_) {                                           \
        er[2 * m_]     = __uint_as_float(U_[m_] << 16);                        \
        er[2 * m_ + 1] = __uint_as_float(U_[m_] & 0xffff0000u);                \
    }                                                                          \
    {   /* prefetch B(a_{T+3}) */                                              \
        const int tl_ = ((T_) + 3 < TDIM) ? (T_) + 3 : TDIM - 1;               \
        const uint* up_ = bnn32 + (size_t)a_s[tl_] * 2048 + (rbase >> 1) * 64 + lane; \
        _Pragma("unroll")                                                      \
        for (int m_ = 0; m_ < 8; ++m_) U_[m_] = up_[m_ * 64];                  \
    }                                                                          \
    bar_lds();                           /* the ONE barrier */                 \
    {   /* redundant update (x4) + pipelined ecz(t+1), ILP-parallel */         \
        float sv_ = part_s[cur_][0][lane] + part_s[cur_][1][lane]              \
                  + part_s[cur_][2][lane] + part_s[cur_][3][lane];             \
        float u_ = (sv_ + EPSV) * ecz_cur;                                     \
        float S_ = wave_sum64(u_);                                             \
        if (wave == 0 && lane == 0)                                            \
            out_lp[(size_t)(T_) * NDIM + n] = cm_cur + __logf(S_);             \
        bval = u_ / S_;                                                        \
        float z2n_ = z2p_s[nxt_][0][lane] + z2p_s[nxt_][1][lane]               \
                   + z2p_s[nxt_][2][lane] + z2p_s[nxt_][3][lane];              \
        float cn_ = c0_r - 0.5f * z2n_;                                        \
        cm_cur = wave_max64(cn_);                                              \
        ecz_cur = __expf(cn_ - cm_cur);                                        \
    }                                                                          \
} while (0)

__global__ __launch_bounds__(256) void belief4_kernel(
    const float* __restrict__ o, const int* __restrict__ a,
    const float* __restrict__ theta, const __hip_bfloat16* __restrict__ bn,
    const float* __restrict__ invstd, const float* __restrict__ c0g,
    const float* __restrict__ Dws,
    float* __restrict__ out_b, float* __restrict__ out_lp)
{
    __shared__ float o_s[TDIM * ODIM];       // 25.6 KB
    __shared__ int   a_s[TDIM];
    __shared__ float mean_s[SDIM * 33];
    __shared__ float istd_s[SDIM * 33];
    __shared__ float c0_sh[SDIM];
    __shared__ float part_s[2][4][68];
    __shared__ float z2p_s[2][4][SDIM];

    const int n = blockIdx.x, tid = threadIdx.x;
    const int wave = tid >> 6, lane = tid & 63;
    const int rbase = wave * 16, ob = wave * 8;
    const float* thn = theta + (size_t)n * NP;
    const uint* bnn32 = (const uint*)(bn + (size_t)n * KDIM * SDIM * SDIM);

    for (int idx = tid; idx < TDIM * ODIM; idx += 256)
        o_s[idx] = o[((size_t)(idx >> 5) * NDIM + n) * ODIM + (idx & 31)];
    if (tid < TDIM) a_s[tid] = a[tid * NDIM + n];
    for (int idx = tid; idx < SDIM * ODIM; idx += 256) {
        int s = idx >> 5, oo = idx & 31;
        mean_s[s * 33 + oo] = thn[idx];
        istd_s[s * 33 + oo] = invstd[(size_t)n * SDIM * ODIM + idx];
    }
    if (tid < SDIM) c0_sh[tid] = c0g[n * SDIM + tid];
    __syncthreads();

    const float c0_r = c0_sh[lane];
    float bval = Dws[n * SDIM + lane];
    float mean_r[8], istd_r[8];
#pragma unroll
    for (int j = 0; j < 8; ++j) {
        mean_r[j] = mean_s[lane * 33 + ob + j];
        istd_r[j] = istd_s[lane * 33 + ob + j];
    }

    float er[16];
    uint u0[8], u1[8];
    {   // prologue: er <- B(a_0); u0 <- B(a_1); u1 <- B(a_2)
        const uint* p0 = bnn32 + (size_t)a_s[0] * 2048 + (rbase >> 1) * 64 + lane;
#pragma unroll
        for (int m = 0; m < 8; ++m) u0[m] = p0[m * 64];
#pragma unroll
        for (int m = 0; m < 8; ++m) {
            er[2 * m]     = __uint_as_float(u0[m] << 16);
            er[2 * m + 1] = __uint_as_float(u0[m] & 0xffff0000u);
        }
        const uint* p1 = bnn32 + (size_t)a_s[1] * 2048 + (rbase >> 1) * 64 + lane;
#pragma unroll
        for (int m = 0; m < 8; ++m) u0[m] = p1[m * 64];
        const uint* p2 = bnn32 + (size_t)a_s[2] * 2048 + (rbase >> 1) * 64 + lane;
#pragma unroll
        for (int m = 0; m < 8; ++m) u1[m] = p2[m * 64];
    }
    {   // z2p for t=0
        const float* om = &o_s[ob];
        float zz = 0.f;
#pragma unroll
        for (int j = 0; j < 8; ++j) {
            float z = (om[j] - mean_r[j]) * istd_r[j];
            zz += z * z;
        }
        z2p_s[0][wave][lane] = zz;
    }
    __syncthreads();
    float ecz_cur, cm_cur;
    {   // ecz(0)
        float z2 = z2p_s[0][0][lane] + z2p_s[0][1][lane]
                 + z2p_s[0][2][lane] + z2p_s[0][3][lane];
        float c = c0_r - 0.5f * z2;
        cm_cur = wave_max64(c);
        ecz_cur = __expf(c - cm_cur);
    }

#pragma unroll 1
    for (int t = 0; t < TDIM; t += 2) {
        BS4(t, u0);
        BS4(t + 1, u1);
    }
}

// ===================== TIER-2/3 belief (f32 logits + exp) =====================
#define Z2PART(TT_, BUF_) do {                                                 \
    const int ob_ = (wave - 1) * 8;                                            \
    const float* om_ = &o_s[(TT_) * ODIM + ob_];                               \
    float zz_ = 0.f;                                                           \
    _Pragma("unroll")                                                          \
    for (int j_ = 0; j_ < 8; ++j_) {                                           \
        float z_ = (om_[j_] - mean_s[lane * 33 + ob_ + j_])                    \
                 * istd_s[lane * 33 + ob_ + j_];                               \
        zz_ += z_ * z_;                                                        \
    }                                                                          \
    z2p_s[BUF_][wave - 1][lane] = zz_;                                         \
} while (0)

#define BSTEP(T_, RAW_) do {                                                   \
    const int cur_ = (T_) & 1, nxt_ = cur_ ^ 1;                                \
    if (wave >= 1) {                                                           \
        float acc_ = 0.f;                                                      \
        _Pragma("unroll")                                                      \
        for (int ii = 0; ii < 10; ++ii)                                        \
            if (ii < nrow) acc_ += er[ii] * b_s[cur_][rbase + ii];             \
        part_s[wave - 1][lane] = acc_;                                         \
        if (wave == 6) out_b[((size_t)(T_) * NDIM + n) * SDIM + lane] = b_s[cur_][lane]; \
    }                                                                          \
    bar_lds();                                                                 \
    if (wave == 0) {                                                           \
        float sv_ = part_s[0][lane] + part_s[1][lane] + part_s[2][lane]        \
                  + part_s[3][lane] + part_s[4][lane] + part_s[5][lane]        \
                  + part_s[6][lane];                                           \
        float z2_ = z2p_s[cur_][0][lane] + z2p_s[cur_][1][lane]                \
                  + z2p_s[cur_][2][lane] + z2p_s[cur_][3][lane];               \
        float joint_ = __logf(sv_ + EPSV) + c0_s[lane] - 0.5f * z2_;           \
        float m_ = wave_max64(joint_);                                         \
        float e_ = __expf(joint_ - m_);                                        \
        float ss_ = wave_sum64(e_);                                            \
        b_s[nxt_][lane] = e_ / ss_;                                            \
        if (lane == 0) out_lp[(size_t)(T_) * NDIM + n] = m_ + __logf(ss_);     \
    } else {                                                                   \
        if ((T_) + 1 < TDIM) {                                                 \
            const int an_ = a_s[(T_) + 1];                                     \
            const float* ln_ = lseA + an_ * SDIM;                              \
            _Pragma("unroll")                                                  \
            for (int ii = 0; ii < 10; ++ii)                                    \
                if (ii < nrow) er[ii] = __expf(RAW_[ii] - ln_[rbase + ii]);    \
            if (wave <= 4) Z2PART((T_) + 1, nxt_);                             \
        }                                                                      \
        const int tl_ = ((T_) + 3 < TDIM) ? (T_) + 3 : TDIM - 1;               \
        const int a3_ = a_s[tl_];                                              \
        const float* X3_ = Xn + (size_t)a3_ * SDIM * SDIM;                     \
        _Pragma("unroll")                                                      \
        for (int ii = 0; ii < 10; ++ii)                                        \
            if (ii < nrow) RAW_[ii] = X3_[(size_t)(rbase + ii) * SDIM + lane]; \
    }                                                                          \
    bar_lds();                                                                 \
} while (0)

__global__ __launch_bounds__(512) void belief_kernel(
    const float* __restrict__ o, const int* __restrict__ a,
    const float* __restrict__ theta, const float* __restrict__ lse,
    const float* __restrict__ invstd, const float* __restrict__ c0g,
    const float* __restrict__ Dws,
    float* __restrict__ out_b, float* __restrict__ out_lp)
{
    __shared__ float o_s[TDIM * ODIM];
    __shared__ int   a_s[TDIM];
    __shared__ float mean_s[SDIM * 33];
    __shared__ float istd_s[SDIM * 33];
    __shared__ float lseA[KDIM * SDIM];
    __shared__ float c0_s[SDIM];
    __shared__ float b_s[2][SDIM];
    __shared__ float part_s[7][68];
    __shared__ float z2p_s[2][4][SDIM];

    const int n = blockIdx.x, tid = threadIdx.x;
    const int wave = tid >> 6, lane = tid & 63;
    const float* thn = theta + (size_t)n * NP;
    const float* Xn  = thn + 4096;

    for (int idx = tid; idx < TDIM * ODIM; idx += 512)
        o_s[idx] = o[((size_t)(idx >> 5) * NDIM + n) * ODIM + (idx & 31)];
    if (tid < TDIM) a_s[tid] = a[tid * NDIM + n];
    for (int idx = tid; idx < SDIM * ODIM; idx += 512) {
        int s = idx >> 5, oo = idx & 31;
        mean_s[s * 33 + oo] = thn[idx];
        istd_s[s * 33 + oo] = invstd[(size_t)n * SDIM * ODIM + idx];
    }
    for (int idx = tid; idx < KDIM * SDIM; idx += 512)
        lseA[idx] = lse[(size_t)n * KDIM * SDIM + idx];
    if (tid < SDIM) { c0_s[tid] = c0g[n * SDIM + tid]; b_s[0][tid] = Dws[n * SDIM + tid]; }
    __syncthreads();

    const int rbase = (wave >= 1) ? (wave - 1) * 10 : 0;
    const int nrow  = (wave >= 1) ? ((SDIM - rbase) < 10 ? (SDIM - rbase) : 10) : 0;

    float er[10], raw0[10], raw1[10];
    if (wave >= 1) {
        const int a0 = a_s[0];
        const float* X0 = Xn + (size_t)a0 * SDIM * SDIM;
        const float* l0 = lseA + a0 * SDIM;
#pragma unroll
        for (int ii = 0; ii < 10; ++ii)
            if (ii < nrow) er[ii] = __expf(X0[(size_t)(rbase + ii) * SDIM + lane] - l0[rbase + ii]);
        const int a1 = a_s[1];
        const float* X1 = Xn + (size_t)a1 * SDIM * SDIM;
#pragma unroll
        for (int ii = 0; ii < 10; ++ii)
            if (ii < nrow) raw0[ii] = X1[(size_t)(rbase + ii) * SDIM + lane];
        const int a2 = a_s[2];
        const float* X2 = Xn + (size_t)a2 * SDIM * SDIM;
#pragma unroll
        for (int ii = 0; ii < 10; ++ii)
            if (ii < nrow) raw1[ii] = X2[(size_t)(rbase + ii) * SDIM + lane];
        if (wave <= 4) Z2PART(0, 0);
    }
    __syncthreads();

#pragma unroll 1
    for (int t = 0; t < TDIM; t += 2) {
        BSTEP(t, raw0);
        BSTEP(t + 1, raw1);
    }
}

// ------- VI: thread-owns-row, q streamed to global workspace -------
__global__ __launch_bounds__(512) void vi_kernel(
    const float* __restrict__ theta, const float* __restrict__ lse,
    const float* __restrict__ rws, float* __restrict__ q_ws)
{
    __shared__ float q_lds[KDIM * 68];
    __shared__ __align__(16) float v_lds[68];
    const int n = blockIdx.x, tid = threadIdx.x;
    const float* Xn = theta + (size_t)n * NP + 4096;

    const float l0  = lse[(size_t)n * 1024 + tid];
    const float l1  = lse[(size_t)n * 1024 + 512 + tid];
    const float rr0 = rws[(size_t)n * 1024 + tid];
    const float rr1 = rws[(size_t)n * 1024 + 512 + tid];

    float4 er0[16], er1[16];
    {
        const float* X0 = Xn + (size_t)tid * 64;
        const float* X1 = Xn + (size_t)(512 + tid) * 64;
#pragma unroll
        for (int j = 0; j < 16; ++j) {
            float4 x = *(const float4*)(X0 + j * 4);
            er0[j] = make_float4(__expf(x.x - l0), __expf(x.y - l0),
                                 __expf(x.z - l0), __expf(x.w - l0));
            float4 y = *(const float4*)(X1 + j * 4);
            er1[j] = make_float4(__expf(y.x - l1), __expf(y.y - l1),
                                 __expf(y.z - l1), __expf(y.w - l1));
        }
    }

    float qr0 = rr0, qr1 = rr1;
    float* qw = q_ws + (size_t)n * HDIM * 1024;
    const int kq0 = tid >> 6, iq = tid & 63;
    qw[tid] = qr0;
    qw[512 + tid] = qr1;
    q_lds[kq0 * 68 + iq] = qr0;
    q_lds[(8 + kq0) * 68 + iq] = qr1;
    __syncthreads();

#pragma unroll 1
    for (int h = 1; h < HDIM; ++h) {
        if (tid < 64) {
            float m = -1e30f;
#pragma unroll
            for (int k = 0; k < KDIM; ++k) m = fmaxf(m, q_lds[k * 68 + tid]);
            float s = 0.f;
#pragma unroll
            for (int k = 0; k < KDIM; ++k) s += __expf(q_lds[k * 68 + tid] - m);
            v_lds[tid] = m + __logf(s);
        }
        bar_lds();
        float a0x = 0.f, a0y = 0.f, a0z = 0.f, a0w = 0.f;
        float a1x = 0.f, a1y = 0.f, a1z = 0.f, a1w = 0.f;
#pragma unroll
        for (int jq = 0; jq < 16; ++jq) {
            const float4 v4 = *(const float4*)&v_lds[jq * 4];
            a0x += er0[jq].x * v4.x; a0y += er0[jq].y * v4.y;
            a0z += er0[jq].z * v4.z; a0w += er0[jq].w * v4.w;
            a1x += er1[jq].x * v4.x; a1y += er1[jq].y * v4.y;
            a1z += er1[jq].z * v4.z; a1w += er1[jq].w * v4.w;
        }
        qr0 = rr0 + ((a0x + a0y) + (a0z + a0w));
        qr1 = rr1 + ((a1x + a1y) + (a1z + a1w));
        qw[(size_t)h * 1024 + tid] = qr0;
        qw[(size_t)h * 1024 + 512 + tid] = qr1;
        q_lds[kq0 * 68 + iq] = qr0;
        q_lds[(8 + kq0) * 68 + iq] = qr1;
        bar_lds();
    }
}

// ------- policy (broadcast): thread (h,k) owns q-row; 8 t per barrier -------
__global__ __launch_bounds__(512, 1) void policy_bc_kernel(
    const float* __restrict__ q_ws, const float* __restrict__ out_b_g,
    const float* __restrict__ pdfg, float* __restrict__ out_pi)
{
    __shared__ __align__(16) float b_all[TDIM * SDIM];   // 51,200 B
    __shared__ float part[2][8][8][17];                  // [buf][tt][wave][k]
    __shared__ float pdf_s[32];

    const int n = blockIdx.x, tid = threadIdx.x;
    const int w = tid >> 6, lane = tid & 63;
    const int hl = lane >> 4, kk = lane & 15;
    const int hown = w * 4 + hl;                 // 0..31 (30,31 pad)
    const float* qn = q_ws + (size_t)n * HDIM * 1024;

    for (int idx = tid; idx < TDIM * 16; idx += 512) {
        const int t = idx >> 4, jq = idx & 15;
        *(float4*)&b_all[t * SDIM + jq * 4] =
            *(const float4*)&out_b_g[((size_t)t * NDIM + n) * SDIM + jq * 4];
    }
    if (tid < 32) pdf_s[tid] = (tid < HDIM) ? pdfg[n * HDIM + tid] : 0.f;

    float4 qrow[16];
    if (hown < HDIM) {
#pragma unroll
        for (int jq = 0; jq < 16; ++jq)
            qrow[jq] = *(const float4*)&qn[(size_t)hown * 1024 + kk * 64 + jq * 4];
    } else {
#pragma unroll
        for (int jq = 0; jq < 16; ++jq)
            qrow[jq] = make_float4(0.f, 0.f, 0.f, 0.f);
    }
    __syncthreads();
    const float pdfh = pdf_s[hown];

#define PVAL(T_, OUTV_) do {                                                   \
    const float* br_ = &b_all[(T_) * SDIM];                                    \
    float ax_ = 0.f, ay_ = 0.f, az_ = 0.f, aw_ = 0.f;                          \
    _Pragma("unroll")                                                          \
    for (int jq_ = 0; jq_ < 16; ++jq_) {                                       \
        const float4 b4_ = *(const float4*)&br_[jq_ * 4];                      \
        ax_ += qrow[jq_].x * b4_.x; ay_ += qrow[jq_].y * b4_.y;                \
        az_ += qrow[jq_].z * b4_.z; aw_ += qrow[jq_].w * b4_.w;                \
    }                                                                          \
    float acc_ = (ax_ + ay_) + (az_ + aw_);                                    \
    float m_ = acc_;                                                           \
    m_ = fmaxf(m_, __shfl_xor(m_, 1, 64));                                     \
    m_ = fmaxf(m_, __shfl_xor(m_, 2, 64));                                     \
    m_ = fmaxf(m_, __shfl_xor(m_, 4, 64));                                     \
    m_ = fmaxf(m_, __shfl_xor(m_, 8, 64));                                     \
    float e_ = __expf(acc_ - m_);                                              \
    float S_ = e_;                                                             \
    S_ += __shfl_xor(S_, 1, 64);                                               \
    S_ += __shfl_xor(S_, 2, 64);                                               \
    S_ += __shfl_xor(S_, 4, 64);                                               \
    S_ += __shfl_xor(S_, 8, 64);                                               \
    float v_ = pdfh * e_ / S_;                                                 \
    v_ += __shfl_xor(v_, 16, 64);                                              \
    v_ += __shfl_xor(v_, 32, 64);                                              \
    OUTV_ = v_;                                                                \
} while (0)

#pragma unroll 1
    for (int t0 = 0; t0 < TDIM; t0 += 8) {       // 25 groups, 1 barrier each
        const int buf = (t0 >> 3) & 1;
        float v0, v1, v2, v3, v4, v5, v6, v7;
        PVAL(t0 + 0, v0); PVAL(t0 + 1, v1); PVAL(t0 + 2, v2); PVAL(t0 + 3, v3);
        PVAL(t0 + 4, v4); PVAL(t0 + 5, v5); PVAL(t0 + 6, v6); PVAL(t0 + 7, v7);
        if (lane < 16) {
            part[buf][0][w][lane] = v0; part[buf][1][w][lane] = v1;
            part[buf][2][w][lane] = v2; part[buf][3][w][lane] = v3;
            part[buf][4][w][lane] = v4; part[buf][5][w][lane] = v5;
            part[buf][6][w][lane] = v6; part[buf][7][w][lane] = v7;
        }
        bar_lds();
        if (lane < 16) {                         // wave w emits t0 + w
            float s8 = 0.f;
#pragma unroll
            for (int ww = 0; ww < 8; ++ww) s8 += part[buf][w][ww][lane];
            out_pi[((size_t)(t0 + w) * NDIM + n) * KDIM + lane] = s8;
        }
    }
#undef PVAL
}

// ------- tier-3 fallback: fused VI+policy (no extra ws) -------
__global__ __launch_bounds__(512) void vi_policy_kernel(
    const float* __restrict__ theta, const float* __restrict__ lse,
    const float* __restrict__ rws, const float* __restrict__ pdfg,
    const float* __restrict__ out_b_g, float* __restrict__ out_pi)
{
    __shared__ __align__(16) float q_s[HDIM * KDIM * 68];
    __shared__ float r_s[KDIM * SDIM];
    __shared__ float lse_s[KDIM * SDIM];
    __shared__ __align__(16) float v_s[SDIM];
    __shared__ __align__(16) float b_lds[64 * 68];
    __shared__ float pdf_s[32];

    const int n = blockIdx.x, tid = threadIdx.x;
    const int wave = tid >> 6, lane = tid & 63;
    const int sub = lane & 15, rq = lane >> 4;
    const float* Xn = theta + (size_t)n * NP + 4096;

    for (int idx = tid; idx < KDIM * SDIM; idx += 512) {
        r_s[idx]   = rws[(size_t)n * KDIM * SDIM + idx];
        lse_s[idx] = lse[(size_t)n * KDIM * SDIM + idx];
    }
    if (tid < HDIM) pdf_s[tid] = pdfg[n * HDIM + tid];
    __syncthreads();

    for (int idx = tid; idx < KDIM * SDIM; idx += 512)
        q_s[(idx >> 6) * 68 + (idx & 63)] = r_s[idx];

    float4 breg[32];
#pragma unroll
    for (int it = 0; it < 32; ++it) {
        const int row = it * 32 + wave * 4 + rq;
        const float* xr = Xn + (size_t)row * SDIM + sub * 4;
        const float l = lse_s[row];
        breg[it] = make_float4(__expf(xr[0] - l), __expf(xr[1] - l),
                               __expf(xr[2] - l), __expf(xr[3] - l));
    }
    bar_lds();

#pragma unroll 1
    for (int h = 1; h < HDIM; ++h) {
        if (tid < SDIM) {
            const int base = (h - 1) * KDIM;
            float m = -1e30f;
#pragma unroll
            for (int k = 0; k < KDIM; ++k) m = fmaxf(m, q_s[(base + k) * 68 + tid]);
            float ssum = 0.f;
#pragma unroll
            for (int k = 0; k < KDIM; ++k) ssum += __expf(q_s[(base + k) * 68 + tid] - m);
            v_s[tid] = m + __logf(ssum);
        }
        bar_lds();
        const float4 v4 = *(const float4*)&v_s[sub * 4];
#pragma unroll
        for (int it = 0; it < 32; ++it) {
            const int row = it * 32 + wave * 4 + rq;
            float acc = breg[it].x * v4.x + breg[it].y * v4.y
                      + breg[it].z * v4.z + breg[it].w * v4.w;
            acc += __shfl_xor(acc, 1, 64);
            acc += __shfl_xor(acc, 2, 64);
            acc += __shfl_xor(acc, 4, 64);
            acc += __shfl_xor(acc, 8, 64);
            if (sub == 0)
                q_s[(h * KDIM + (row >> 6)) * 68 + (row & 63)] = r_s[row] + acc;
        }
        bar_lds();
    }

    const int tc = tid >> 4, kk = tid & 15;
#pragma unroll 1
    for (int t0 = 0; t0 < TDIM; t0 += 64) {
        const int nt = (TDIM - t0) < 64 ? (TDIM - t0) : 64;
        for (int idx = tid; idx < nt * 16; idx += 512) {
            const int row = idx >> 4, jq = idx & 15;
            *(float4*)&b_lds[row * 68 + jq * 4] =
                *(const float4*)&out_b_g[(((size_t)(t0 + row)) * NDIM + n) * SDIM + jq * 4];
        }
        bar_lds();
        const bool vA = tc < nt, vB = (tc + 32) < nt;
        float4 bqA[16], bqB[16];
        if (vA) {
#pragma unroll
            for (int jq = 0; jq < 16; ++jq)
                bqA[jq] = *(const float4*)&b_lds[tc * 68 + jq * 4];
        }
        if (vB) {
#pragma unroll
            for (int jq = 0; jq < 16; ++jq)
                bqB[jq] = *(const float4*)&b_lds[(tc + 32) * 68 + jq * 4];
        }
        float pikA = 0.f, pikB = 0.f;
#pragma unroll 1
        for (int h = 0; h < HDIM; ++h) {
            const float* qr = &q_s[(h * KDIM + kk) * 68];
            float aA = 0.f, aB = 0.f;
#pragma unroll
            for (int jq = 0; jq < 16; ++jq) {
                const float4 qv = *(const float4*)&qr[jq * 4];
                if (vA) aA += qv.x * bqA[jq].x + qv.y * bqA[jq].y
                            + qv.z * bqA[jq].z + qv.w * bqA[jq].w;
                if (vB) aB += qv.x * bqB[jq].x + qv.y * bqB[jq].y
                            + qv.z * bqB[jq].z + qv.w * bqB[jq].w;
            }
            float mA = aA, mB = aB;
            mA = fmaxf(mA, __shfl_xor(mA, 1, 64));
            mA = fmaxf(mA, __shfl_xor(mA, 2, 64));
            mA = fmaxf(mA, __shfl_xor(mA, 4, 64));
            mA = fmaxf(mA, __shfl_xor(mA, 8, 64));
            mB = fmaxf(mB, __shfl_xor(mB, 1, 64));
            mB = fmaxf(mB, __shfl_xor(mB, 2, 64));
            mB = fmaxf(mB, __shfl_xor(mB, 4, 64));
            mB = fmaxf(mB, __shfl_xor(mB, 8, 64));
            float eA = __expf(aA - mA), eB = __expf(aB - mB);
            float SA = eA, SB = eB;
            SA += __shfl_xor(SA, 1, 64);
            SA += __shfl_xor(SA, 2, 64);
            SA += __shfl_xor(SA, 4, 64);
            SA += __shfl_xor(SA, 8, 64);
            SB += __shfl_xor(SB, 1, 64);
            SB += __shfl_xor(SB, 2, 64);
            SB += __shfl_xor(SB, 4, 64);
            SB += __shfl_xor(SB, 8, 64);
            const float ph = pdf_s[h];
            pikA += ph * eA / SA;
            pikB += ph * eB / SB;
        }
        if (vA) out_pi[(((size_t)(t0 + tc)) * NDIM + n) * KDIM + kk] = pikA;
        if (vB) out_pi[(((size_t)(t0 + 32 + tc)) * NDIM + n) * KDIM + kk] = pikB;
        bar_lds();
    }
}

extern "C" void kernel_launch(void* const* d_in, const int* in_sizes, int n_in,
                              void* d_out, int out_size, void* d_ws, size_t ws_size,
                              hipStream_t stream) {
    (void)in_sizes; (void)n_in; (void)out_size;
    const float* o     = (const float*)d_in[0];
    const int*   a     = (const int*)d_in[1];
    const float* theta = (const float*)d_in[2];
    float* out = (float*)d_out;
    float* ws  = (float*)d_ws;

    float* lse    = ws;                                   // N*K*S
    float* rws    = lse    + (size_t)NDIM * KDIM * SDIM;  // N*K*S
    float* invstd = rws    + (size_t)NDIM * KDIM * SDIM;  // N*S*O
    float* c0     = invstd + (size_t)NDIM * SDIM * ODIM;  // N*S
    float* ent    = c0     + (size_t)NDIM * SDIM;         // N*S
    float* logC   = ent    + (size_t)NDIM * SDIM;         // N*S
    float* Dws    = logC   + (size_t)NDIM * SDIM;         // N*S
    float* pdfws  = Dws    + (size_t)NDIM * SDIM;         // N*H
    float* q_ws   = pdfws  + (size_t)NDIM * HDIM;         // N*H*K*S f32 (63 MB)
    __hip_bfloat16* bn = (__hip_bfloat16*)(q_ws + (size_t)NDIM * HDIM * KDIM * SDIM);

    const size_t f_base = (size_t)NDIM * KDIM * SDIM * 2
                        + (size_t)NDIM * SDIM * ODIM
                        + (size_t)NDIM * SDIM * 4
                        + (size_t)NDIM * HDIM;
    const size_t f_q  = (size_t)NDIM * HDIM * KDIM * SDIM;
    const size_t need2 = (f_base + f_q) * 4;                       // ~72 MB
    const size_t need1 = need2 + (size_t)NDIM * KDIM * SDIM * SDIM * 2; // ~139 MB

    float* out_pi = out;
    float* out_b  = out + (size_t)TDIM * NDIM * KDIM;
    float* out_lp = out + (size_t)TDIM * NDIM * KDIM + (size_t)TDIM * NDIM * SDIM;

    transform_kernel<<<NDIM, 256, 0, stream>>>(theta, invstd, c0, ent, logC, Dws, pdfws);

    if (ws_size >= need1) {
        row_stats_kernel<<<(NDIM * KDIM * SDIM) / 4, 256, 0, stream>>>(
            theta, logC, ent, lse, rws, bn);
        belief4_kernel<<<NDIM, 256, 0, stream>>>(
            o, a, theta, bn, invstd, c0, Dws, out_b, out_lp);
        vi_kernel<<<NDIM, 512, 0, stream>>>(theta, lse, rws, q_ws);
        policy_bc_kernel<<<NDIM, 512, 0, stream>>>(q_ws, out_b, pdfws, out_pi);
    } else if (ws_size >= need2) {
        row_stats_kernel<<<(NDIM * KDIM * SDIM) / 4, 256, 0, stream>>>(
            theta, logC, ent, lse, rws, (__hip_bfloat16*)nullptr);
        belief_kernel<<<NDIM, 512, 0, stream>>>(
            o, a, theta, lse, invstd, c0, Dws, out_b, out_lp);
        vi_kernel<<<NDIM, 512, 0, stream>>>(theta, lse, rws, q_ws);
        policy_bc_kernel<<<NDIM, 512, 0, stream>>>(q_ws, out_b, pdfws, out_pi);
    } else {
        row_stats_kernel<<<(NDIM * KDIM * SDIM) / 4, 256, 0, stream>>>(
            theta, logC, ent, lse, rws, (__hip_bfloat16*)nullptr);
        belief_kernel<<<NDIM, 512, 0, stream>>>(
            o, a, theta, lse, invstd, c0, Dws, out_b, out_lp);
        vi_policy_kernel<<<NDIM, 512, 0, stream>>>(theta, lse, rws, pdfws, out_b, out_pi);
    }
}